// Round 3
// baseline (1552.426 us; speedup 1.0000x reference)
//
#include <hip/hip_runtime.h>

#define N_NODES 100000
#define N_EDGES 220000
#define N_TOT   320000   // E + N self loops
#define N_B     4096
#define HIDDEN  256
#define BN_S    0.9999950000374997f
#define LDSW    40       // LDS row stride in bf16 elems (80 B, 16B-aligned, conflict-free)
#define NSCANB  98       // ceil(100000/1024)
#define NEG_INF (-__builtin_inff())

typedef __attribute__((ext_vector_type(8))) short bf16x8;
typedef __attribute__((ext_vector_type(4))) float f32x4;

__device__ __forceinline__ float bf2f(unsigned short u) {
  return __uint_as_float(((unsigned int)u) << 16);
}
__device__ __forceinline__ unsigned short f2bf(float f) {
  unsigned int x = __float_as_uint(f);
  unsigned int lsb = (x >> 16) & 1u;
  x += 0x7fffu + lsb;
  return (unsigned short)(x >> 16);
}

// ---------------- zero-init of counters ----------------
__global__ void zero_kernel(int* __restrict__ deg, int* __restrict__ cursor, float* __restrict__ macc) {
  int i = blockIdx.x * blockDim.x + threadIdx.x;
  if (i < N_NODES) { deg[i] = 0; cursor[i] = 0; }
  if (i < 16) macc[i] = 0.f;
}

// ---------------- mean of edge_attr ----------------
__global__ void mean_kernel(const float* __restrict__ ea, float* __restrict__ macc) {
  int lane = threadIdx.x & 63;
  float loc[10];
#pragma unroll
  for (int k = 0; k < 10; ++k) loc[k] = 0.f;
  for (int e = blockIdx.x * blockDim.x + threadIdx.x; e < N_EDGES; e += gridDim.x * blockDim.x) {
    const float* p = ea + (size_t)e * 10;
#pragma unroll
    for (int k = 0; k < 10; ++k) loc[k] += p[k];
  }
#pragma unroll
  for (int k = 0; k < 10; ++k) {
    float v = loc[k];
#pragma unroll
    for (int o = 1; o < 64; o <<= 1) v += __shfl_xor(v, o);
    if (lane == 0) atomicAdd(&macc[k], v);
  }
}

__global__ void meanattr_kernel(const float* __restrict__ macc, float* __restrict__ meanattr) {
  int t = threadIdx.x;
  const float invE = 1.f / (float)N_EDGES;
  if (t < 10) meanattr[t] = macc[t] * invE;
}

// ---------------- CSR build ----------------
__global__ void count_kernel(const int* __restrict__ ei, int* __restrict__ deg) {
  for (int e = blockIdx.x * blockDim.x + threadIdx.x; e < N_TOT; e += gridDim.x * blockDim.x) {
    int t;
    if (e < N_EDGES) t = ei[N_EDGES + e];
    else             t = e - N_EDGES;
    atomicAdd(&deg[t], 1);
  }
}

// ---------------- 3-phase scan ----------------
__global__ __launch_bounds__(1024) void scan1_kernel(const int* __restrict__ deg,
                                                     int* __restrict__ rowptr,
                                                     int* __restrict__ bsum) {
  __shared__ int buf[1024];
  int t = threadIdx.x;
  int i = blockIdx.x * 1024 + t;
  int v = (i < N_NODES) ? deg[i] : 0;
  buf[t] = v;
  __syncthreads();
  for (int off = 1; off < 1024; off <<= 1) {
    int add = (t >= off) ? buf[t - off] : 0;
    __syncthreads();
    buf[t] += add;
    __syncthreads();
  }
  if (i < N_NODES) rowptr[i + 1] = buf[t];
  if (t == 1023) bsum[blockIdx.x] = buf[t];
  if (i == 0) rowptr[0] = 0;
}

__global__ __launch_bounds__(128) void scan2_kernel(int* __restrict__ bsum) {
  __shared__ int buf[128];
  int t = threadIdx.x;
  int v = (t < NSCANB) ? bsum[t] : 0;
  buf[t] = v;
  __syncthreads();
  for (int off = 1; off < 128; off <<= 1) {
    int add = (t >= off) ? buf[t - off] : 0;
    __syncthreads();
    buf[t] += add;
    __syncthreads();
  }
  if (t < NSCANB) bsum[t] = buf[t];
}

__global__ __launch_bounds__(1024) void scan3_kernel(int* __restrict__ rowptr,
                                                     const int* __restrict__ bsum) {
  int b = blockIdx.x;
  if (b == 0) return;
  int i = b * 1024 + threadIdx.x;
  if (i < N_NODES) rowptr[i + 1] += bsum[b - 1];
}

__global__ void scatter_kernel(const int* __restrict__ ei, const int* __restrict__ rowptr,
                               int* __restrict__ cursor, int* __restrict__ csr) {
  for (int e = blockIdx.x * blockDim.x + threadIdx.x; e < N_TOT; e += gridDim.x * blockDim.x) {
    int t;
    if (e < N_EDGES) t = ei[N_EDGES + e];
    else             t = e - N_EDGES;
    int pos = atomicAdd(&cursor[t], 1);
    csr[rowptr[t] + pos] = e;
  }
}

__global__ void brp_kernel(const int* __restrict__ batch, int* __restrict__ brp) {
  for (int i = blockIdx.x * blockDim.x + threadIdx.x; i < N_NODES; i += gridDim.x * blockDim.x) {
    int bi = batch[i];
    int bp = (i == 0) ? -1 : batch[i - 1];
    for (int b = bp + 1; b <= bi; ++b) brp[b] = i;
    if (i == N_NODES - 1) {
      for (int b = bi + 1; b <= N_B; ++b) brp[b] = N_NODES;
    }
  }
}

// ---------------- x -> padded bf16 [N,96] ----------------
__global__ void convx_kernel(const float* __restrict__ x, unsigned short* __restrict__ xp) {
  int total = N_NODES * 96;
  for (int idx = blockIdx.x * blockDim.x + threadIdx.x; idx < total; idx += gridDim.x * blockDim.x) {
    int nn = idx / 96;
    int j = idx - nn * 96;
    unsigned short v = 0;
    if (j < 75) v = f2bf(x[(size_t)nn * 75 + j]);
    xp[idx] = v;
  }
}

// ---------------- weight transpose+bf16: dst[n*Kp+k] = src[k*N+n] (0 beyond K) ----------------
__global__ void wt_kernel(const float* __restrict__ src, unsigned short* __restrict__ dst,
                          int K, int Kp, int N) {
  int idx = blockIdx.x * blockDim.x + threadIdx.x;
  int total = N * Kp;
  if (idx >= total) return;
  int n = idx / Kp, k = idx - n * Kp;
  dst[idx] = (k < K) ? f2bf(src[(size_t)k * N + n]) : (unsigned short)0;
}

// ---------------- all 4 layers Wl^T||Wr^T in one launch ----------------
// dst [i][512][256]; rows 0..255 = Wl[i]^T, rows 256..511 = Wr[i]^T
__global__ void wlr_kernel(const float* __restrict__ Wl, const float* __restrict__ Wr,
                           unsigned short* __restrict__ dst) {
  const int total = 4 * 512 * 256;
  for (int idx = blockIdx.x * blockDim.x + threadIdx.x; idx < total; idx += gridDim.x * blockDim.x) {
    int i = idx >> 17;          // /131072
    int rem = idx & 131071;
    int n = rem >> 8;           // 0..511
    int k = rem & 255;
    float v = (n < 256) ? Wl[(size_t)i * 65536 + k * 256 + n]
                        : Wr[(size_t)i * 65536 + k * 256 + (n - 256)];
    dst[idx] = f2bf(v);
  }
}

// ---------------- bf16 MFMA GEMM: C = act((A @ Bt^T + bias)*scale) ----------------
__global__ __launch_bounds__(256) void gemm_mfma(
    const unsigned short* __restrict__ A, const unsigned short* __restrict__ Bt,
    const float* __restrict__ bias, float* __restrict__ Cf, unsigned short* __restrict__ Cb,
    int M, int Ncol, int K, int act, float scale)
{
  __shared__ unsigned short As[128 * LDSW];
  __shared__ unsigned short Bs[128 * LDSW];
  const int tid = threadIdx.x;
  const int wave = tid >> 6;
  const int lane = tid & 63;
  const int col0 = blockIdx.x * 128;
  const int row0 = blockIdx.y * 128;
  const int wrow = (wave >> 1) * 64;
  const int wcol = (wave & 1) * 64;
  const int lrow = lane & 15;
  const int quad = lane >> 4;

  f32x4 acc[4][4] = {};

  const int srow = tid >> 1;          // 0..127
  const int shalf = (tid & 1) * 16;   // 0 or 16 (bf16 elems)

  for (int k0 = 0; k0 < K; k0 += 32) {
    {
      int gr = row0 + srow;
      uint4 a0 = {0, 0, 0, 0}, a1 = {0, 0, 0, 0};
      if (gr < M) {
        const unsigned short* src = A + (size_t)gr * K + k0 + shalf;
        a0 = *(const uint4*)(src);
        a1 = *(const uint4*)(src + 8);
      }
      *(uint4*)(&As[srow * LDSW + shalf]) = a0;
      *(uint4*)(&As[srow * LDSW + shalf + 8]) = a1;
      const unsigned short* srcb = Bt + (size_t)(col0 + srow) * K + k0 + shalf;
      *(uint4*)(&Bs[srow * LDSW + shalf]) = *(const uint4*)(srcb);
      *(uint4*)(&Bs[srow * LDSW + shalf + 8]) = *(const uint4*)(srcb + 8);
    }
    __syncthreads();
    bf16x8 afr[4], bfr[4];
#pragma unroll
    for (int mt = 0; mt < 4; ++mt)
      afr[mt] = *(const bf16x8*)(&As[(wrow + mt * 16 + lrow) * LDSW + quad * 8]);
#pragma unroll
    for (int nt = 0; nt < 4; ++nt)
      bfr[nt] = *(const bf16x8*)(&Bs[(wcol + nt * 16 + lrow) * LDSW + quad * 8]);
#pragma unroll
    for (int mt = 0; mt < 4; ++mt)
#pragma unroll
      for (int nt = 0; nt < 4; ++nt)
        acc[mt][nt] = __builtin_amdgcn_mfma_f32_16x16x32_bf16(afr[mt], bfr[nt], acc[mt][nt], 0, 0, 0);
    __syncthreads();
  }

#pragma unroll
  for (int mt = 0; mt < 4; ++mt) {
#pragma unroll
    for (int nt = 0; nt < 4; ++nt) {
      int gcol = col0 + wcol + nt * 16 + lrow;
      float bv = bias ? bias[gcol] : 0.f;
#pragma unroll
      for (int r = 0; r < 4; ++r) {
        int grow = row0 + wrow + mt * 16 + quad * 4 + r;
        if (grow >= M) continue;
        float v = (acc[mt][nt][r] + bv) * scale;
        if (act == 1) v = fmaxf(v, 0.f);
        else if (act == 2) v = (v > 0.f) ? v : (__expf(v) - 1.f);
        if (Cf) Cf[(size_t)grow * Ncol + gcol] = v;
        if (Cb) Cb[(size_t)grow * Ncol + gcol] = f2bf(v);
      }
    }
  }
}

// ---------------- fused pooling-gate GEMM: gate = relu(hb@Wg1+bg1) . Wg2 + bg2 ----------------
__global__ __launch_bounds__(256) void gemm_gate(
    const unsigned short* __restrict__ A, const unsigned short* __restrict__ Bt,
    const float* __restrict__ bg1, const float* __restrict__ Wg2,
    const float* __restrict__ bg2, float* __restrict__ gate, int M)
{
  __shared__ unsigned short As[128 * LDSW];
  __shared__ unsigned short Bs[128 * LDSW];
  __shared__ float gbuf[128][2];
  const int tid = threadIdx.x;
  const int wave = tid >> 6;
  const int lane = tid & 63;
  const int row0 = blockIdx.x * 128;
  const int wrow = (wave >> 1) * 64;
  const int wcol = (wave & 1) * 64;
  const int lrow = lane & 15;
  const int quad = lane >> 4;

  f32x4 acc[4][4] = {};
  const int srow = tid >> 1;
  const int shalf = (tid & 1) * 16;

  for (int k0 = 0; k0 < 256; k0 += 32) {
    {
      int gr = row0 + srow;
      uint4 a0 = {0, 0, 0, 0}, a1 = {0, 0, 0, 0};
      if (gr < M) {
        const unsigned short* src = A + (size_t)gr * 256 + k0 + shalf;
        a0 = *(const uint4*)(src);
        a1 = *(const uint4*)(src + 8);
      }
      *(uint4*)(&As[srow * LDSW + shalf]) = a0;
      *(uint4*)(&As[srow * LDSW + shalf + 8]) = a1;
      const unsigned short* srcb = Bt + (size_t)srow * 256 + k0 + shalf;
      *(uint4*)(&Bs[srow * LDSW + shalf]) = *(const uint4*)(srcb);
      *(uint4*)(&Bs[srow * LDSW + shalf + 8]) = *(const uint4*)(srcb + 8);
    }
    __syncthreads();
    bf16x8 afr[4], bfr[4];
#pragma unroll
    for (int mt = 0; mt < 4; ++mt)
      afr[mt] = *(const bf16x8*)(&As[(wrow + mt * 16 + lrow) * LDSW + quad * 8]);
#pragma unroll
    for (int nt = 0; nt < 4; ++nt)
      bfr[nt] = *(const bf16x8*)(&Bs[(wcol + nt * 16 + lrow) * LDSW + quad * 8]);
#pragma unroll
    for (int mt = 0; mt < 4; ++mt)
#pragma unroll
      for (int nt = 0; nt < 4; ++nt)
        acc[mt][nt] = __builtin_amdgcn_mfma_f32_16x16x32_bf16(afr[mt], bfr[nt], acc[mt][nt], 0, 0, 0);
    __syncthreads();
  }

  float p[4][4];
#pragma unroll
  for (int mt = 0; mt < 4; ++mt)
#pragma unroll
    for (int r = 0; r < 4; ++r) p[mt][r] = 0.f;
#pragma unroll
  for (int nt = 0; nt < 4; ++nt) {
    int gcol = wcol + nt * 16 + lrow;
    float b1v = bg1[gcol];
    float w2v = Wg2[gcol];
#pragma unroll
    for (int mt = 0; mt < 4; ++mt)
#pragma unroll
      for (int r = 0; r < 4; ++r) {
        float v = fmaxf(acc[mt][nt][r] + b1v, 0.f);
        p[mt][r] = fmaf(v, w2v, p[mt][r]);
      }
  }
#pragma unroll
  for (int mt = 0; mt < 4; ++mt)
#pragma unroll
    for (int r = 0; r < 4; ++r) {
      float v = p[mt][r];
      v += __shfl_xor(v, 1);
      v += __shfl_xor(v, 2);
      v += __shfl_xor(v, 4);
      v += __shfl_xor(v, 8);
      if (lrow == 0) gbuf[wrow + mt * 16 + quad * 4 + r][wcol >> 6] = v;
    }
  __syncthreads();
  if (tid < 128) {
    int grow = row0 + tid;
    if (grow < M) gate[grow] = gbuf[tid][0] + gbuf[tid][1] + bg2[0];
  }
}

// ---------------- f32 GEMM for the tiny readout layers ----------------
__global__ __launch_bounds__(256) void gemm_f32(
    const float* __restrict__ A, const float* __restrict__ B,
    const float* __restrict__ bias, float* __restrict__ C,
    int M, int Ncol, int K, int act, float scale)
{
  __shared__ float As[32][68];
  __shared__ float Bs[32][68];
  const int tid = threadIdx.x;
  const int tx = tid & 15, ty = tid >> 4;
  const int col0 = blockIdx.x * 64;
  const int row0 = blockIdx.y * 64;
  float acc[4][4];
#pragma unroll
  for (int i = 0; i < 4; ++i)
#pragma unroll
    for (int j = 0; j < 4; ++j) acc[i][j] = 0.f;

  const int ar = tid >> 3;
  const int ak = (tid & 7) * 4;
  const int bk = tid >> 4;
  const int bc = (tid & 15) * 4;

  for (int k0 = 0; k0 < K; k0 += 32) {
#pragma unroll
    for (int p = 0; p < 2; ++p) {
      int r = ar + p * 32;
      int grow = row0 + r;
      float4 v = make_float4(0.f, 0.f, 0.f, 0.f);
      if (grow < M) v = *(const float4*)(A + (size_t)grow * K + k0 + ak);
      As[ak + 0][r] = v.x; As[ak + 1][r] = v.y; As[ak + 2][r] = v.z; As[ak + 3][r] = v.w;
    }
#pragma unroll
    for (int p = 0; p < 2; ++p) {
      int kk = bk + p * 16;
      float4 v = *(const float4*)(B + (size_t)(k0 + kk) * Ncol + col0 + bc);
      *(float4*)(&Bs[kk][bc]) = v;
    }
    __syncthreads();
#pragma unroll
    for (int kk = 0; kk < 32; ++kk) {
      float4 a = *(const float4*)(&As[kk][ty * 4]);
      float4 b = *(const float4*)(&Bs[kk][tx * 4]);
      float av[4] = {a.x, a.y, a.z, a.w};
      float bv[4] = {b.x, b.y, b.z, b.w};
#pragma unroll
      for (int i = 0; i < 4; ++i)
#pragma unroll
        for (int j = 0; j < 4; ++j) acc[i][j] = fmaf(av[i], bv[j], acc[i][j]);
    }
    __syncthreads();
  }
  float bvals[4] = {0.f, 0.f, 0.f, 0.f};
  if (bias) {
#pragma unroll
    for (int j = 0; j < 4; ++j) bvals[j] = bias[col0 + tx * 4 + j];
  }
#pragma unroll
  for (int i = 0; i < 4; ++i) {
    int r = row0 + ty * 4 + i;
    if (r >= M) continue;
    float4 outv;
    float* o = (float*)&outv;
#pragma unroll
    for (int j = 0; j < 4; ++j) {
      float v = (acc[i][j] + bvals[j]) * scale;
      if (act == 1) v = fmaxf(v, 0.f);
      else if (act == 2) v = (v > 0.f) ? v : (__expf(v) - 1.f);
      o[j] = v;
    }
    *(float4*)(C + (size_t)r * Ncol + col0 + tx * 4) = outv;
  }
}

// ---------------- fused GATv2 attention + aggregate + BN/ELU/residual ----------------
// one wave per node (one-shot); lane l owns channels [4l,4l+4); head = l>>3.
// Edge loop unrolled by 4, branchless: remainder slots clamp the csr index and
// force logit=-inf (exp(-inf-mn)=0 kills their contribution). 4 independent
// gather chains in flight; one merged online-softmax update per quad.
__global__ __launch_bounds__(256) void attn_kernel(
    const unsigned short* __restrict__ xlr,
    float* __restrict__ h, unsigned short* __restrict__ hb,
    const int* __restrict__ ei, const float* __restrict__ eattr,
    const float* __restrict__ We, const float* __restrict__ att,
    const float* __restrict__ bgat, const float* __restrict__ meanattr,
    const int* __restrict__ rowptr, const int* __restrict__ csr)
{
  const int lane = threadIdx.x & 63;
  const int wv = threadIdx.x >> 6;
  const int n = blockIdx.x * 4 + wv;
  if (n >= N_NODES) return;
  const int c0 = lane * 4;

  const int s = rowptr[n], e = rowptr[n + 1];

  float xrn[4];
  {
    ushort4 u = *(const ushort4*)(xlr + (size_t)n * 512 + 256 + c0);
    xrn[0] = bf2f(u.x); xrn[1] = bf2f(u.y); xrn[2] = bf2f(u.z); xrn[3] = bf2f(u.w);
  }
  // prefetch residual early so its latency hides under the edge loop
  float4 hold = *(const float4*)(h + (size_t)n * HIDDEN + c0);

  float4 attf4 = *(const float4*)(att + c0);
  float attf[4] = {attf4.x, attf4.y, attf4.z, attf4.w};
  float wef[10][4];
#pragma unroll
  for (int k = 0; k < 10; ++k) {
    float4 w4 = *(const float4*)(We + k * 256 + c0);
    wef[k][0] = w4.x; wef[k][1] = w4.y; wef[k][2] = w4.z; wef[k][3] = w4.w;
  }

  // branchless per-edge gather (ei[] has 2E ints so ei[eid] is always in-bounds)
  auto gather = [&](int eid, float x[4]) -> float {
    bool real = eid < N_EDGES;
    int sv = ei[eid];
    int srcn = real ? sv : (eid - N_EDGES);
    const float* eap = real ? (eattr + (size_t)eid * 10) : meanattr;
    float2 q0 = *(const float2*)(eap + 0);
    float2 q1 = *(const float2*)(eap + 2);
    float2 q2 = *(const float2*)(eap + 4);
    float2 q3 = *(const float2*)(eap + 6);
    float2 q4 = *(const float2*)(eap + 8);
    ushort4 u = *(const ushort4*)(xlr + (size_t)srcn * 512 + c0);
    x[0] = bf2f(u.x); x[1] = bf2f(u.y); x[2] = bf2f(u.z); x[3] = bf2f(u.w);
    float ev[10] = {q0.x, q0.y, q1.x, q1.y, q2.x, q2.y, q3.x, q3.y, q4.x, q4.y};
    float p0 = 0.f, p1 = 0.f, p2 = 0.f, p3 = 0.f;
#pragma unroll
    for (int k = 0; k < 10; ++k) {
      p0 = fmaf(ev[k], wef[k][0], p0);
      p1 = fmaf(ev[k], wef[k][1], p1);
      p2 = fmaf(ev[k], wef[k][2], p2);
      p3 = fmaf(ev[k], wef[k][3], p3);
    }
    float s0 = x[0] + xrn[0] + p0;
    float s1 = x[1] + xrn[1] + p1;
    float s2 = x[2] + xrn[2] + p2;
    float s3 = x[3] + xrn[3] + p3;
    s0 = (s0 > 0.f) ? s0 : 0.2f * s0;
    s1 = (s1 > 0.f) ? s1 : 0.2f * s1;
    s2 = (s2 > 0.f) ? s2 : 0.2f * s2;
    s3 = (s3 > 0.f) ? s3 : 0.2f * s3;
    float part = s0 * attf[0] + s1 * attf[1] + s2 * attf[2] + s3 * attf[3];
    part += __shfl_xor(part, 1);
    part += __shfl_xor(part, 2);
    part += __shfl_xor(part, 4);
    return part;
  };

  float m = NEG_INF;
  float d = 0.f;
  float a0 = 0.f, a1 = 0.f, a2 = 0.f, a3 = 0.f;
  const int elast = e - 1;
  for (int idx = s; idx < e; idx += 4) {
    int i1 = idx + 1, i2 = idx + 2, i3 = idx + 3;
    int c1 = (i1 <= elast) ? i1 : elast;
    int c2 = (i2 <= elast) ? i2 : elast;
    int c3 = (i3 <= elast) ? i3 : elast;
    int e0 = csr[idx];
    int e1 = csr[c1];
    int e2 = csr[c2];
    int e3 = csr[c3];
    float x0[4], x1[4], x2[4], x3[4];
    float l0 = gather(e0, x0);
    float l1 = gather(e1, x1);
    float l2 = gather(e2, x2);
    float l3 = gather(e3, x3);
    if (i1 > elast) l1 = NEG_INF;
    if (i2 > elast) l2 = NEG_INF;
    if (i3 > elast) l3 = NEG_INF;
    float mn = fmaxf(fmaxf(m, fmaxf(l0, l1)), fmaxf(l2, l3));
    float sc = __expf(m - mn);
    float w0 = __expf(l0 - mn);
    float w1 = __expf(l1 - mn);
    float w2 = __expf(l2 - mn);
    float w3 = __expf(l3 - mn);
    d = d * sc + ((w0 + w1) + (w2 + w3));
    a0 = a0 * sc + (w0 * x0[0] + w1 * x1[0]) + (w2 * x2[0] + w3 * x3[0]);
    a1 = a1 * sc + (w0 * x0[1] + w1 * x1[1]) + (w2 * x2[1] + w3 * x3[1]);
    a2 = a2 * sc + (w0 * x0[2] + w1 * x1[2]) + (w2 * x2[2] + w3 * x3[2]);
    a3 = a3 * sc + (w0 * x0[3] + w1 * x1[3]) + (w2 * x2[3] + w3 * x3[3]);
    m = mn;
  }

  float inv = 1.f / (d + 1e-16f);
  float4 bg = *(const float4*)(bgat + c0);
  float ov[4] = {a0 * inv, a1 * inv, a2 * inv, a3 * inv};
  float bgv[4] = {bg.x, bg.y, bg.z, bg.w};
  float hv[4] = {hold.x, hold.y, hold.z, hold.w};
  float4 res;
  float* rp = (float*)&res;
  ushort4 resb;
  unsigned short* rb = (unsigned short*)&resb;
#pragma unroll
  for (int j = 0; j < 4; ++j) {
    float v = (ov[j] + bgv[j]) * BN_S;
    v = (v > 0.f) ? v : (__expf(v) - 1.f);
    float nv = v + hv[j];
    rp[j] = nv;
    rb[j] = f2bf(nv);
  }
  *(float4*)(h + (size_t)n * HIDDEN + c0) = res;
  *(ushort4*)(hb + (size_t)n * HIDDEN + c0) = resb;
}

// ---------------- global attention pooling per graph ----------------
__global__ __launch_bounds__(64) void pool_kernel(
    const float* __restrict__ gate, const float* __restrict__ h,
    const int* __restrict__ brp, float* __restrict__ pooled)
{
  int b = blockIdx.x;
  int lane = threadIdx.x;
  int s = brp[b], e = brp[b + 1];
  float m = -__builtin_inff();
  for (int i = s + lane; i < e; i += 64) m = fmaxf(m, gate[i]);
#pragma unroll
  for (int o = 1; o < 64; o <<= 1) m = fmaxf(m, __shfl_xor(m, o));
  float d = 0.f;
  for (int i = s + lane; i < e; i += 64) d += __expf(gate[i] - m);
#pragma unroll
  for (int o = 1; o < 64; o <<= 1) d += __shfl_xor(d, o);
  float inv = 1.f / (d + 1e-16f);
  int c0 = lane * 4;
  float acc[4] = {0.f, 0.f, 0.f, 0.f};
  for (int i = s; i < e; ++i) {
    float w = __expf(gate[i] - m) * inv;
    float4 hv = *(const float4*)(h + (size_t)i * HIDDEN + c0);
    acc[0] = fmaf(w, hv.x, acc[0]);
    acc[1] = fmaf(w, hv.y, acc[1]);
    acc[2] = fmaf(w, hv.z, acc[2]);
    acc[3] = fmaf(w, hv.w, acc[3]);
  }
  float4 outv = make_float4(acc[0], acc[1], acc[2], acc[3]);
  *(float4*)(pooled + (size_t)b * HIDDEN + c0) = outv;
}

// ---------------- final: out[b] = r3[b,:] . W4 + b4 ----------------
__global__ __launch_bounds__(256) void out_kernel(
    const float* __restrict__ r3, const float* __restrict__ W4,
    const float* __restrict__ b4, float* __restrict__ out)
{
  int lane = threadIdx.x & 63;
  int wv = threadIdx.x >> 6;
  int b = blockIdx.x * 4 + wv;
  if (b >= N_B) return;
  float v = r3[(size_t)b * 64 + lane] * W4[lane];
#pragma unroll
  for (int o = 1; o < 64; o <<= 1) v += __shfl_xor(v, o);
  if (lane == 0) out[b] = v + b4[0];
}

extern "C" void kernel_launch(void* const* d_in, const int* in_sizes, int n_in,
                              void* d_out, int out_size, void* d_ws, size_t ws_size,
                              hipStream_t stream)
{
  const float* x    = (const float*)d_in[0];
  const int* ei     = (const int*)d_in[1];
  const float* ea   = (const float*)d_in[2];
  const int* batch  = (const int*)d_in[3];
  const float* W_in = (const float*)d_in[4];
  const float* b_in = (const float*)d_in[5];
  const float* Wl   = (const float*)d_in[6];
  const float* Wr   = (const float*)d_in[7];
  const float* We   = (const float*)d_in[8];
  const float* att  = (const float*)d_in[9];
  const float* bgat = (const float*)d_in[10];
  const float* Wg1  = (const float*)d_in[11];
  const float* bg1  = (const float*)d_in[12];
  const float* Wg2  = (const float*)d_in[13];
  const float* bg2  = (const float*)d_in[14];
  const float* W1   = (const float*)d_in[15];
  const float* b1   = (const float*)d_in[16];
  const float* W2   = (const float*)d_in[17];
  const float* b2   = (const float*)d_in[18];
  const float* W3   = (const float*)d_in[19];
  const float* b3   = (const float*)d_in[20];
  const float* W4   = (const float*)d_in[21];
  const float* b4   = (const float*)d_in[22];
  float* out = (float*)d_out;

  char* ws = (char*)d_ws;
  size_t off = 0;
  auto alloc = [&](size_t bytes) -> char* {
    char* p = ws + off;
    off += (bytes + 255) & ~(size_t)255;
    return p;
  };
  float* h            = (float*)alloc((size_t)N_NODES * HIDDEN * 4);           // 102.4 MB
  unsigned short* hb  = (unsigned short*)alloc((size_t)N_NODES * HIDDEN * 2);  // 51.2 MB
  unsigned short* xlr = (unsigned short*)alloc((size_t)N_NODES * 512 * 2);     // 102.4 MB
  int* deg       = (int*)alloc((size_t)N_NODES * 4);
  int* rowptr    = (int*)alloc((size_t)(N_NODES + 1) * 4);
  int* cursor    = (int*)alloc((size_t)N_NODES * 4);
  int* csr       = (int*)alloc((size_t)N_TOT * 4);
  int* brp       = (int*)alloc((size_t)(N_B + 1) * 4);
  int* bsum      = (int*)alloc(512);
  float* macc    = (float*)alloc(64);
  float* meanattr= (float*)alloc(64);
  unsigned short* Wint  = (unsigned short*)alloc(256 * 96 * 2);       // [256][96]
  unsigned short* Wlrt  = (unsigned short*)alloc(4 * 512 * 256 * 2);  // [i][512][256] = Wl^T || Wr^T
  unsigned short* Wg1t  = (unsigned short*)alloc(128 * 256 * 2);      // [128][256]
  // total ≈ 258.7 MB < 268.4 MB ws  ✓

  // aliases into dead regions of xlr:
  unsigned short* xpad = xlr;            // [N,96] bf16, pre-layer0 only
  float* base2  = (float*)xlr;           // xlr fully dead after last attn layer
  float* gate   = base2;                 // [N] f32
  float* pooled = base2 + 1000000;       // [B,256] f32
  float* r1     = base2 + 3000000;       // [B,256] f32
  float* r2     = base2 + 5000000;       // [B,128] f32
  float* r3     = base2 + 6000000;       // [B,64]  f32

  if (ws_size < off) {
    hipMemsetAsync(d_out, 0, (size_t)out_size * 4, stream);
    return;
  }

  zero_kernel<<<391, 256, 0, stream>>>(deg, cursor, macc);
  mean_kernel<<<256, 256, 0, stream>>>(ea, macc);
  meanattr_kernel<<<1, 64, 0, stream>>>(macc, meanattr);
  count_kernel<<<1250, 256, 0, stream>>>(ei, deg);
  scan1_kernel<<<NSCANB, 1024, 0, stream>>>(deg, rowptr, bsum);
  scan2_kernel<<<1, 128, 0, stream>>>(bsum);
  scan3_kernel<<<NSCANB, 1024, 0, stream>>>(rowptr, bsum);
  scatter_kernel<<<1250, 256, 0, stream>>>(ei, rowptr, cursor, csr);
  brp_kernel<<<512, 256, 0, stream>>>(batch, brp);

  // weight conversions (transpose + bf16)
  wt_kernel<<<(256 * 96 + 255) / 256, 256, 0, stream>>>(W_in, Wint, 75, 96, 256);
  wlr_kernel<<<512, 256, 0, stream>>>(Wl, Wr, Wlrt);
  wt_kernel<<<128, 256, 0, stream>>>(Wg1, Wg1t, 256, 256, 128);
  convx_kernel<<<4096, 256, 0, stream>>>(x, xpad);

  // input projection: h = elu((x @ W_in + b_in) * BN_S)  [MFMA, K=96]
  gemm_mfma<<<dim3(2, 782), 256, 0, stream>>>(xpad, Wint, b_in, h, hb,
                                              N_NODES, 256, 96, 2, BN_S);

  for (int i = 0; i < 4; ++i) {
    // fused xl||xr GEMM: [N,256] @ [256,512] -> xlr [N,512]
    gemm_mfma<<<dim3(4, 782), 256, 0, stream>>>(hb, Wlrt + (size_t)i * 131072, nullptr,
                                                nullptr, xlr, N_NODES, 512, 256, 0, 1.f);
    attn_kernel<<<25000, 256, 0, stream>>>(xlr, h, hb, ei, ea,
                                           We + (size_t)i * 2560, att + (size_t)i * 256,
                                           bgat + (size_t)i * 256, meanattr,
                                           rowptr, csr);
  }

  // fused pooling gate: gate = relu(hb @ Wg1 + bg1) . Wg2 + bg2
  gemm_gate<<<782, 256, 0, stream>>>(hb, Wg1t, bg1, Wg2, bg2, gate, N_NODES);
  pool_kernel<<<N_B, 64, 0, stream>>>(gate, h, brp, pooled);

  // readout MLP (f32, tiny)
  gemm_f32<<<dim3(4, 64), 256, 0, stream>>>(pooled, W1, b1, r1, N_B, 256, 256, 1, BN_S);
  gemm_f32<<<dim3(2, 64), 256, 0, stream>>>(r1, W2, b2, r2, N_B, 128, 256, 1, BN_S);
  gemm_f32<<<dim3(1, 64), 256, 0, stream>>>(r2, W3, b3, r3, N_B, 64, 128, 1, 1.f);
  out_kernel<<<1024, 256, 0, stream>>>(r3, W4, b4, out);
}

// Round 4
// 1511.526 us; speedup vs baseline: 1.0271x; 1.0271x over previous
//
#include <hip/hip_runtime.h>

#define N_NODES 100000
#define N_EDGES 220000
#define N_B     4096
#define HIDDEN  256
#define BN_S    0.9999950000374997f
#define LDSW    40       // LDS row stride in bf16 elems (80 B, 16B-aligned, conflict-free)
#define NSCANB  98       // ceil(100000/1024)

typedef __attribute__((ext_vector_type(8))) short bf16x8;
typedef __attribute__((ext_vector_type(4))) float f32x4;

__device__ __forceinline__ float bf2f(unsigned short u) {
  return __uint_as_float(((unsigned int)u) << 16);
}
__device__ __forceinline__ unsigned short f2bf(float f) {
  unsigned int x = __float_as_uint(f);
  unsigned int lsb = (x >> 16) & 1u;
  x += 0x7fffu + lsb;
  return (unsigned short)(x >> 16);
}

// ---------------- zero-init of counters ----------------
__global__ void zero_kernel(int* __restrict__ deg, int* __restrict__ cursor, float* __restrict__ macc) {
  int i = blockIdx.x * blockDim.x + threadIdx.x;
  if (i < N_NODES) { deg[i] = 0; cursor[i] = 0; }
  if (i < 16) macc[i] = 0.f;
}

// ---------------- mean of edge_attr ----------------
__global__ void mean_kernel(const float* __restrict__ ea, float* __restrict__ macc) {
  int lane = threadIdx.x & 63;
  float loc[10];
#pragma unroll
  for (int k = 0; k < 10; ++k) loc[k] = 0.f;
  for (int e = blockIdx.x * blockDim.x + threadIdx.x; e < N_EDGES; e += gridDim.x * blockDim.x) {
    const float* p = ea + (size_t)e * 10;
#pragma unroll
    for (int k = 0; k < 10; ++k) loc[k] += p[k];
  }
#pragma unroll
  for (int k = 0; k < 10; ++k) {
    float v = loc[k];
#pragma unroll
    for (int o = 1; o < 64; o <<= 1) v += __shfl_xor(v, o);
    if (lane == 0) atomicAdd(&macc[k], v);
  }
}

__global__ void meanattr_kernel(const float* __restrict__ macc, float* __restrict__ meanattr) {
  int t = threadIdx.x;
  const float invE = 1.f / (float)N_EDGES;
  if (t < 10) meanattr[t] = macc[t] * invE;
}

// ---------------- ep_self[i][c] = meanattr . We[i][:,c]  (self-loop edge projection) ----------------
__global__ void epself_kernel(const float* __restrict__ meanattr, const float* __restrict__ We,
                              float* __restrict__ ep_self) {
  int i = blockIdx.x;
  int c = threadIdx.x;
  float s = 0.f;
#pragma unroll
  for (int k = 0; k < 10; ++k)
    s += meanattr[k] * We[(size_t)i * 2560 + k * 256 + c];
  ep_self[i * 256 + c] = s;
}

// ---------------- CSR build (REAL edges only; self-loops handled analytically) ----------------
__global__ void count_kernel(const int* __restrict__ ei, int* __restrict__ deg) {
  for (int e = blockIdx.x * blockDim.x + threadIdx.x; e < N_EDGES; e += gridDim.x * blockDim.x) {
    atomicAdd(&deg[ei[N_EDGES + e]], 1);
  }
}

// ---------------- 3-phase scan ----------------
__global__ __launch_bounds__(1024) void scan1_kernel(const int* __restrict__ deg,
                                                     int* __restrict__ rowptr,
                                                     int* __restrict__ bsum) {
  __shared__ int buf[1024];
  int t = threadIdx.x;
  int i = blockIdx.x * 1024 + t;
  int v = (i < N_NODES) ? deg[i] : 0;
  buf[t] = v;
  __syncthreads();
  for (int off = 1; off < 1024; off <<= 1) {
    int add = (t >= off) ? buf[t - off] : 0;
    __syncthreads();
    buf[t] += add;
    __syncthreads();
  }
  if (i < N_NODES) rowptr[i + 1] = buf[t];
  if (t == 1023) bsum[blockIdx.x] = buf[t];
  if (i == 0) rowptr[0] = 0;
}

__global__ __launch_bounds__(128) void scan2_kernel(int* __restrict__ bsum) {
  __shared__ int buf[128];
  int t = threadIdx.x;
  int v = (t < NSCANB) ? bsum[t] : 0;
  buf[t] = v;
  __syncthreads();
  for (int off = 1; off < 128; off <<= 1) {
    int add = (t >= off) ? buf[t - off] : 0;
    __syncthreads();
    buf[t] += add;
    __syncthreads();
  }
  if (t < NSCANB) bsum[t] = buf[t];
}

__global__ __launch_bounds__(1024) void scan3_kernel(int* __restrict__ rowptr,
                                                     const int* __restrict__ bsum) {
  int b = blockIdx.x;
  if (b == 0) return;
  int i = b * 1024 + threadIdx.x;
  if (i < N_NODES) rowptr[i + 1] += bsum[b - 1];
}

__global__ void scatter_kernel(const int* __restrict__ ei, const int* __restrict__ rowptr,
                               int* __restrict__ cursor, int* __restrict__ csr) {
  for (int e = blockIdx.x * blockDim.x + threadIdx.x; e < N_EDGES; e += gridDim.x * blockDim.x) {
    int t = ei[N_EDGES + e];
    int pos = atomicAdd(&cursor[t], 1);
    csr[rowptr[t] + pos] = e;
  }
}

__global__ void brp_kernel(const int* __restrict__ batch, int* __restrict__ brp) {
  for (int i = blockIdx.x * blockDim.x + threadIdx.x; i < N_NODES; i += gridDim.x * blockDim.x) {
    int bi = batch[i];
    int bp = (i == 0) ? -1 : batch[i - 1];
    for (int b = bp + 1; b <= bi; ++b) brp[b] = i;
    if (i == N_NODES - 1) {
      for (int b = bi + 1; b <= N_B; ++b) brp[b] = N_NODES;
    }
  }
}

// ---------------- x -> padded bf16 [N,96] ----------------
__global__ void convx_kernel(const float* __restrict__ x, unsigned short* __restrict__ xp) {
  int total = N_NODES * 96;
  for (int idx = blockIdx.x * blockDim.x + threadIdx.x; idx < total; idx += gridDim.x * blockDim.x) {
    int nn = idx / 96;
    int j = idx - nn * 96;
    unsigned short v = 0;
    if (j < 75) v = f2bf(x[(size_t)nn * 75 + j]);
    xp[idx] = v;
  }
}

// ---------------- weight transpose+bf16: dst[n*Kp+k] = src[k*N+n] (0 beyond K) ----------------
__global__ void wt_kernel(const float* __restrict__ src, unsigned short* __restrict__ dst,
                          int K, int Kp, int N) {
  int idx = blockIdx.x * blockDim.x + threadIdx.x;
  int total = N * Kp;
  if (idx >= total) return;
  int n = idx / Kp, k = idx - n * Kp;
  dst[idx] = (k < K) ? f2bf(src[(size_t)k * N + n]) : (unsigned short)0;
}

// ---------------- all 4 layers Wl^T||Wr^T in one launch ----------------
__global__ void wlr_kernel(const float* __restrict__ Wl, const float* __restrict__ Wr,
                           unsigned short* __restrict__ dst) {
  const int total = 4 * 512 * 256;
  for (int idx = blockIdx.x * blockDim.x + threadIdx.x; idx < total; idx += gridDim.x * blockDim.x) {
    int i = idx >> 17;          // /131072
    int rem = idx & 131071;
    int n = rem >> 8;           // 0..511
    int k = rem & 255;
    float v = (n < 256) ? Wl[(size_t)i * 65536 + k * 256 + n]
                        : Wr[(size_t)i * 65536 + k * 256 + (n - 256)];
    dst[idx] = f2bf(v);
  }
}

// ---------------- bf16 MFMA GEMM: C = act((A @ Bt^T + bias)*scale) ----------------
__global__ __launch_bounds__(256) void gemm_mfma(
    const unsigned short* __restrict__ A, const unsigned short* __restrict__ Bt,
    const float* __restrict__ bias, float* __restrict__ Cf, unsigned short* __restrict__ Cb,
    int M, int Ncol, int K, int act, float scale)
{
  __shared__ unsigned short As[128 * LDSW];
  __shared__ unsigned short Bs[128 * LDSW];
  const int tid = threadIdx.x;
  const int wave = tid >> 6;
  const int lane = tid & 63;
  const int col0 = blockIdx.x * 128;
  const int row0 = blockIdx.y * 128;
  const int wrow = (wave >> 1) * 64;
  const int wcol = (wave & 1) * 64;
  const int lrow = lane & 15;
  const int quad = lane >> 4;

  f32x4 acc[4][4] = {};

  const int srow = tid >> 1;          // 0..127
  const int shalf = (tid & 1) * 16;   // 0 or 16 (bf16 elems)

  for (int k0 = 0; k0 < K; k0 += 32) {
    {
      int gr = row0 + srow;
      uint4 a0 = {0, 0, 0, 0}, a1 = {0, 0, 0, 0};
      if (gr < M) {
        const unsigned short* src = A + (size_t)gr * K + k0 + shalf;
        a0 = *(const uint4*)(src);
        a1 = *(const uint4*)(src + 8);
      }
      *(uint4*)(&As[srow * LDSW + shalf]) = a0;
      *(uint4*)(&As[srow * LDSW + shalf + 8]) = a1;
      const unsigned short* srcb = Bt + (size_t)(col0 + srow) * K + k0 + shalf;
      *(uint4*)(&Bs[srow * LDSW + shalf]) = *(const uint4*)(srcb);
      *(uint4*)(&Bs[srow * LDSW + shalf + 8]) = *(const uint4*)(srcb + 8);
    }
    __syncthreads();
    bf16x8 afr[4], bfr[4];
#pragma unroll
    for (int mt = 0; mt < 4; ++mt)
      afr[mt] = *(const bf16x8*)(&As[(wrow + mt * 16 + lrow) * LDSW + quad * 8]);
#pragma unroll
    for (int nt = 0; nt < 4; ++nt)
      bfr[nt] = *(const bf16x8*)(&Bs[(wcol + nt * 16 + lrow) * LDSW + quad * 8]);
#pragma unroll
    for (int mt = 0; mt < 4; ++mt)
#pragma unroll
      for (int nt = 0; nt < 4; ++nt)
        acc[mt][nt] = __builtin_amdgcn_mfma_f32_16x16x32_bf16(afr[mt], bfr[nt], acc[mt][nt], 0, 0, 0);
    __syncthreads();
  }

#pragma unroll
  for (int mt = 0; mt < 4; ++mt) {
#pragma unroll
    for (int nt = 0; nt < 4; ++nt) {
      int gcol = col0 + wcol + nt * 16 + lrow;
      float bv = bias ? bias[gcol] : 0.f;
#pragma unroll
      for (int r = 0; r < 4; ++r) {
        int grow = row0 + wrow + mt * 16 + quad * 4 + r;
        if (grow >= M) continue;
        float v = (acc[mt][nt][r] + bv) * scale;
        if (act == 1) v = fmaxf(v, 0.f);
        else if (act == 2) v = (v > 0.f) ? v : (__expf(v) - 1.f);
        if (Cf) Cf[(size_t)grow * Ncol + gcol] = v;
        if (Cb) Cb[(size_t)grow * Ncol + gcol] = f2bf(v);
      }
    }
  }
}

// ---------------- fused pooling-gate GEMM: gate = relu(hb@Wg1+bg1) . Wg2 + bg2 ----------------
__global__ __launch_bounds__(256) void gemm_gate(
    const unsigned short* __restrict__ A, const unsigned short* __restrict__ Bt,
    const float* __restrict__ bg1, const float* __restrict__ Wg2,
    const float* __restrict__ bg2, float* __restrict__ gate, int M)
{
  __shared__ unsigned short As[128 * LDSW];
  __shared__ unsigned short Bs[128 * LDSW];
  __shared__ float gbuf[128][2];
  const int tid = threadIdx.x;
  const int wave = tid >> 6;
  const int lane = tid & 63;
  const int row0 = blockIdx.x * 128;
  const int wrow = (wave >> 1) * 64;
  const int wcol = (wave & 1) * 64;
  const int lrow = lane & 15;
  const int quad = lane >> 4;

  f32x4 acc[4][4] = {};
  const int srow = tid >> 1;
  const int shalf = (tid & 1) * 16;

  for (int k0 = 0; k0 < 256; k0 += 32) {
    {
      int gr = row0 + srow;
      uint4 a0 = {0, 0, 0, 0}, a1 = {0, 0, 0, 0};
      if (gr < M) {
        const unsigned short* src = A + (size_t)gr * 256 + k0 + shalf;
        a0 = *(const uint4*)(src);
        a1 = *(const uint4*)(src + 8);
      }
      *(uint4*)(&As[srow * LDSW + shalf]) = a0;
      *(uint4*)(&As[srow * LDSW + shalf + 8]) = a1;
      const unsigned short* srcb = Bt + (size_t)srow * 256 + k0 + shalf;
      *(uint4*)(&Bs[srow * LDSW + shalf]) = *(const uint4*)(srcb);
      *(uint4*)(&Bs[srow * LDSW + shalf + 8]) = *(const uint4*)(srcb + 8);
    }
    __syncthreads();
    bf16x8 afr[4], bfr[4];
#pragma unroll
    for (int mt = 0; mt < 4; ++mt)
      afr[mt] = *(const bf16x8*)(&As[(wrow + mt * 16 + lrow) * LDSW + quad * 8]);
#pragma unroll
    for (int nt = 0; nt < 4; ++nt)
      bfr[nt] = *(const bf16x8*)(&Bs[(wcol + nt * 16 + lrow) * LDSW + quad * 8]);
#pragma unroll
    for (int mt = 0; mt < 4; ++mt)
#pragma unroll
      for (int nt = 0; nt < 4; ++nt)
        acc[mt][nt] = __builtin_amdgcn_mfma_f32_16x16x32_bf16(afr[mt], bfr[nt], acc[mt][nt], 0, 0, 0);
    __syncthreads();
  }

  float p[4][4];
#pragma unroll
  for (int mt = 0; mt < 4; ++mt)
#pragma unroll
    for (int r = 0; r < 4; ++r) p[mt][r] = 0.f;
#pragma unroll
  for (int nt = 0; nt < 4; ++nt) {
    int gcol = wcol + nt * 16 + lrow;
    float b1v = bg1[gcol];
    float w2v = Wg2[gcol];
#pragma unroll
    for (int mt = 0; mt < 4; ++mt)
#pragma unroll
      for (int r = 0; r < 4; ++r) {
        float v = fmaxf(acc[mt][nt][r] + b1v, 0.f);
        p[mt][r] = fmaf(v, w2v, p[mt][r]);
      }
  }
#pragma unroll
  for (int mt = 0; mt < 4; ++mt)
#pragma unroll
    for (int r = 0; r < 4; ++r) {
      float v = p[mt][r];
      v += __shfl_xor(v, 1);
      v += __shfl_xor(v, 2);
      v += __shfl_xor(v, 4);
      v += __shfl_xor(v, 8);
      if (lrow == 0) gbuf[wrow + mt * 16 + quad * 4 + r][wcol >> 6] = v;
    }
  __syncthreads();
  if (tid < 128) {
    int grow = row0 + tid;
    if (grow < M) gate[grow] = gbuf[tid][0] + gbuf[tid][1] + bg2[0];
  }
}

// ---------------- f32 GEMM for the tiny readout layers ----------------
__global__ __launch_bounds__(256) void gemm_f32(
    const float* __restrict__ A, const float* __restrict__ B,
    const float* __restrict__ bias, float* __restrict__ C,
    int M, int Ncol, int K, int act, float scale)
{
  __shared__ float As[32][68];
  __shared__ float Bs[32][68];
  const int tid = threadIdx.x;
  const int tx = tid & 15, ty = tid >> 4;
  const int col0 = blockIdx.x * 64;
  const int row0 = blockIdx.y * 64;
  float acc[4][4];
#pragma unroll
  for (int i = 0; i < 4; ++i)
#pragma unroll
    for (int j = 0; j < 4; ++j) acc[i][j] = 0.f;

  const int ar = tid >> 3;
  const int ak = (tid & 7) * 4;
  const int bk = tid >> 4;
  const int bc = (tid & 15) * 4;

  for (int k0 = 0; k0 < K; k0 += 32) {
#pragma unroll
    for (int p = 0; p < 2; ++p) {
      int r = ar + p * 32;
      int grow = row0 + r;
      float4 v = make_float4(0.f, 0.f, 0.f, 0.f);
      if (grow < M) v = *(const float4*)(A + (size_t)grow * K + k0 + ak);
      As[ak + 0][r] = v.x; As[ak + 1][r] = v.y; As[ak + 2][r] = v.z; As[ak + 3][r] = v.w;
    }
#pragma unroll
    for (int p = 0; p < 2; ++p) {
      int kk = bk + p * 16;
      float4 v = *(const float4*)(B + (size_t)(k0 + kk) * Ncol + col0 + bc);
      *(float4*)(&Bs[kk][bc]) = v;
    }
    __syncthreads();
#pragma unroll
    for (int kk = 0; kk < 32; ++kk) {
      float4 a = *(const float4*)(&As[kk][ty * 4]);
      float4 b = *(const float4*)(&Bs[kk][tx * 4]);
      float av[4] = {a.x, a.y, a.z, a.w};
      float bv[4] = {b.x, b.y, b.z, b.w};
#pragma unroll
      for (int i = 0; i < 4; ++i)
#pragma unroll
        for (int j = 0; j < 4; ++j) acc[i][j] = fmaf(av[i], bv[j], acc[i][j]);
    }
    __syncthreads();
  }
  float bvals[4] = {0.f, 0.f, 0.f, 0.f};
  if (bias) {
#pragma unroll
    for (int j = 0; j < 4; ++j) bvals[j] = bias[col0 + tx * 4 + j];
  }
#pragma unroll
  for (int i = 0; i < 4; ++i) {
    int r = row0 + ty * 4 + i;
    if (r >= M) continue;
    float4 outv;
    float* o = (float*)&outv;
#pragma unroll
    for (int j = 0; j < 4; ++j) {
      float v = (acc[i][j] + bvals[j]) * scale;
      if (act == 1) v = fmaxf(v, 0.f);
      else if (act == 2) v = (v > 0.f) ? v : (__expf(v) - 1.f);
      o[j] = v;
    }
    *(float4*)(C + (size_t)r * Ncol + col0 + tx * 4) = outv;
  }
}

// ---------------- PASS A: edge-parallel logits (real edges only) ----------------
// one wave per edge-pair per iteration; lane l owns channels [4l,4l+4); head = l>>3.
// logits[e][h] = sum_c lrelu(xl[src,c]+xr[tgt,c]+ep[c]) * att[h, c mod 32]
__global__ __launch_bounds__(256) void logits_kernel(
    const unsigned short* __restrict__ xlr,
    const int* __restrict__ ei, const float* __restrict__ eattr,
    const float* __restrict__ We, const float* __restrict__ att,
    float* __restrict__ logits)
{
  const int lane = threadIdx.x & 63;
  const int wv = threadIdx.x >> 6;
  const int c0 = lane * 4;
  const int head = lane >> 3;

  float4 attf4 = *(const float4*)(att + c0);
  float attf[4] = {attf4.x, attf4.y, attf4.z, attf4.w};
  float wef[10][4];
#pragma unroll
  for (int k = 0; k < 10; ++k) {
    float4 w4 = *(const float4*)(We + k * 256 + c0);
    wef[k][0] = w4.x; wef[k][1] = w4.y; wef[k][2] = w4.z; wef[k][3] = w4.w;
  }

  auto edge_logit = [&](int e) {
    int src = ei[e];
    int tgt = ei[N_EDGES + e];
    const float* eap = eattr + (size_t)e * 10;
    float2 q0 = *(const float2*)(eap + 0);
    float2 q1 = *(const float2*)(eap + 2);
    float2 q2 = *(const float2*)(eap + 4);
    float2 q3 = *(const float2*)(eap + 6);
    float2 q4 = *(const float2*)(eap + 8);
    ushort4 ua = *(const ushort4*)(xlr + (size_t)src * 512 + c0);
    ushort4 ub = *(const ushort4*)(xlr + (size_t)tgt * 512 + 256 + c0);
    float ev[10] = {q0.x, q0.y, q1.x, q1.y, q2.x, q2.y, q3.x, q3.y, q4.x, q4.y};
    float p0 = 0.f, p1 = 0.f, p2 = 0.f, p3 = 0.f;
#pragma unroll
    for (int k = 0; k < 10; ++k) {
      p0 = fmaf(ev[k], wef[k][0], p0);
      p1 = fmaf(ev[k], wef[k][1], p1);
      p2 = fmaf(ev[k], wef[k][2], p2);
      p3 = fmaf(ev[k], wef[k][3], p3);
    }
    float s0 = bf2f(ua.x) + bf2f(ub.x) + p0;
    float s1 = bf2f(ua.y) + bf2f(ub.y) + p1;
    float s2 = bf2f(ua.z) + bf2f(ub.z) + p2;
    float s3 = bf2f(ua.w) + bf2f(ub.w) + p3;
    s0 = (s0 > 0.f) ? s0 : 0.2f * s0;
    s1 = (s1 > 0.f) ? s1 : 0.2f * s1;
    s2 = (s2 > 0.f) ? s2 : 0.2f * s2;
    s3 = (s3 > 0.f) ? s3 : 0.2f * s3;
    float part = s0 * attf[0] + s1 * attf[1] + s2 * attf[2] + s3 * attf[3];
    part += __shfl_xor(part, 1);
    part += __shfl_xor(part, 2);
    part += __shfl_xor(part, 4);
    if ((lane & 7) == 0) logits[(size_t)e * 8 + head] = part;
  };

  const int nw = gridDim.x * 4;                 // waves in grid
  const int e0 = (blockIdx.x * 4 + wv) * 2;     // contiguous pair per wave
  for (int e = e0; e < N_EDGES; e += nw * 2) {
    edge_logit(e);
    if (e + 1 < N_EDGES) edge_logit(e + 1);
  }
}

// ---------------- PASS B: node-parallel softmax + aggregate + BN/ELU/residual ----------------
// one wave per node; lane l owns channels [4l,4l+4); head = l>>3.
// Self-loop handled analytically via ep_self; loop2 iterations are independent
// (no online rescale) so multiple gathers stay in flight.
__global__ __launch_bounds__(256) void attn_kernel(
    const unsigned short* __restrict__ xlr,
    float* __restrict__ h, unsigned short* __restrict__ hb,
    const int* __restrict__ ei, const float* __restrict__ logits,
    const float* __restrict__ att, const float* __restrict__ bgat,
    const float* __restrict__ ep_self,
    const int* __restrict__ rowptr, const int* __restrict__ csr)
{
  const int lane = threadIdx.x & 63;
  const int wv = threadIdx.x >> 6;
  const int n = blockIdx.x * 4 + wv;
  if (n >= N_NODES) return;
  const int c0 = lane * 4;
  const int head = lane >> 3;

  const int s = rowptr[n], e = rowptr[n + 1];

  ushort4 ul = *(const ushort4*)(xlr + (size_t)n * 512 + c0);        // xl[n]
  ushort4 ur = *(const ushort4*)(xlr + (size_t)n * 512 + 256 + c0);  // xr[n]
  float4 hold = *(const float4*)(h + (size_t)n * HIDDEN + c0);
  float4 attf = *(const float4*)(att + c0);
  float4 eps = *(const float4*)(ep_self + c0);

  float xln[4] = {bf2f(ul.x), bf2f(ul.y), bf2f(ul.z), bf2f(ul.w)};

  // self-loop logit
  float lself;
  {
    float s0 = xln[0] + bf2f(ur.x) + eps.x;
    float s1 = xln[1] + bf2f(ur.y) + eps.y;
    float s2 = xln[2] + bf2f(ur.z) + eps.z;
    float s3 = xln[3] + bf2f(ur.w) + eps.w;
    s0 = (s0 > 0.f) ? s0 : 0.2f * s0;
    s1 = (s1 > 0.f) ? s1 : 0.2f * s1;
    s2 = (s2 > 0.f) ? s2 : 0.2f * s2;
    s3 = (s3 > 0.f) ? s3 : 0.2f * s3;
    float part = s0 * attf.x + s1 * attf.y + s2 * attf.z + s3 * attf.w;
    part += __shfl_xor(part, 1);
    part += __shfl_xor(part, 2);
    part += __shfl_xor(part, 4);
    lself = part;
  }

  // loop1: max over real in-edge logits (clamped duplicates are free for max)
  float m = lself;
  const int elast = e - 1;
  for (int idx = s; idx < e; idx += 4) {
    int i1 = idx + 1, i2 = idx + 2, i3 = idx + 3;
    int eid0 = csr[idx];
    int eid1 = csr[(i1 <= elast) ? i1 : elast];
    int eid2 = csr[(i2 <= elast) ? i2 : elast];
    int eid3 = csr[(i3 <= elast) ? i3 : elast];
    float l0 = logits[(size_t)eid0 * 8 + head];
    float l1 = logits[(size_t)eid1 * 8 + head];
    float l2 = logits[(size_t)eid2 * 8 + head];
    float l3 = logits[(size_t)eid3 * 8 + head];
    m = fmaxf(fmaxf(m, fmaxf(l0, l1)), fmaxf(l2, l3));
  }

  // loop2: independent accumulate (no rescale chain)
  float wself = __expf(lself - m);
  float d = wself;
  float a0 = wself * xln[0], a1 = wself * xln[1], a2 = wself * xln[2], a3 = wself * xln[3];
  for (int idx = s; idx < e; idx += 2) {
    int i1 = idx + 1;
    bool v1 = (i1 <= elast);
    int eid0 = csr[idx];
    int eid1 = csr[v1 ? i1 : elast];
    float l0 = logits[(size_t)eid0 * 8 + head];
    float l1 = logits[(size_t)eid1 * 8 + head];
    int s0 = ei[eid0];
    int s1 = ei[eid1];
    float w0 = __expf(l0 - m);
    float w1 = v1 ? __expf(l1 - m) : 0.f;
    ushort4 u0 = *(const ushort4*)(xlr + (size_t)s0 * 512 + c0);
    ushort4 u1 = *(const ushort4*)(xlr + (size_t)s1 * 512 + c0);
    d += w0 + w1;
    a0 += w0 * bf2f(u0.x) + w1 * bf2f(u1.x);
    a1 += w0 * bf2f(u0.y) + w1 * bf2f(u1.y);
    a2 += w0 * bf2f(u0.z) + w1 * bf2f(u1.z);
    a3 += w0 * bf2f(u0.w) + w1 * bf2f(u1.w);
  }

  float inv = 1.f / (d + 1e-16f);
  float4 bg = *(const float4*)(bgat + c0);
  float ov[4] = {a0 * inv, a1 * inv, a2 * inv, a3 * inv};
  float bgv[4] = {bg.x, bg.y, bg.z, bg.w};
  float hv[4] = {hold.x, hold.y, hold.z, hold.w};
  float4 res;
  float* rp = (float*)&res;
  ushort4 resb;
  unsigned short* rb = (unsigned short*)&resb;
#pragma unroll
  for (int j = 0; j < 4; ++j) {
    float v = (ov[j] + bgv[j]) * BN_S;
    v = (v > 0.f) ? v : (__expf(v) - 1.f);
    float nv = v + hv[j];
    rp[j] = nv;
    rb[j] = f2bf(nv);
  }
  *(float4*)(h + (size_t)n * HIDDEN + c0) = res;
  *(ushort4*)(hb + (size_t)n * HIDDEN + c0) = resb;
}

// ---------------- global attention pooling per graph ----------------
__global__ __launch_bounds__(64) void pool_kernel(
    const float* __restrict__ gate, const float* __restrict__ h,
    const int* __restrict__ brp, float* __restrict__ pooled)
{
  int b = blockIdx.x;
  int lane = threadIdx.x;
  int s = brp[b], e = brp[b + 1];
  float m = -__builtin_inff();
  for (int i = s + lane; i < e; i += 64) m = fmaxf(m, gate[i]);
#pragma unroll
  for (int o = 1; o < 64; o <<= 1) m = fmaxf(m, __shfl_xor(m, o));
  float d = 0.f;
  for (int i = s + lane; i < e; i += 64) d += __expf(gate[i] - m);
#pragma unroll
  for (int o = 1; o < 64; o <<= 1) d += __shfl_xor(d, o);
  float inv = 1.f / (d + 1e-16f);
  int c0 = lane * 4;
  float acc[4] = {0.f, 0.f, 0.f, 0.f};
  for (int i = s; i < e; ++i) {
    float w = __expf(gate[i] - m) * inv;
    float4 hv = *(const float4*)(h + (size_t)i * HIDDEN + c0);
    acc[0] = fmaf(w, hv.x, acc[0]);
    acc[1] = fmaf(w, hv.y, acc[1]);
    acc[2] = fmaf(w, hv.z, acc[2]);
    acc[3] = fmaf(w, hv.w, acc[3]);
  }
  float4 outv = make_float4(acc[0], acc[1], acc[2], acc[3]);
  *(float4*)(pooled + (size_t)b * HIDDEN + c0) = outv;
}

// ---------------- final: out[b] = r3[b,:] . W4 + b4 ----------------
__global__ __launch_bounds__(256) void out_kernel(
    const float* __restrict__ r3, const float* __restrict__ W4,
    const float* __restrict__ b4, float* __restrict__ out)
{
  int lane = threadIdx.x & 63;
  int wv = threadIdx.x >> 6;
  int b = blockIdx.x * 4 + wv;
  if (b >= N_B) return;
  float v = r3[(size_t)b * 64 + lane] * W4[lane];
#pragma unroll
  for (int o = 1; o < 64; o <<= 1) v += __shfl_xor(v, o);
  if (lane == 0) out[b] = v + b4[0];
}

extern "C" void kernel_launch(void* const* d_in, const int* in_sizes, int n_in,
                              void* d_out, int out_size, void* d_ws, size_t ws_size,
                              hipStream_t stream)
{
  const float* x    = (const float*)d_in[0];
  const int* ei     = (const int*)d_in[1];
  const float* ea   = (const float*)d_in[2];
  const int* batch  = (const int*)d_in[3];
  const float* W_in = (const float*)d_in[4];
  const float* b_in = (const float*)d_in[5];
  const float* Wl   = (const float*)d_in[6];
  const float* Wr   = (const float*)d_in[7];
  const float* We   = (const float*)d_in[8];
  const float* att  = (const float*)d_in[9];
  const float* bgat = (const float*)d_in[10];
  const float* Wg1  = (const float*)d_in[11];
  const float* bg1  = (const float*)d_in[12];
  const float* Wg2  = (const float*)d_in[13];
  const float* bg2  = (const float*)d_in[14];
  const float* W1   = (const float*)d_in[15];
  const float* b1   = (const float*)d_in[16];
  const float* W2   = (const float*)d_in[17];
  const float* b2   = (const float*)d_in[18];
  const float* W3   = (const float*)d_in[19];
  const float* b3   = (const float*)d_in[20];
  const float* W4   = (const float*)d_in[21];
  const float* b4   = (const float*)d_in[22];
  float* out = (float*)d_out;

  char* ws = (char*)d_ws;
  size_t off = 0;
  auto alloc = [&](size_t bytes) -> char* {
    char* p = ws + off;
    off += (bytes + 255) & ~(size_t)255;
    return p;
  };
  float* h            = (float*)alloc((size_t)N_NODES * HIDDEN * 4);           // 102.4 MB
  unsigned short* hb  = (unsigned short*)alloc((size_t)N_NODES * HIDDEN * 2);  // 51.2 MB
  unsigned short* xlr = (unsigned short*)alloc((size_t)N_NODES * 512 * 2);     // 102.4 MB
  int* deg       = (int*)alloc((size_t)N_NODES * 4);
  int* rowptr    = (int*)alloc((size_t)(N_NODES + 1) * 4);
  int* cursor    = (int*)alloc((size_t)N_NODES * 4);
  int* csr       = (int*)alloc((size_t)N_EDGES * 4);       // real edges only
  int* brp       = (int*)alloc((size_t)(N_B + 1) * 4);
  int* bsum      = (int*)alloc(512);
  float* macc    = (float*)alloc(64);
  float* meanattr= (float*)alloc(64);
  float* ep_self = (float*)alloc(4 * 256 * 4);
  float* logits  = (float*)alloc((size_t)N_EDGES * 8 * 4); // 7.04 MB
  unsigned short* Wint  = (unsigned short*)alloc(256 * 96 * 2);       // [256][96]
  unsigned short* Wlrt  = (unsigned short*)alloc(4 * 512 * 256 * 2);  // [i][512][256] = Wl^T || Wr^T
  unsigned short* Wg1t  = (unsigned short*)alloc(128 * 256 * 2);      // [128][256]
  // total ≈ 266.3 MB < 268.4 MB ws  ✓

  // aliases into dead regions of xlr:
  unsigned short* xpad = xlr;            // [N,96] bf16, pre-layer0 only
  float* base2  = (float*)xlr;           // xlr fully dead after last attn layer
  float* gate   = base2;                 // [N] f32
  float* pooled = base2 + 1000000;       // [B,256] f32
  float* r1     = base2 + 3000000;       // [B,256] f32
  float* r2     = base2 + 5000000;       // [B,128] f32
  float* r3     = base2 + 6000000;       // [B,64]  f32

  if (ws_size < off) {
    hipMemsetAsync(d_out, 0, (size_t)out_size * 4, stream);
    return;
  }

  zero_kernel<<<391, 256, 0, stream>>>(deg, cursor, macc);
  mean_kernel<<<256, 256, 0, stream>>>(ea, macc);
  meanattr_kernel<<<1, 64, 0, stream>>>(macc, meanattr);
  epself_kernel<<<4, 256, 0, stream>>>(meanattr, We, ep_self);
  count_kernel<<<860, 256, 0, stream>>>(ei, deg);
  scan1_kernel<<<NSCANB, 1024, 0, stream>>>(deg, rowptr, bsum);
  scan2_kernel<<<1, 128, 0, stream>>>(bsum);
  scan3_kernel<<<NSCANB, 1024, 0, stream>>>(rowptr, bsum);
  scatter_kernel<<<860, 256, 0, stream>>>(ei, rowptr, cursor, csr);
  brp_kernel<<<512, 256, 0, stream>>>(batch, brp);

  // weight conversions (transpose + bf16)
  wt_kernel<<<(256 * 96 + 255) / 256, 256, 0, stream>>>(W_in, Wint, 75, 96, 256);
  wlr_kernel<<<512, 256, 0, stream>>>(Wl, Wr, Wlrt);
  wt_kernel<<<128, 256, 0, stream>>>(Wg1, Wg1t, 256, 256, 128);
  convx_kernel<<<4096, 256, 0, stream>>>(x, xpad);

  // input projection: h = elu((x @ W_in + b_in) * BN_S)  [MFMA, K=96]
  gemm_mfma<<<dim3(2, 782), 256, 0, stream>>>(xpad, Wint, b_in, h, hb,
                                              N_NODES, 256, 96, 2, BN_S);

  for (int i = 0; i < 4; ++i) {
    // fused xl||xr GEMM: [N,256] @ [256,512] -> xlr [N,512]
    gemm_mfma<<<dim3(4, 782), 256, 0, stream>>>(hb, Wlrt + (size_t)i * 131072, nullptr,
                                                nullptr, xlr, N_NODES, 512, 256, 0, 1.f);
    // pass A: edge-parallel logits
    logits_kernel<<<2048, 256, 0, stream>>>(xlr, ei, ea, We + (size_t)i * 2560,
                                            att + (size_t)i * 256, logits);
    // pass B: node-parallel softmax + aggregate
    attn_kernel<<<25000, 256, 0, stream>>>(xlr, h, hb, ei, logits,
                                           att + (size_t)i * 256, bgat + (size_t)i * 256,
                                           ep_self + (size_t)i * 256, rowptr, csr);
  }

  // fused pooling gate: gate = relu(hb @ Wg1 + bg1) . Wg2 + bg2
  gemm_gate<<<782, 256, 0, stream>>>(hb, Wg1t, bg1, Wg2, bg2, gate, N_NODES);
  pool_kernel<<<N_B, 64, 0, stream>>>(gate, h, brp, pooled);

  // readout MLP (f32, tiny)
  gemm_f32<<<dim3(4, 64), 256, 0, stream>>>(pooled, W1, b1, r1, N_B, 256, 256, 1, BN_S);
  gemm_f32<<<dim3(2, 64), 256, 0, stream>>>(r1, W2, b2, r2, N_B, 128, 256, 1, BN_S);
  gemm_f32<<<dim3(1, 64), 256, 0, stream>>>(r2, W3, b3, r3, N_B, 64, 128, 1, 1.f);
  out_kernel<<<1024, 256, 0, stream>>>(r3, W4, b4, out);
}

// Round 5
// 1400.933 us; speedup vs baseline: 1.1081x; 1.0789x over previous
//
#include <hip/hip_runtime.h>

#define N_NODES 100000
#define N_EDGES 220000
#define N_B     4096
#define HIDDEN  256
#define BN_S    0.9999950000374997f
#define LDSW    40       // LDS row stride in bf16 elems (80 B, 16B-aligned, conflict-free)
#define NSCANB  98       // ceil(100000/1024)

typedef __attribute__((ext_vector_type(8))) short bf16x8;
typedef __attribute__((ext_vector_type(4))) float f32x4;

__device__ __forceinline__ float bf2f(unsigned short u) {
  return __uint_as_float(((unsigned int)u) << 16);
}
__device__ __forceinline__ unsigned short f2bf(float f) {
  unsigned int x = __float_as_uint(f);
  unsigned int lsb = (x >> 16) & 1u;
  x += 0x7fffu + lsb;
  return (unsigned short)(x >> 16);
}

// ---------------- zero-init of counters ----------------
__global__ void zero_kernel(int* __restrict__ deg, int* __restrict__ cursor, float* __restrict__ macc) {
  int i = blockIdx.x * blockDim.x + threadIdx.x;
  if (i < N_NODES) { deg[i] = 0; cursor[i] = 0; }
  if (i < 16) macc[i] = 0.f;
}

// ---------------- mean of edge_attr ----------------
// block-level reduction, ONE atomic per k per block (64 blocks -> 640 atomics
// total vs previous 10240 same-address atomics that serialized at ~130 us).
__global__ __launch_bounds__(256) void mean_kernel(const float* __restrict__ ea, float* __restrict__ macc) {
  __shared__ float sred[4][16];
  int lane = threadIdx.x & 63;
  int wv = threadIdx.x >> 6;
  float loc[10];
#pragma unroll
  for (int k = 0; k < 10; ++k) loc[k] = 0.f;
  for (int e = blockIdx.x * blockDim.x + threadIdx.x; e < N_EDGES; e += gridDim.x * blockDim.x) {
    const float* p = ea + (size_t)e * 10;
#pragma unroll
    for (int k = 0; k < 10; ++k) loc[k] += p[k];
  }
#pragma unroll
  for (int k = 0; k < 10; ++k) {
    float v = loc[k];
#pragma unroll
    for (int o = 1; o < 64; o <<= 1) v += __shfl_xor(v, o);
    if (lane == 0) sred[wv][k] = v;
  }
  __syncthreads();
  if (threadIdx.x < 10) {
    float s = sred[0][threadIdx.x] + sred[1][threadIdx.x] +
              sred[2][threadIdx.x] + sred[3][threadIdx.x];
    atomicAdd(&macc[threadIdx.x], s);
  }
}

__global__ void meanattr_kernel(const float* __restrict__ macc, float* __restrict__ meanattr) {
  int t = threadIdx.x;
  const float invE = 1.f / (float)N_EDGES;
  if (t < 10) meanattr[t] = macc[t] * invE;
}

// ---------------- ep_self[i][c] = meanattr . We[i][:,c]  (self-loop edge projection) ----------------
__global__ void epself_kernel(const float* __restrict__ meanattr, const float* __restrict__ We,
                              float* __restrict__ ep_self) {
  int i = blockIdx.x;
  int c = threadIdx.x;
  float s = 0.f;
#pragma unroll
  for (int k = 0; k < 10; ++k)
    s += meanattr[k] * We[(size_t)i * 2560 + k * 256 + c];
  ep_self[i * 256 + c] = s;
}

// ---------------- CSR build (REAL edges only; self-loops handled analytically) ----------------
__global__ void count_kernel(const int* __restrict__ ei, int* __restrict__ deg) {
  for (int e = blockIdx.x * blockDim.x + threadIdx.x; e < N_EDGES; e += gridDim.x * blockDim.x) {
    atomicAdd(&deg[ei[N_EDGES + e]], 1);
  }
}

// ---------------- 3-phase scan ----------------
__global__ __launch_bounds__(1024) void scan1_kernel(const int* __restrict__ deg,
                                                     int* __restrict__ rowptr,
                                                     int* __restrict__ bsum) {
  __shared__ int buf[1024];
  int t = threadIdx.x;
  int i = blockIdx.x * 1024 + t;
  int v = (i < N_NODES) ? deg[i] : 0;
  buf[t] = v;
  __syncthreads();
  for (int off = 1; off < 1024; off <<= 1) {
    int add = (t >= off) ? buf[t - off] : 0;
    __syncthreads();
    buf[t] += add;
    __syncthreads();
  }
  if (i < N_NODES) rowptr[i + 1] = buf[t];
  if (t == 1023) bsum[blockIdx.x] = buf[t];
  if (i == 0) rowptr[0] = 0;
}

__global__ __launch_bounds__(128) void scan2_kernel(int* __restrict__ bsum) {
  __shared__ int buf[128];
  int t = threadIdx.x;
  int v = (t < NSCANB) ? bsum[t] : 0;
  buf[t] = v;
  __syncthreads();
  for (int off = 1; off < 128; off <<= 1) {
    int add = (t >= off) ? buf[t - off] : 0;
    __syncthreads();
    buf[t] += add;
    __syncthreads();
  }
  if (t < NSCANB) bsum[t] = buf[t];
}

__global__ __launch_bounds__(1024) void scan3_kernel(int* __restrict__ rowptr,
                                                     const int* __restrict__ bsum) {
  int b = blockIdx.x;
  if (b == 0) return;
  int i = b * 1024 + threadIdx.x;
  if (i < N_NODES) rowptr[i + 1] += bsum[b - 1];
}

__global__ void scatter_kernel(const int* __restrict__ ei, const int* __restrict__ rowptr,
                               int* __restrict__ cursor, int* __restrict__ csr) {
  for (int e = blockIdx.x * blockDim.x + threadIdx.x; e < N_EDGES; e += gridDim.x * blockDim.x) {
    int t = ei[N_EDGES + e];
    int pos = atomicAdd(&cursor[t], 1);
    csr[rowptr[t] + pos] = e;
  }
}

__global__ void brp_kernel(const int* __restrict__ batch, int* __restrict__ brp) {
  for (int i = blockIdx.x * blockDim.x + threadIdx.x; i < N_NODES; i += gridDim.x * blockDim.x) {
    int bi = batch[i];
    int bp = (i == 0) ? -1 : batch[i - 1];
    for (int b = bp + 1; b <= bi; ++b) brp[b] = i;
    if (i == N_NODES - 1) {
      for (int b = bi + 1; b <= N_B; ++b) brp[b] = N_NODES;
    }
  }
}

// ---------------- x -> padded bf16 [N,96] ----------------
__global__ void convx_kernel(const float* __restrict__ x, unsigned short* __restrict__ xp) {
  int total = N_NODES * 96;
  for (int idx = blockIdx.x * blockDim.x + threadIdx.x; idx < total; idx += gridDim.x * blockDim.x) {
    int nn = idx / 96;
    int j = idx - nn * 96;
    unsigned short v = 0;
    if (j < 75) v = f2bf(x[(size_t)nn * 75 + j]);
    xp[idx] = v;
  }
}

// ---------------- weight transpose+bf16: dst[n*Kp+k] = src[k*N+n] (0 beyond K) ----------------
__global__ void wt_kernel(const float* __restrict__ src, unsigned short* __restrict__ dst,
                          int K, int Kp, int N) {
  int idx = blockIdx.x * blockDim.x + threadIdx.x;
  int total = N * Kp;
  if (idx >= total) return;
  int n = idx / Kp, k = idx - n * Kp;
  dst[idx] = (k < K) ? f2bf(src[(size_t)k * N + n]) : (unsigned short)0;
}

// ---------------- all 4 layers Wl^T||Wr^T in one launch ----------------
__global__ void wlr_kernel(const float* __restrict__ Wl, const float* __restrict__ Wr,
                           unsigned short* __restrict__ dst) {
  const int total = 4 * 512 * 256;
  for (int idx = blockIdx.x * blockDim.x + threadIdx.x; idx < total; idx += gridDim.x * blockDim.x) {
    int i = idx >> 17;          // /131072
    int rem = idx & 131071;
    int n = rem >> 8;           // 0..511
    int k = rem & 255;
    float v = (n < 256) ? Wl[(size_t)i * 65536 + k * 256 + n]
                        : Wr[(size_t)i * 65536 + k * 256 + (n - 256)];
    dst[idx] = f2bf(v);
  }
}

// ---------------- bf16 MFMA GEMM: C = act((A @ Bt^T + bias)*scale) ----------------
__global__ __launch_bounds__(256) void gemm_mfma(
    const unsigned short* __restrict__ A, const unsigned short* __restrict__ Bt,
    const float* __restrict__ bias, float* __restrict__ Cf, unsigned short* __restrict__ Cb,
    int M, int Ncol, int K, int act, float scale)
{
  __shared__ unsigned short As[128 * LDSW];
  __shared__ unsigned short Bs[128 * LDSW];
  const int tid = threadIdx.x;
  const int wave = tid >> 6;
  const int lane = tid & 63;
  const int col0 = blockIdx.x * 128;
  const int row0 = blockIdx.y * 128;
  const int wrow = (wave >> 1) * 64;
  const int wcol = (wave & 1) * 64;
  const int lrow = lane & 15;
  const int quad = lane >> 4;

  f32x4 acc[4][4] = {};

  const int srow = tid >> 1;          // 0..127
  const int shalf = (tid & 1) * 16;   // 0 or 16 (bf16 elems)

  for (int k0 = 0; k0 < K; k0 += 32) {
    {
      int gr = row0 + srow;
      uint4 a0 = {0, 0, 0, 0}, a1 = {0, 0, 0, 0};
      if (gr < M) {
        const unsigned short* src = A + (size_t)gr * K + k0 + shalf;
        a0 = *(const uint4*)(src);
        a1 = *(const uint4*)(src + 8);
      }
      *(uint4*)(&As[srow * LDSW + shalf]) = a0;
      *(uint4*)(&As[srow * LDSW + shalf + 8]) = a1;
      const unsigned short* srcb = Bt + (size_t)(col0 + srow) * K + k0 + shalf;
      *(uint4*)(&Bs[srow * LDSW + shalf]) = *(const uint4*)(srcb);
      *(uint4*)(&Bs[srow * LDSW + shalf + 8]) = *(const uint4*)(srcb + 8);
    }
    __syncthreads();
    bf16x8 afr[4], bfr[4];
#pragma unroll
    for (int mt = 0; mt < 4; ++mt)
      afr[mt] = *(const bf16x8*)(&As[(wrow + mt * 16 + lrow) * LDSW + quad * 8]);
#pragma unroll
    for (int nt = 0; nt < 4; ++nt)
      bfr[nt] = *(const bf16x8*)(&Bs[(wcol + nt * 16 + lrow) * LDSW + quad * 8]);
#pragma unroll
    for (int mt = 0; mt < 4; ++mt)
#pragma unroll
      for (int nt = 0; nt < 4; ++nt)
        acc[mt][nt] = __builtin_amdgcn_mfma_f32_16x16x32_bf16(afr[mt], bfr[nt], acc[mt][nt], 0, 0, 0);
    __syncthreads();
  }

#pragma unroll
  for (int mt = 0; mt < 4; ++mt) {
#pragma unroll
    for (int nt = 0; nt < 4; ++nt) {
      int gcol = col0 + wcol + nt * 16 + lrow;
      float bv = bias ? bias[gcol] : 0.f;
#pragma unroll
      for (int r = 0; r < 4; ++r) {
        int grow = row0 + wrow + mt * 16 + quad * 4 + r;
        if (grow >= M) continue;
        float v = (acc[mt][nt][r] + bv) * scale;
        if (act == 1) v = fmaxf(v, 0.f);
        else if (act == 2) v = (v > 0.f) ? v : (__expf(v) - 1.f);
        if (Cf) Cf[(size_t)grow * Ncol + gcol] = v;
        if (Cb) Cb[(size_t)grow * Ncol + gcol] = f2bf(v);
      }
    }
  }
}

// ---------------- fused pooling-gate GEMM: gate = relu(hb@Wg1+bg1) . Wg2 + bg2 ----------------
__global__ __launch_bounds__(256) void gemm_gate(
    const unsigned short* __restrict__ A, const unsigned short* __restrict__ Bt,
    const float* __restrict__ bg1, const float* __restrict__ Wg2,
    const float* __restrict__ bg2, float* __restrict__ gate, int M)
{
  __shared__ unsigned short As[128 * LDSW];
  __shared__ unsigned short Bs[128 * LDSW];
  __shared__ float gbuf[128][2];
  const int tid = threadIdx.x;
  const int wave = tid >> 6;
  const int lane = tid & 63;
  const int row0 = blockIdx.x * 128;
  const int wrow = (wave >> 1) * 64;
  const int wcol = (wave & 1) * 64;
  const int lrow = lane & 15;
  const int quad = lane >> 4;

  f32x4 acc[4][4] = {};
  const int srow = tid >> 1;
  const int shalf = (tid & 1) * 16;

  for (int k0 = 0; k0 < 256; k0 += 32) {
    {
      int gr = row0 + srow;
      uint4 a0 = {0, 0, 0, 0}, a1 = {0, 0, 0, 0};
      if (gr < M) {
        const unsigned short* src = A + (size_t)gr * 256 + k0 + shalf;
        a0 = *(const uint4*)(src);
        a1 = *(const uint4*)(src + 8);
      }
      *(uint4*)(&As[srow * LDSW + shalf]) = a0;
      *(uint4*)(&As[srow * LDSW + shalf + 8]) = a1;
      const unsigned short* srcb = Bt + (size_t)srow * 256 + k0 + shalf;
      *(uint4*)(&Bs[srow * LDSW + shalf]) = *(const uint4*)(srcb);
      *(uint4*)(&Bs[srow * LDSW + shalf + 8]) = *(const uint4*)(srcb + 8);
    }
    __syncthreads();
    bf16x8 afr[4], bfr[4];
#pragma unroll
    for (int mt = 0; mt < 4; ++mt)
      afr[mt] = *(const bf16x8*)(&As[(wrow + mt * 16 + lrow) * LDSW + quad * 8]);
#pragma unroll
    for (int nt = 0; nt < 4; ++nt)
      bfr[nt] = *(const bf16x8*)(&Bs[(wcol + nt * 16 + lrow) * LDSW + quad * 8]);
#pragma unroll
    for (int mt = 0; mt < 4; ++mt)
#pragma unroll
      for (int nt = 0; nt < 4; ++nt)
        acc[mt][nt] = __builtin_amdgcn_mfma_f32_16x16x32_bf16(afr[mt], bfr[nt], acc[mt][nt], 0, 0, 0);
    __syncthreads();
  }

  float p[4][4];
#pragma unroll
  for (int mt = 0; mt < 4; ++mt)
#pragma unroll
    for (int r = 0; r < 4; ++r) p[mt][r] = 0.f;
#pragma unroll
  for (int nt = 0; nt < 4; ++nt) {
    int gcol = wcol + nt * 16 + lrow;
    float b1v = bg1[gcol];
    float w2v = Wg2[gcol];
#pragma unroll
    for (int mt = 0; mt < 4; ++mt)
#pragma unroll
      for (int r = 0; r < 4; ++r) {
        float v = fmaxf(acc[mt][nt][r] + b1v, 0.f);
        p[mt][r] = fmaf(v, w2v, p[mt][r]);
      }
  }
#pragma unroll
  for (int mt = 0; mt < 4; ++mt)
#pragma unroll
    for (int r = 0; r < 4; ++r) {
      float v = p[mt][r];
      v += __shfl_xor(v, 1);
      v += __shfl_xor(v, 2);
      v += __shfl_xor(v, 4);
      v += __shfl_xor(v, 8);
      if (lrow == 0) gbuf[wrow + mt * 16 + quad * 4 + r][wcol >> 6] = v;
    }
  __syncthreads();
  if (tid < 128) {
    int grow = row0 + tid;
    if (grow < M) gate[grow] = gbuf[tid][0] + gbuf[tid][1] + bg2[0];
  }
}

// ---------------- f32 GEMM for the tiny readout layers ----------------
__global__ __launch_bounds__(256) void gemm_f32(
    const float* __restrict__ A, const float* __restrict__ B,
    const float* __restrict__ bias, float* __restrict__ C,
    int M, int Ncol, int K, int act, float scale)
{
  __shared__ float As[32][68];
  __shared__ float Bs[32][68];
  const int tid = threadIdx.x;
  const int tx = tid & 15, ty = tid >> 4;
  const int col0 = blockIdx.x * 64;
  const int row0 = blockIdx.y * 64;
  float acc[4][4];
#pragma unroll
  for (int i = 0; i < 4; ++i)
#pragma unroll
    for (int j = 0; j < 4; ++j) acc[i][j] = 0.f;

  const int ar = tid >> 3;
  const int ak = (tid & 7) * 4;
  const int bk = tid >> 4;
  const int bc = (tid & 15) * 4;

  for (int k0 = 0; k0 < K; k0 += 32) {
#pragma unroll
    for (int p = 0; p < 2; ++p) {
      int r = ar + p * 32;
      int grow = row0 + r;
      float4 v = make_float4(0.f, 0.f, 0.f, 0.f);
      if (grow < M) v = *(const float4*)(A + (size_t)grow * K + k0 + ak);
      As[ak + 0][r] = v.x; As[ak + 1][r] = v.y; As[ak + 2][r] = v.z; As[ak + 3][r] = v.w;
    }
#pragma unroll
    for (int p = 0; p < 2; ++p) {
      int kk = bk + p * 16;
      float4 v = *(const float4*)(B + (size_t)(k0 + kk) * Ncol + col0 + bc);
      *(float4*)(&Bs[kk][bc]) = v;
    }
    __syncthreads();
#pragma unroll
    for (int kk = 0; kk < 32; ++kk) {
      float4 a = *(const float4*)(&As[kk][ty * 4]);
      float4 b = *(const float4*)(&Bs[kk][tx * 4]);
      float av[4] = {a.x, a.y, a.z, a.w};
      float bv[4] = {b.x, b.y, b.z, b.w};
#pragma unroll
      for (int i = 0; i < 4; ++i)
#pragma unroll
        for (int j = 0; j < 4; ++j) acc[i][j] = fmaf(av[i], bv[j], acc[i][j]);
    }
    __syncthreads();
  }
  float bvals[4] = {0.f, 0.f, 0.f, 0.f};
  if (bias) {
#pragma unroll
    for (int j = 0; j < 4; ++j) bvals[j] = bias[col0 + tx * 4 + j];
  }
#pragma unroll
  for (int i = 0; i < 4; ++i) {
    int r = row0 + ty * 4 + i;
    if (r >= M) continue;
    float4 outv;
    float* o = (float*)&outv;
#pragma unroll
    for (int j = 0; j < 4; ++j) {
      float v = (acc[i][j] + bvals[j]) * scale;
      if (act == 1) v = fmaxf(v, 0.f);
      else if (act == 2) v = (v > 0.f) ? v : (__expf(v) - 1.f);
      o[j] = v;
    }
    *(float4*)(C + (size_t)r * Ncol + col0 + tx * 4) = outv;
  }
}

// ---------------- PASS A: edge-parallel logits (real edges only) ----------------
__global__ __launch_bounds__(256) void logits_kernel(
    const unsigned short* __restrict__ xlr,
    const int* __restrict__ ei, const float* __restrict__ eattr,
    const float* __restrict__ We, const float* __restrict__ att,
    float* __restrict__ logits)
{
  const int lane = threadIdx.x & 63;
  const int wv = threadIdx.x >> 6;
  const int c0 = lane * 4;
  const int head = lane >> 3;

  float4 attf4 = *(const float4*)(att + c0);
  float attf[4] = {attf4.x, attf4.y, attf4.z, attf4.w};
  float wef[10][4];
#pragma unroll
  for (int k = 0; k < 10; ++k) {
    float4 w4 = *(const float4*)(We + k * 256 + c0);
    wef[k][0] = w4.x; wef[k][1] = w4.y; wef[k][2] = w4.z; wef[k][3] = w4.w;
  }

  auto edge_logit = [&](int e) {
    int src = ei[e];
    int tgt = ei[N_EDGES + e];
    const float* eap = eattr + (size_t)e * 10;
    float2 q0 = *(const float2*)(eap + 0);
    float2 q1 = *(const float2*)(eap + 2);
    float2 q2 = *(const float2*)(eap + 4);
    float2 q3 = *(const float2*)(eap + 6);
    float2 q4 = *(const float2*)(eap + 8);
    ushort4 ua = *(const ushort4*)(xlr + (size_t)src * 512 + c0);
    ushort4 ub = *(const ushort4*)(xlr + (size_t)tgt * 512 + 256 + c0);
    float ev[10] = {q0.x, q0.y, q1.x, q1.y, q2.x, q2.y, q3.x, q3.y, q4.x, q4.y};
    float p0 = 0.f, p1 = 0.f, p2 = 0.f, p3 = 0.f;
#pragma unroll
    for (int k = 0; k < 10; ++k) {
      p0 = fmaf(ev[k], wef[k][0], p0);
      p1 = fmaf(ev[k], wef[k][1], p1);
      p2 = fmaf(ev[k], wef[k][2], p2);
      p3 = fmaf(ev[k], wef[k][3], p3);
    }
    float s0 = bf2f(ua.x) + bf2f(ub.x) + p0;
    float s1 = bf2f(ua.y) + bf2f(ub.y) + p1;
    float s2 = bf2f(ua.z) + bf2f(ub.z) + p2;
    float s3 = bf2f(ua.w) + bf2f(ub.w) + p3;
    s0 = (s0 > 0.f) ? s0 : 0.2f * s0;
    s1 = (s1 > 0.f) ? s1 : 0.2f * s1;
    s2 = (s2 > 0.f) ? s2 : 0.2f * s2;
    s3 = (s3 > 0.f) ? s3 : 0.2f * s3;
    float part = s0 * attf[0] + s1 * attf[1] + s2 * attf[2] + s3 * attf[3];
    part += __shfl_xor(part, 1);
    part += __shfl_xor(part, 2);
    part += __shfl_xor(part, 4);
    if ((lane & 7) == 0) logits[(size_t)e * 8 + head] = part;
  };

  const int nw = gridDim.x * 4;                 // waves in grid
  const int e0 = (blockIdx.x * 4 + wv) * 2;     // contiguous pair per wave
  for (int e = e0; e < N_EDGES; e += nw * 2) {
    edge_logit(e);
    if (e + 1 < N_EDGES) edge_logit(e + 1);
  }
}

// ---------------- PASS B: node-parallel softmax + aggregate + BN/ELU/residual ----------------
__global__ __launch_bounds__(256) void attn_kernel(
    const unsigned short* __restrict__ xlr,
    float* __restrict__ h, unsigned short* __restrict__ hb,
    const int* __restrict__ ei, const float* __restrict__ logits,
    const float* __restrict__ att, const float* __restrict__ bgat,
    const float* __restrict__ ep_self,
    const int* __restrict__ rowptr, const int* __restrict__ csr)
{
  const int lane = threadIdx.x & 63;
  const int wv = threadIdx.x >> 6;
  const int n = blockIdx.x * 4 + wv;
  if (n >= N_NODES) return;
  const int c0 = lane * 4;
  const int head = lane >> 3;

  const int s = rowptr[n], e = rowptr[n + 1];

  ushort4 ul = *(const ushort4*)(xlr + (size_t)n * 512 + c0);        // xl[n]
  ushort4 ur = *(const ushort4*)(xlr + (size_t)n * 512 + 256 + c0);  // xr[n]
  float4 hold = *(const float4*)(h + (size_t)n * HIDDEN + c0);
  float4 attf = *(const float4*)(att + c0);
  float4 eps = *(const float4*)(ep_self + c0);

  float xln[4] = {bf2f(ul.x), bf2f(ul.y), bf2f(ul.z), bf2f(ul.w)};

  // self-loop logit
  float lself;
  {
    float s0 = xln[0] + bf2f(ur.x) + eps.x;
    float s1 = xln[1] + bf2f(ur.y) + eps.y;
    float s2 = xln[2] + bf2f(ur.z) + eps.z;
    float s3 = xln[3] + bf2f(ur.w) + eps.w;
    s0 = (s0 > 0.f) ? s0 : 0.2f * s0;
    s1 = (s1 > 0.f) ? s1 : 0.2f * s1;
    s2 = (s2 > 0.f) ? s2 : 0.2f * s2;
    s3 = (s3 > 0.f) ? s3 : 0.2f * s3;
    float part = s0 * attf.x + s1 * attf.y + s2 * attf.z + s3 * attf.w;
    part += __shfl_xor(part, 1);
    part += __shfl_xor(part, 2);
    part += __shfl_xor(part, 4);
    lself = part;
  }

  // loop1: max over real in-edge logits (clamped duplicates are free for max)
  float m = lself;
  const int elast = e - 1;
  for (int idx = s; idx < e; idx += 4) {
    int i1 = idx + 1, i2 = idx + 2, i3 = idx + 3;
    int eid0 = csr[idx];
    int eid1 = csr[(i1 <= elast) ? i1 : elast];
    int eid2 = csr[(i2 <= elast) ? i2 : elast];
    int eid3 = csr[(i3 <= elast) ? i3 : elast];
    float l0 = logits[(size_t)eid0 * 8 + head];
    float l1 = logits[(size_t)eid1 * 8 + head];
    float l2 = logits[(size_t)eid2 * 8 + head];
    float l3 = logits[(size_t)eid3 * 8 + head];
    m = fmaxf(fmaxf(m, fmaxf(l0, l1)), fmaxf(l2, l3));
  }

  // loop2: independent accumulate (no rescale chain)
  float wself = __expf(lself - m);
  float d = wself;
  float a0 = wself * xln[0], a1 = wself * xln[1], a2 = wself * xln[2], a3 = wself * xln[3];
  for (int idx = s; idx < e; idx += 2) {
    int i1 = idx + 1;
    bool v1 = (i1 <= elast);
    int eid0 = csr[idx];
    int eid1 = csr[v1 ? i1 : elast];
    float l0 = logits[(size_t)eid0 * 8 + head];
    float l1 = logits[(size_t)eid1 * 8 + head];
    int s0 = ei[eid0];
    int s1 = ei[eid1];
    float w0 = __expf(l0 - m);
    float w1 = v1 ? __expf(l1 - m) : 0.f;
    ushort4 u0 = *(const ushort4*)(xlr + (size_t)s0 * 512 + c0);
    ushort4 u1 = *(const ushort4*)(xlr + (size_t)s1 * 512 + c0);
    d += w0 + w1;
    a0 += w0 * bf2f(u0.x) + w1 * bf2f(u1.x);
    a1 += w0 * bf2f(u0.y) + w1 * bf2f(u1.y);
    a2 += w0 * bf2f(u0.z) + w1 * bf2f(u1.z);
    a3 += w0 * bf2f(u0.w) + w1 * bf2f(u1.w);
  }

  float inv = 1.f / (d + 1e-16f);
  float4 bg = *(const float4*)(bgat + c0);
  float ov[4] = {a0 * inv, a1 * inv, a2 * inv, a3 * inv};
  float bgv[4] = {bg.x, bg.y, bg.z, bg.w};
  float hv[4] = {hold.x, hold.y, hold.z, hold.w};
  float4 res;
  float* rp = (float*)&res;
  ushort4 resb;
  unsigned short* rb = (unsigned short*)&resb;
#pragma unroll
  for (int j = 0; j < 4; ++j) {
    float v = (ov[j] + bgv[j]) * BN_S;
    v = (v > 0.f) ? v : (__expf(v) - 1.f);
    float nv = v + hv[j];
    rp[j] = nv;
    rb[j] = f2bf(nv);
  }
  *(float4*)(h + (size_t)n * HIDDEN + c0) = res;
  *(ushort4*)(hb + (size_t)n * HIDDEN + c0) = resb;
}

// ---------------- global attention pooling per graph ----------------
__global__ __launch_bounds__(64) void pool_kernel(
    const float* __restrict__ gate, const float* __restrict__ h,
    const int* __restrict__ brp, float* __restrict__ pooled)
{
  int b = blockIdx.x;
  int lane = threadIdx.x;
  int s = brp[b], e = brp[b + 1];
  float m = -__builtin_inff();
  for (int i = s + lane; i < e; i += 64) m = fmaxf(m, gate[i]);
#pragma unroll
  for (int o = 1; o < 64; o <<= 1) m = fmaxf(m, __shfl_xor(m, o));
  float d = 0.f;
  for (int i = s + lane; i < e; i += 64) d += __expf(gate[i] - m);
#pragma unroll
  for (int o = 1; o < 64; o <<= 1) d += __shfl_xor(d, o);
  float inv = 1.f / (d + 1e-16f);
  int c0 = lane * 4;
  float acc[4] = {0.f, 0.f, 0.f, 0.f};
  for (int i = s; i < e; ++i) {
    float w = __expf(gate[i] - m) * inv;
    float4 hv = *(const float4*)(h + (size_t)i * HIDDEN + c0);
    acc[0] = fmaf(w, hv.x, acc[0]);
    acc[1] = fmaf(w, hv.y, acc[1]);
    acc[2] = fmaf(w, hv.z, acc[2]);
    acc[3] = fmaf(w, hv.w, acc[3]);
  }
  float4 outv = make_float4(acc[0], acc[1], acc[2], acc[3]);
  *(float4*)(pooled + (size_t)b * HIDDEN + c0) = outv;
}

// ---------------- final: out[b] = r3[b,:] . W4 + b4 ----------------
__global__ __launch_bounds__(256) void out_kernel(
    const float* __restrict__ r3, const float* __restrict__ W4,
    const float* __restrict__ b4, float* __restrict__ out)
{
  int lane = threadIdx.x & 63;
  int wv = threadIdx.x >> 6;
  int b = blockIdx.x * 4 + wv;
  if (b >= N_B) return;
  float v = r3[(size_t)b * 64 + lane] * W4[lane];
#pragma unroll
  for (int o = 1; o < 64; o <<= 1) v += __shfl_xor(v, o);
  if (lane == 0) out[b] = v + b4[0];
}

extern "C" void kernel_launch(void* const* d_in, const int* in_sizes, int n_in,
                              void* d_out, int out_size, void* d_ws, size_t ws_size,
                              hipStream_t stream)
{
  const float* x    = (const float*)d_in[0];
  const int* ei     = (const int*)d_in[1];
  const float* ea   = (const float*)d_in[2];
  const int* batch  = (const int*)d_in[3];
  const float* W_in = (const float*)d_in[4];
  const float* b_in = (const float*)d_in[5];
  const float* Wl   = (const float*)d_in[6];
  const float* Wr   = (const float*)d_in[7];
  const float* We   = (const float*)d_in[8];
  const float* att  = (const float*)d_in[9];
  const float* bgat = (const float*)d_in[10];
  const float* Wg1  = (const float*)d_in[11];
  const float* bg1  = (const float*)d_in[12];
  const float* Wg2  = (const float*)d_in[13];
  const float* bg2  = (const float*)d_in[14];
  const float* W1   = (const float*)d_in[15];
  const float* b1   = (const float*)d_in[16];
  const float* W2   = (const float*)d_in[17];
  const float* b2   = (const float*)d_in[18];
  const float* W3   = (const float*)d_in[19];
  const float* b3   = (const float*)d_in[20];
  const float* W4   = (const float*)d_in[21];
  const float* b4   = (const float*)d_in[22];
  float* out = (float*)d_out;

  char* ws = (char*)d_ws;
  size_t off = 0;
  auto alloc = [&](size_t bytes) -> char* {
    char* p = ws + off;
    off += (bytes + 255) & ~(size_t)255;
    return p;
  };
  float* h            = (float*)alloc((size_t)N_NODES * HIDDEN * 4);           // 102.4 MB
  unsigned short* hb  = (unsigned short*)alloc((size_t)N_NODES * HIDDEN * 2);  // 51.2 MB
  unsigned short* xlr = (unsigned short*)alloc((size_t)N_NODES * 512 * 2);     // 102.4 MB
  int* deg       = (int*)alloc((size_t)N_NODES * 4);
  int* rowptr    = (int*)alloc((size_t)(N_NODES + 1) * 4);
  int* cursor    = (int*)alloc((size_t)N_NODES * 4);
  int* csr       = (int*)alloc((size_t)N_EDGES * 4);       // real edges only
  int* brp       = (int*)alloc((size_t)(N_B + 1) * 4);
  int* bsum      = (int*)alloc(512);
  float* macc    = (float*)alloc(64);
  float* meanattr= (float*)alloc(64);
  float* ep_self = (float*)alloc(4 * 256 * 4);
  float* logits  = (float*)alloc((size_t)N_EDGES * 8 * 4); // 7.04 MB
  unsigned short* Wint  = (unsigned short*)alloc(256 * 96 * 2);       // [256][96]
  unsigned short* Wlrt  = (unsigned short*)alloc(4 * 512 * 256 * 2);  // [i][512][256] = Wl^T || Wr^T
  unsigned short* Wg1t  = (unsigned short*)alloc(128 * 256 * 2);      // [128][256]
  // total ≈ 266.3 MB < 268.4 MB ws  ✓

  // aliases into dead regions of xlr:
  unsigned short* xpad = xlr;            // [N,96] bf16, pre-layer0 only
  float* base2  = (float*)xlr;           // xlr fully dead after last attn layer
  float* gate   = base2;                 // [N] f32
  float* pooled = base2 + 1000000;       // [B,256] f32
  float* r1     = base2 + 3000000;       // [B,256] f32
  float* r2     = base2 + 5000000;       // [B,128] f32
  float* r3     = base2 + 6000000;       // [B,64]  f32

  if (ws_size < off) {
    hipMemsetAsync(d_out, 0, (size_t)out_size * 4, stream);
    return;
  }

  zero_kernel<<<391, 256, 0, stream>>>(deg, cursor, macc);
  mean_kernel<<<64, 256, 0, stream>>>(ea, macc);
  meanattr_kernel<<<1, 64, 0, stream>>>(macc, meanattr);
  epself_kernel<<<4, 256, 0, stream>>>(meanattr, We, ep_self);
  count_kernel<<<860, 256, 0, stream>>>(ei, deg);
  scan1_kernel<<<NSCANB, 1024, 0, stream>>>(deg, rowptr, bsum);
  scan2_kernel<<<1, 128, 0, stream>>>(bsum);
  scan3_kernel<<<NSCANB, 1024, 0, stream>>>(rowptr, bsum);
  scatter_kernel<<<860, 256, 0, stream>>>(ei, rowptr, cursor, csr);
  brp_kernel<<<512, 256, 0, stream>>>(batch, brp);

  // weight conversions (transpose + bf16)
  wt_kernel<<<(256 * 96 + 255) / 256, 256, 0, stream>>>(W_in, Wint, 75, 96, 256);
  wlr_kernel<<<512, 256, 0, stream>>>(Wl, Wr, Wlrt);
  wt_kernel<<<128, 256, 0, stream>>>(Wg1, Wg1t, 256, 256, 128);
  convx_kernel<<<4096, 256, 0, stream>>>(x, xpad);

  // input projection: h = elu((x @ W_in + b_in) * BN_S)  [MFMA, K=96]
  gemm_mfma<<<dim3(2, 782), 256, 0, stream>>>(xpad, Wint, b_in, h, hb,
                                              N_NODES, 256, 96, 2, BN_S);

  for (int i = 0; i < 4; ++i) {
    // fused xl||xr GEMM: [N,256] @ [256,512] -> xlr [N,512]
    gemm_mfma<<<dim3(4, 782), 256, 0, stream>>>(hb, Wlrt + (size_t)i * 131072, nullptr,
                                                nullptr, xlr, N_NODES, 512, 256, 0, 1.f);
    // pass A: edge-parallel logits
    logits_kernel<<<2048, 256, 0, stream>>>(xlr, ei, ea, We + (size_t)i * 2560,
                                            att + (size_t)i * 256, logits);
    // pass B: node-parallel softmax + aggregate
    attn_kernel<<<25000, 256, 0, stream>>>(xlr, h, hb, ei, logits,
                                           att + (size_t)i * 256, bgat + (size_t)i * 256,
                                           ep_self + (size_t)i * 256, rowptr, csr);
  }

  // fused pooling gate: gate = relu(hb @ Wg1 + bg1) . Wg2 + bg2
  gemm_gate<<<782, 256, 0, stream>>>(hb, Wg1t, bg1, Wg2, bg2, gate, N_NODES);
  pool_kernel<<<N_B, 64, 0, stream>>>(gate, h, brp, pooled);

  // readout MLP (f32, tiny)
  gemm_f32<<<dim3(4, 64), 256, 0, stream>>>(pooled, W1, b1, r1, N_B, 256, 256, 1, BN_S);
  gemm_f32<<<dim3(2, 64), 256, 0, stream>>>(r1, W2, b2, r2, N_B, 128, 256, 1, BN_S);
  gemm_f32<<<dim3(1, 64), 256, 0, stream>>>(r2, W3, b3, r3, N_B, 64, 128, 1, 1.f);
  out_kernel<<<1024, 256, 0, stream>>>(r3, W4, b4, out);
}

// Round 6
// 1360.857 us; speedup vs baseline: 1.1408x; 1.0294x over previous
//
#include <hip/hip_runtime.h>

#define N_NODES 100000
#define N_EDGES 220000
#define N_B     4096
#define HIDDEN  256
#define BN_S    0.9999950000374997f
#define NSCANB  98       // ceil(100000/1024)

typedef __attribute__((ext_vector_type(8))) short bf16x8;
typedef __attribute__((ext_vector_type(4))) float f32x4;

__device__ __forceinline__ float bf2f(unsigned short u) {
  return __uint_as_float(((unsigned int)u) << 16);
}
__device__ __forceinline__ unsigned short f2bf(float f) {
  unsigned int x = __float_as_uint(f);
  unsigned int lsb = (x >> 16) & 1u;
  x += 0x7fffu + lsb;
  return (unsigned short)(x >> 16);
}

// async global->LDS 16B: dest is wave-uniform base + lane*16 (linear);
// per-lane GLOBAL address carries the XOR swizzle (m173 pattern).
__device__ __forceinline__ void g2lds16(const void* g, void* l) {
  __builtin_amdgcn_global_load_lds(
      (const __attribute__((address_space(1))) unsigned int*)g,
      (__attribute__((address_space(3))) unsigned int*)l, 16, 0, 0);
}

// bijective XCD swizzle (m204): hardware round-robins blockIdx across 8 XCDs;
// remap so each XCD owns a contiguous chunk of logical workgroups.
__device__ __forceinline__ int xcd_swz(int b, int nwg) {
  int q = nwg >> 3, r = nwg & 7;
  int xcd = b & 7, idx = b >> 3;
  int base = (xcd < r) ? xcd * (q + 1) : r * (q + 1) + (xcd - r) * q;
  return base + idx;
}

// ---------------- zero-init of counters ----------------
__global__ void zero_kernel(int* __restrict__ deg, int* __restrict__ cursor, float* __restrict__ macc) {
  int i = blockIdx.x * blockDim.x + threadIdx.x;
  if (i < N_NODES) { deg[i] = 0; cursor[i] = 0; }
  if (i < 16) macc[i] = 0.f;
}

// ---------------- mean of edge_attr (block-reduced, 1 atomic/k/block) ----------------
__global__ __launch_bounds__(256) void mean_kernel(const float* __restrict__ ea, float* __restrict__ macc) {
  __shared__ float sred[4][16];
  int lane = threadIdx.x & 63;
  int wv = threadIdx.x >> 6;
  float loc[10];
#pragma unroll
  for (int k = 0; k < 10; ++k) loc[k] = 0.f;
  for (int e = blockIdx.x * blockDim.x + threadIdx.x; e < N_EDGES; e += gridDim.x * blockDim.x) {
    const float* p = ea + (size_t)e * 10;
#pragma unroll
    for (int k = 0; k < 10; ++k) loc[k] += p[k];
  }
#pragma unroll
  for (int k = 0; k < 10; ++k) {
    float v = loc[k];
#pragma unroll
    for (int o = 1; o < 64; o <<= 1) v += __shfl_xor(v, o);
    if (lane == 0) sred[wv][k] = v;
  }
  __syncthreads();
  if (threadIdx.x < 10) {
    float s = sred[0][threadIdx.x] + sred[1][threadIdx.x] +
              sred[2][threadIdx.x] + sred[3][threadIdx.x];
    atomicAdd(&macc[threadIdx.x], s);
  }
}

__global__ void meanattr_kernel(const float* __restrict__ macc, float* __restrict__ meanattr) {
  int t = threadIdx.x;
  const float invE = 1.f / (float)N_EDGES;
  if (t < 10) meanattr[t] = macc[t] * invE;
}

// ---------------- ep_self[i][c] = meanattr . We[i][:,c] ----------------
__global__ void epself_kernel(const float* __restrict__ meanattr, const float* __restrict__ We,
                              float* __restrict__ ep_self) {
  int i = blockIdx.x;
  int c = threadIdx.x;
  float s = 0.f;
#pragma unroll
  for (int k = 0; k < 10; ++k)
    s += meanattr[k] * We[(size_t)i * 2560 + k * 256 + c];
  ep_self[i * 256 + c] = s;
}

// ---------------- CSR build (REAL edges only) ----------------
__global__ void count_kernel(const int* __restrict__ ei, int* __restrict__ deg) {
  for (int e = blockIdx.x * blockDim.x + threadIdx.x; e < N_EDGES; e += gridDim.x * blockDim.x) {
    atomicAdd(&deg[ei[N_EDGES + e]], 1);
  }
}

// ---------------- 3-phase scan ----------------
__global__ __launch_bounds__(1024) void scan1_kernel(const int* __restrict__ deg,
                                                     int* __restrict__ rowptr,
                                                     int* __restrict__ bsum) {
  __shared__ int buf[1024];
  int t = threadIdx.x;
  int i = blockIdx.x * 1024 + t;
  int v = (i < N_NODES) ? deg[i] : 0;
  buf[t] = v;
  __syncthreads();
  for (int off = 1; off < 1024; off <<= 1) {
    int add = (t >= off) ? buf[t - off] : 0;
    __syncthreads();
    buf[t] += add;
    __syncthreads();
  }
  if (i < N_NODES) rowptr[i + 1] = buf[t];
  if (t == 1023) bsum[blockIdx.x] = buf[t];
  if (i == 0) rowptr[0] = 0;
}

__global__ __launch_bounds__(128) void scan2_kernel(int* __restrict__ bsum) {
  __shared__ int buf[128];
  int t = threadIdx.x;
  int v = (t < NSCANB) ? bsum[t] : 0;
  buf[t] = v;
  __syncthreads();
  for (int off = 1; off < 128; off <<= 1) {
    int add = (t >= off) ? buf[t - off] : 0;
    __syncthreads();
    buf[t] += add;
    __syncthreads();
  }
  if (t < NSCANB) bsum[t] = buf[t];
}

__global__ __launch_bounds__(1024) void scan3_kernel(int* __restrict__ rowptr,
                                                     const int* __restrict__ bsum) {
  int b = blockIdx.x;
  if (b == 0) return;
  int i = b * 1024 + threadIdx.x;
  if (i < N_NODES) rowptr[i + 1] += bsum[b - 1];
}

__global__ void scatter_kernel(const int* __restrict__ ei, const int* __restrict__ rowptr,
                               int* __restrict__ cursor, int* __restrict__ csr) {
  for (int e = blockIdx.x * blockDim.x + threadIdx.x; e < N_EDGES; e += gridDim.x * blockDim.x) {
    int t = ei[N_EDGES + e];
    int pos = atomicAdd(&cursor[t], 1);
    csr[rowptr[t] + pos] = e;
  }
}

__global__ void brp_kernel(const int* __restrict__ batch, int* __restrict__ brp) {
  for (int i = blockIdx.x * blockDim.x + threadIdx.x; i < N_NODES; i += gridDim.x * blockDim.x) {
    int bi = batch[i];
    int bp = (i == 0) ? -1 : batch[i - 1];
    for (int b = bp + 1; b <= bi; ++b) brp[b] = i;
    if (i == N_NODES - 1) {
      for (int b = bi + 1; b <= N_B; ++b) brp[b] = N_NODES;
    }
  }
}

// ---------------- x -> padded bf16 [N,96] ----------------
__global__ void convx_kernel(const float* __restrict__ x, unsigned short* __restrict__ xp) {
  int total = N_NODES * 96;
  for (int idx = blockIdx.x * blockDim.x + threadIdx.x; idx < total; idx += gridDim.x * blockDim.x) {
    int nn = idx / 96;
    int j = idx - nn * 96;
    unsigned short v = 0;
    if (j < 75) v = f2bf(x[(size_t)nn * 75 + j]);
    xp[idx] = v;
  }
}

// ---------------- weight transpose+bf16 ----------------
__global__ void wt_kernel(const float* __restrict__ src, unsigned short* __restrict__ dst,
                          int K, int Kp, int N) {
  int idx = blockIdx.x * blockDim.x + threadIdx.x;
  int total = N * Kp;
  if (idx >= total) return;
  int n = idx / Kp, k = idx - n * Kp;
  dst[idx] = (k < K) ? f2bf(src[(size_t)k * N + n]) : (unsigned short)0;
}

// ---------------- all 4 layers Wl^T||Wr^T in one launch ----------------
__global__ void wlr_kernel(const float* __restrict__ Wl, const float* __restrict__ Wr,
                           unsigned short* __restrict__ dst) {
  const int total = 4 * 512 * 256;
  for (int idx = blockIdx.x * blockDim.x + threadIdx.x; idx < total; idx += gridDim.x * blockDim.x) {
    int i = idx >> 17;          // /131072
    int rem = idx & 131071;
    int n = rem >> 8;           // 0..511
    int k = rem & 255;
    float v = (n < 256) ? Wl[(size_t)i * 65536 + k * 256 + n]
                        : Wr[(size_t)i * 65536 + k * 256 + (n - 256)];
    dst[idx] = f2bf(v);
  }
}

// ---------------- bf16 MFMA GEMM, m97-style staging ----------------
// 1D grid with XCD swizzle; linear LDS [128][32] filled by global_load_lds(16B);
// read-side XOR swizzle slot^=(row>>1)&3 applied on BOTH the per-lane global
// source address and the ds_read address -> conflict-free (2-way).
__global__ __launch_bounds__(256) void gemm_mfma(
    const unsigned short* __restrict__ A, const unsigned short* __restrict__ Bt,
    const float* __restrict__ bias, float* __restrict__ Cf, unsigned short* __restrict__ Cb,
    int M, int Ncol, int K, int act, float scale, int gx)
{
  __shared__ unsigned short As[128 * 32];
  __shared__ unsigned short Bs[128 * 32];
  const int tid = threadIdx.x;
  const int wave = tid >> 6;
  const int lane = tid & 63;

  const int wg = xcd_swz(blockIdx.x, gridDim.x);
  const int col0 = (wg % gx) * 128;
  const int row0 = (wg / gx) * 128;

  const int wrow = (wave >> 1) * 64;
  const int wcol = (wave & 1) * 64;
  const int lrow = lane & 15;
  const int quad = lane >> 4;

  // staging geometry: wave stages tile rows [32*wave, 32*wave+32)
  const int rbase = wave * 32;
  const int lr4 = lane >> 2;      // 0..15
  const int lc = lane & 3;        // 16B slot
  const int tr0 = rbase + lr4;
  const int tr1 = rbase + 16 + lr4;
  int gra0 = row0 + tr0; if (gra0 > M - 1) gra0 = M - 1;  // clamp: rows >= M discarded in epilogue
  int gra1 = row0 + tr1; if (gra1 > M - 1) gra1 = M - 1;
  const int sca0 = (lc ^ ((tr0 >> 1) & 3)) * 8;   // pre-swizzled source slot (elems)
  const int sca1 = (lc ^ ((tr1 >> 1) & 3)) * 8;
  const unsigned short* pa0 = A + (size_t)gra0 * K + sca0;
  const unsigned short* pa1 = A + (size_t)gra1 * K + sca1;
  const unsigned short* pb0 = Bt + (size_t)(col0 + tr0) * K + sca0;
  const unsigned short* pb1 = Bt + (size_t)(col0 + tr1) * K + sca1;
  unsigned short* la0 = &As[rbase * 32];
  unsigned short* la1 = &As[(rbase + 16) * 32];
  unsigned short* lb0 = &Bs[rbase * 32];
  unsigned short* lb1 = &Bs[(rbase + 16) * 32];

  f32x4 acc[4][4] = {};

  for (int k0 = 0; k0 < K; k0 += 32) {
    g2lds16(pa0 + k0, la0);
    g2lds16(pa1 + k0, la1);
    g2lds16(pb0 + k0, lb0);
    g2lds16(pb1 + k0, lb1);
    __syncthreads();   // drains vmcnt (global_load_lds) before LDS reads
    bf16x8 afr[4], bfr[4];
#pragma unroll
    for (int mt = 0; mt < 4; ++mt) {
      int rr = wrow + mt * 16 + lrow;
      afr[mt] = *(const bf16x8*)(&As[rr * 32 + ((quad ^ ((rr >> 1) & 3)) << 3)]);
    }
#pragma unroll
    for (int nt = 0; nt < 4; ++nt) {
      int rr = wcol + nt * 16 + lrow;
      bfr[nt] = *(const bf16x8*)(&Bs[rr * 32 + ((quad ^ ((rr >> 1) & 3)) << 3)]);
    }
#pragma unroll
    for (int mt = 0; mt < 4; ++mt)
#pragma unroll
      for (int nt = 0; nt < 4; ++nt)
        acc[mt][nt] = __builtin_amdgcn_mfma_f32_16x16x32_bf16(afr[mt], bfr[nt], acc[mt][nt], 0, 0, 0);
    __syncthreads();
  }

#pragma unroll
  for (int mt = 0; mt < 4; ++mt) {
#pragma unroll
    for (int nt = 0; nt < 4; ++nt) {
      int gcol = col0 + wcol + nt * 16 + lrow;
      float bv = bias ? bias[gcol] : 0.f;
#pragma unroll
      for (int r = 0; r < 4; ++r) {
        int grow = row0 + wrow + mt * 16 + quad * 4 + r;
        if (grow >= M) continue;
        float v = (acc[mt][nt][r] + bv) * scale;
        if (act == 1) v = fmaxf(v, 0.f);
        else if (act == 2) v = (v > 0.f) ? v : (__expf(v) - 1.f);
        if (Cf) Cf[(size_t)grow * Ncol + gcol] = v;
        if (Cb) Cb[(size_t)grow * Ncol + gcol] = f2bf(v);
      }
    }
  }
}

// ---------------- fused pooling-gate GEMM (same staging) ----------------
__global__ __launch_bounds__(256) void gemm_gate(
    const unsigned short* __restrict__ A, const unsigned short* __restrict__ Bt,
    const float* __restrict__ bg1, const float* __restrict__ Wg2,
    const float* __restrict__ bg2, float* __restrict__ gate, int M)
{
  __shared__ unsigned short As[128 * 32];
  __shared__ unsigned short Bs[128 * 32];
  __shared__ float gbuf[128][2];
  const int tid = threadIdx.x;
  const int wave = tid >> 6;
  const int lane = tid & 63;

  const int wg = xcd_swz(blockIdx.x, gridDim.x);
  const int row0 = wg * 128;

  const int wrow = (wave >> 1) * 64;
  const int wcol = (wave & 1) * 64;
  const int lrow = lane & 15;
  const int quad = lane >> 4;

  const int rbase = wave * 32;
  const int lr4 = lane >> 2;
  const int lc = lane & 3;
  const int tr0 = rbase + lr4;
  const int tr1 = rbase + 16 + lr4;
  int gra0 = row0 + tr0; if (gra0 > M - 1) gra0 = M - 1;
  int gra1 = row0 + tr1; if (gra1 > M - 1) gra1 = M - 1;
  const int sca0 = (lc ^ ((tr0 >> 1) & 3)) * 8;
  const int sca1 = (lc ^ ((tr1 >> 1) & 3)) * 8;
  const unsigned short* pa0 = A + (size_t)gra0 * 256 + sca0;
  const unsigned short* pa1 = A + (size_t)gra1 * 256 + sca1;
  const unsigned short* pb0 = Bt + (size_t)tr0 * 256 + sca0;
  const unsigned short* pb1 = Bt + (size_t)tr1 * 256 + sca1;
  unsigned short* la0 = &As[rbase * 32];
  unsigned short* la1 = &As[(rbase + 16) * 32];
  unsigned short* lb0 = &Bs[rbase * 32];
  unsigned short* lb1 = &Bs[(rbase + 16) * 32];

  f32x4 acc[4][4] = {};

  for (int k0 = 0; k0 < 256; k0 += 32) {
    g2lds16(pa0 + k0, la0);
    g2lds16(pa1 + k0, la1);
    g2lds16(pb0 + k0, lb0);
    g2lds16(pb1 + k0, lb1);
    __syncthreads();
    bf16x8 afr[4], bfr[4];
#pragma unroll
    for (int mt = 0; mt < 4; ++mt) {
      int rr = wrow + mt * 16 + lrow;
      afr[mt] = *(const bf16x8*)(&As[rr * 32 + ((quad ^ ((rr >> 1) & 3)) << 3)]);
    }
#pragma unroll
    for (int nt = 0; nt < 4; ++nt) {
      int rr = wcol + nt * 16 + lrow;
      bfr[nt] = *(const bf16x8*)(&Bs[rr * 32 + ((quad ^ ((rr >> 1) & 3)) << 3)]);
    }
#pragma unroll
    for (int mt = 0; mt < 4; ++mt)
#pragma unroll
      for (int nt = 0; nt < 4; ++nt)
        acc[mt][nt] = __builtin_amdgcn_mfma_f32_16x16x32_bf16(afr[mt], bfr[nt], acc[mt][nt], 0, 0, 0);
    __syncthreads();
  }

  float p[4][4];
#pragma unroll
  for (int mt = 0; mt < 4; ++mt)
#pragma unroll
    for (int r = 0; r < 4; ++r) p[mt][r] = 0.f;
#pragma unroll
  for (int nt = 0; nt < 4; ++nt) {
    int gcol = wcol + nt * 16 + lrow;
    float b1v = bg1[gcol];
    float w2v = Wg2[gcol];
#pragma unroll
    for (int mt = 0; mt < 4; ++mt)
#pragma unroll
      for (int r = 0; r < 4; ++r) {
        float v = fmaxf(acc[mt][nt][r] + b1v, 0.f);
        p[mt][r] = fmaf(v, w2v, p[mt][r]);
      }
  }
#pragma unroll
  for (int mt = 0; mt < 4; ++mt)
#pragma unroll
    for (int r = 0; r < 4; ++r) {
      float v = p[mt][r];
      v += __shfl_xor(v, 1);
      v += __shfl_xor(v, 2);
      v += __shfl_xor(v, 4);
      v += __shfl_xor(v, 8);
      if (lrow == 0) gbuf[wrow + mt * 16 + quad * 4 + r][wcol >> 6] = v;
    }
  __syncthreads();
  if (tid < 128) {
    int grow = row0 + tid;
    if (grow < M) gate[grow] = gbuf[tid][0] + gbuf[tid][1] + bg2[0];
  }
}

// ---------------- f32 GEMM for the tiny readout layers ----------------
__global__ __launch_bounds__(256) void gemm_f32(
    const float* __restrict__ A, const float* __restrict__ B,
    const float* __restrict__ bias, float* __restrict__ C,
    int M, int Ncol, int K, int act, float scale)
{
  __shared__ float As[32][68];
  __shared__ float Bs[32][68];
  const int tid = threadIdx.x;
  const int tx = tid & 15, ty = tid >> 4;
  const int col0 = blockIdx.x * 64;
  const int row0 = blockIdx.y * 64;
  float acc[4][4];
#pragma unroll
  for (int i = 0; i < 4; ++i)
#pragma unroll
    for (int j = 0; j < 4; ++j) acc[i][j] = 0.f;

  const int ar = tid >> 3;
  const int ak = (tid & 7) * 4;
  const int bk = tid >> 4;
  const int bc = (tid & 15) * 4;

  for (int k0 = 0; k0 < K; k0 += 32) {
#pragma unroll
    for (int p = 0; p < 2; ++p) {
      int r = ar + p * 32;
      int grow = row0 + r;
      float4 v = make_float4(0.f, 0.f, 0.f, 0.f);
      if (grow < M) v = *(const float4*)(A + (size_t)grow * K + k0 + ak);
      As[ak + 0][r] = v.x; As[ak + 1][r] = v.y; As[ak + 2][r] = v.z; As[ak + 3][r] = v.w;
    }
#pragma unroll
    for (int p = 0; p < 2; ++p) {
      int kk = bk + p * 16;
      float4 v = *(const float4*)(B + (size_t)(k0 + kk) * Ncol + col0 + bc);
      *(float4*)(&Bs[kk][bc]) = v;
    }
    __syncthreads();
#pragma unroll
    for (int kk = 0; kk < 32; ++kk) {
      float4 a = *(const float4*)(&As[kk][ty * 4]);
      float4 b = *(const float4*)(&Bs[kk][tx * 4]);
      float av[4] = {a.x, a.y, a.z, a.w};
      float bv[4] = {b.x, b.y, b.z, b.w};
#pragma unroll
      for (int i = 0; i < 4; ++i)
#pragma unroll
        for (int j = 0; j < 4; ++j) acc[i][j] = fmaf(av[i], bv[j], acc[i][j]);
    }
    __syncthreads();
  }
  float bvals[4] = {0.f, 0.f, 0.f, 0.f};
  if (bias) {
#pragma unroll
    for (int j = 0; j < 4; ++j) bvals[j] = bias[col0 + tx * 4 + j];
  }
#pragma unroll
  for (int i = 0; i < 4; ++i) {
    int r = row0 + ty * 4 + i;
    if (r >= M) continue;
    float4 outv;
    float* o = (float*)&outv;
#pragma unroll
    for (int j = 0; j < 4; ++j) {
      float v = (acc[i][j] + bvals[j]) * scale;
      if (act == 1) v = fmaxf(v, 0.f);
      else if (act == 2) v = (v > 0.f) ? v : (__expf(v) - 1.f);
      o[j] = v;
    }
    *(float4*)(C + (size_t)r * Ncol + col0 + tx * 4) = outv;
  }
}

// ---------------- PASS A: edge-parallel logits (real edges only) ----------------
__global__ __launch_bounds__(256) void logits_kernel(
    const unsigned short* __restrict__ xlr,
    const int* __restrict__ ei, const float* __restrict__ eattr,
    const float* __restrict__ We, const float* __restrict__ att,
    float* __restrict__ logits)
{
  const int lane = threadIdx.x & 63;
  const int wv = threadIdx.x >> 6;
  const int c0 = lane * 4;
  const int head = lane >> 3;

  float4 attf4 = *(const float4*)(att + c0);
  float attf[4] = {attf4.x, attf4.y, attf4.z, attf4.w};
  float wef[10][4];
#pragma unroll
  for (int k = 0; k < 10; ++k) {
    float4 w4 = *(const float4*)(We + k * 256 + c0);
    wef[k][0] = w4.x; wef[k][1] = w4.y; wef[k][2] = w4.z; wef[k][3] = w4.w;
  }

  auto edge_logit = [&](int e) {
    int src = ei[e];
    int tgt = ei[N_EDGES + e];
    const float* eap = eattr + (size_t)e * 10;
    float2 q0 = *(const float2*)(eap + 0);
    float2 q1 = *(const float2*)(eap + 2);
    float2 q2 = *(const float2*)(eap + 4);
    float2 q3 = *(const float2*)(eap + 6);
    float2 q4 = *(const float2*)(eap + 8);
    ushort4 ua = *(const ushort4*)(xlr + (size_t)src * 512 + c0);
    ushort4 ub = *(const ushort4*)(xlr + (size_t)tgt * 512 + 256 + c0);
    float ev[10] = {q0.x, q0.y, q1.x, q1.y, q2.x, q2.y, q3.x, q3.y, q4.x, q4.y};
    float p0 = 0.f, p1 = 0.f, p2 = 0.f, p3 = 0.f;
#pragma unroll
    for (int k = 0; k < 10; ++k) {
      p0 = fmaf(ev[k], wef[k][0], p0);
      p1 = fmaf(ev[k], wef[k][1], p1);
      p2 = fmaf(ev[k], wef[k][2], p2);
      p3 = fmaf(ev[k], wef[k][3], p3);
    }
    float s0 = bf2f(ua.x) + bf2f(ub.x) + p0;
    float s1 = bf2f(ua.y) + bf2f(ub.y) + p1;
    float s2 = bf2f(ua.z) + bf2f(ub.z) + p2;
    float s3 = bf2f(ua.w) + bf2f(ub.w) + p3;
    s0 = (s0 > 0.f) ? s0 : 0.2f * s0;
    s1 = (s1 > 0.f) ? s1 : 0.2f * s1;
    s2 = (s2 > 0.f) ? s2 : 0.2f * s2;
    s3 = (s3 > 0.f) ? s3 : 0.2f * s3;
    float part = s0 * attf[0] + s1 * attf[1] + s2 * attf[2] + s3 * attf[3];
    part += __shfl_xor(part, 1);
    part += __shfl_xor(part, 2);
    part += __shfl_xor(part, 4);
    if ((lane & 7) == 0) logits[(size_t)e * 8 + head] = part;
  };

  const int nw = gridDim.x * 4;
  const int e0 = (blockIdx.x * 4 + wv) * 2;
  for (int e = e0; e < N_EDGES; e += nw * 2) {
    edge_logit(e);
    if (e + 1 < N_EDGES) edge_logit(e + 1);
  }
}

// ---------------- PASS B: node-parallel softmax + aggregate + BN/ELU/residual ----------------
__global__ __launch_bounds__(256) void attn_kernel(
    const unsigned short* __restrict__ xlr,
    float* __restrict__ h, unsigned short* __restrict__ hb,
    const int* __restrict__ ei, const float* __restrict__ logits,
    const float* __restrict__ att, const float* __restrict__ bgat,
    const float* __restrict__ ep_self,
    const int* __restrict__ rowptr, const int* __restrict__ csr)
{
  const int lane = threadIdx.x & 63;
  const int wv = threadIdx.x >> 6;
  const int n = blockIdx.x * 4 + wv;
  if (n >= N_NODES) return;
  const int c0 = lane * 4;
  const int head = lane >> 3;

  const int s = rowptr[n], e = rowptr[n + 1];

  ushort4 ul = *(const ushort4*)(xlr + (size_t)n * 512 + c0);        // xl[n]
  ushort4 ur = *(const ushort4*)(xlr + (size_t)n * 512 + 256 + c0);  // xr[n]
  float4 hold = *(const float4*)(h + (size_t)n * HIDDEN + c0);
  float4 attf = *(const float4*)(att + c0);
  float4 eps = *(const float4*)(ep_self + c0);

  float xln[4] = {bf2f(ul.x), bf2f(ul.y), bf2f(ul.z), bf2f(ul.w)};

  // self-loop logit
  float lself;
  {
    float s0 = xln[0] + bf2f(ur.x) + eps.x;
    float s1 = xln[1] + bf2f(ur.y) + eps.y;
    float s2 = xln[2] + bf2f(ur.z) + eps.z;
    float s3 = xln[3] + bf2f(ur.w) + eps.w;
    s0 = (s0 > 0.f) ? s0 : 0.2f * s0;
    s1 = (s1 > 0.f) ? s1 : 0.2f * s1;
    s2 = (s2 > 0.f) ? s2 : 0.2f * s2;
    s3 = (s3 > 0.f) ? s3 : 0.2f * s3;
    float part = s0 * attf.x + s1 * attf.y + s2 * attf.z + s3 * attf.w;
    part += __shfl_xor(part, 1);
    part += __shfl_xor(part, 2);
    part += __shfl_xor(part, 4);
    lself = part;
  }

  // loop1: max over real in-edge logits
  float m = lself;
  const int elast = e - 1;
  for (int idx = s; idx < e; idx += 4) {
    int i1 = idx + 1, i2 = idx + 2, i3 = idx + 3;
    int eid0 = csr[idx];
    int eid1 = csr[(i1 <= elast) ? i1 : elast];
    int eid2 = csr[(i2 <= elast) ? i2 : elast];
    int eid3 = csr[(i3 <= elast) ? i3 : elast];
    float l0 = logits[(size_t)eid0 * 8 + head];
    float l1 = logits[(size_t)eid1 * 8 + head];
    float l2 = logits[(size_t)eid2 * 8 + head];
    float l3 = logits[(size_t)eid3 * 8 + head];
    m = fmaxf(fmaxf(m, fmaxf(l0, l1)), fmaxf(l2, l3));
  }

  // loop2: independent accumulate
  float wself = __expf(lself - m);
  float d = wself;
  float a0 = wself * xln[0], a1 = wself * xln[1], a2 = wself * xln[2], a3 = wself * xln[3];
  for (int idx = s; idx < e; idx += 2) {
    int i1 = idx + 1;
    bool v1 = (i1 <= elast);
    int eid0 = csr[idx];
    int eid1 = csr[v1 ? i1 : elast];
    float l0 = logits[(size_t)eid0 * 8 + head];
    float l1 = logits[(size_t)eid1 * 8 + head];
    int s0 = ei[eid0];
    int s1 = ei[eid1];
    float w0 = __expf(l0 - m);
    float w1 = v1 ? __expf(l1 - m) : 0.f;
    ushort4 u0 = *(const ushort4*)(xlr + (size_t)s0 * 512 + c0);
    ushort4 u1 = *(const ushort4*)(xlr + (size_t)s1 * 512 + c0);
    d += w0 + w1;
    a0 += w0 * bf2f(u0.x) + w1 * bf2f(u1.x);
    a1 += w0 * bf2f(u0.y) + w1 * bf2f(u1.y);
    a2 += w0 * bf2f(u0.z) + w1 * bf2f(u1.z);
    a3 += w0 * bf2f(u0.w) + w1 * bf2f(u1.w);
  }

  float inv = 1.f / (d + 1e-16f);
  float4 bg = *(const float4*)(bgat + c0);
  float ov[4] = {a0 * inv, a1 * inv, a2 * inv, a3 * inv};
  float bgv[4] = {bg.x, bg.y, bg.z, bg.w};
  float hv[4] = {hold.x, hold.y, hold.z, hold.w};
  float4 res;
  float* rp = (float*)&res;
  ushort4 resb;
  unsigned short* rb = (unsigned short*)&resb;
#pragma unroll
  for (int j = 0; j < 4; ++j) {
    float v = (ov[j] + bgv[j]) * BN_S;
    v = (v > 0.f) ? v : (__expf(v) - 1.f);
    float nv = v + hv[j];
    rp[j] = nv;
    rb[j] = f2bf(nv);
  }
  *(float4*)(h + (size_t)n * HIDDEN + c0) = res;
  *(ushort4*)(hb + (size_t)n * HIDDEN + c0) = resb;
}

// ---------------- global attention pooling per graph ----------------
__global__ __launch_bounds__(64) void pool_kernel(
    const float* __restrict__ gate, const float* __restrict__ h,
    const int* __restrict__ brp, float* __restrict__ pooled)
{
  int b = blockIdx.x;
  int lane = threadIdx.x;
  int s = brp[b], e = brp[b + 1];
  float m = -__builtin_inff();
  for (int i = s + lane; i < e; i += 64) m = fmaxf(m, gate[i]);
#pragma unroll
  for (int o = 1; o < 64; o <<= 1) m = fmaxf(m, __shfl_xor(m, o));
  float d = 0.f;
  for (int i = s + lane; i < e; i += 64) d += __expf(gate[i] - m);
#pragma unroll
  for (int o = 1; o < 64; o <<= 1) d += __shfl_xor(d, o);
  float inv = 1.f / (d + 1e-16f);
  int c0 = lane * 4;
  float acc[4] = {0.f, 0.f, 0.f, 0.f};
  for (int i = s; i < e; ++i) {
    float w = __expf(gate[i] - m) * inv;
    float4 hv = *(const float4*)(h + (size_t)i * HIDDEN + c0);
    acc[0] = fmaf(w, hv.x, acc[0]);
    acc[1] = fmaf(w, hv.y, acc[1]);
    acc[2] = fmaf(w, hv.z, acc[2]);
    acc[3] = fmaf(w, hv.w, acc[3]);
  }
  float4 outv = make_float4(acc[0], acc[1], acc[2], acc[3]);
  *(float4*)(pooled + (size_t)b * HIDDEN + c0) = outv;
}

// ---------------- final: out[b] = r3[b,:] . W4 + b4 ----------------
__global__ __launch_bounds__(256) void out_kernel(
    const float* __restrict__ r3, const float* __restrict__ W4,
    const float* __restrict__ b4, float* __restrict__ out)
{
  int lane = threadIdx.x & 63;
  int wv = threadIdx.x >> 6;
  int b = blockIdx.x * 4 + wv;
  if (b >= N_B) return;
  float v = r3[(size_t)b * 64 + lane] * W4[lane];
#pragma unroll
  for (int o = 1; o < 64; o <<= 1) v += __shfl_xor(v, o);
  if (lane == 0) out[b] = v + b4[0];
}

extern "C" void kernel_launch(void* const* d_in, const int* in_sizes, int n_in,
                              void* d_out, int out_size, void* d_ws, size_t ws_size,
                              hipStream_t stream)
{
  const float* x    = (const float*)d_in[0];
  const int* ei     = (const int*)d_in[1];
  const float* ea   = (const float*)d_in[2];
  const int* batch  = (const int*)d_in[3];
  const float* W_in = (const float*)d_in[4];
  const float* b_in = (const float*)d_in[5];
  const float* Wl   = (const float*)d_in[6];
  const float* Wr   = (const float*)d_in[7];
  const float* We   = (const float*)d_in[8];
  const float* att  = (const float*)d_in[9];
  const float* bgat = (const float*)d_in[10];
  const float* Wg1  = (const float*)d_in[11];
  const float* bg1  = (const float*)d_in[12];
  const float* Wg2  = (const float*)d_in[13];
  const float* bg2  = (const float*)d_in[14];
  const float* W1   = (const float*)d_in[15];
  const float* b1   = (const float*)d_in[16];
  const float* W2   = (const float*)d_in[17];
  const float* b2   = (const float*)d_in[18];
  const float* W3   = (const float*)d_in[19];
  const float* b3   = (const float*)d_in[20];
  const float* W4   = (const float*)d_in[21];
  const float* b4   = (const float*)d_in[22];
  float* out = (float*)d_out;

  char* ws = (char*)d_ws;
  size_t off = 0;
  auto alloc = [&](size_t bytes) -> char* {
    char* p = ws + off;
    off += (bytes + 255) & ~(size_t)255;
    return p;
  };
  float* h            = (float*)alloc((size_t)N_NODES * HIDDEN * 4);           // 102.4 MB
  unsigned short* hb  = (unsigned short*)alloc((size_t)N_NODES * HIDDEN * 2);  // 51.2 MB
  unsigned short* xlr = (unsigned short*)alloc((size_t)N_NODES * 512 * 2);     // 102.4 MB
  int* deg       = (int*)alloc((size_t)N_NODES * 4);
  int* rowptr    = (int*)alloc((size_t)(N_NODES + 1) * 4);
  int* cursor    = (int*)alloc((size_t)N_NODES * 4);
  int* csr       = (int*)alloc((size_t)N_EDGES * 4);       // real edges only
  int* brp       = (int*)alloc((size_t)(N_B + 1) * 4);
  int* bsum      = (int*)alloc(512);
  float* macc    = (float*)alloc(64);
  float* meanattr= (float*)alloc(64);
  float* ep_self = (float*)alloc(4 * 256 * 4);
  float* logits  = (float*)alloc((size_t)N_EDGES * 8 * 4); // 7.04 MB
  unsigned short* Wint  = (unsigned short*)alloc(256 * 96 * 2);       // [256][96]
  unsigned short* Wlrt  = (unsigned short*)alloc(4 * 512 * 256 * 2);  // [i][512][256] = Wl^T || Wr^T
  unsigned short* Wg1t  = (unsigned short*)alloc(128 * 256 * 2);      // [128][256]
  // total ≈ 266.3 MB < 268.4 MB ws  ✓

  // aliases into dead regions of xlr:
  unsigned short* xpad = xlr;            // [N,96] bf16, pre-layer0 only
  float* base2  = (float*)xlr;           // xlr fully dead after last attn layer
  float* gate   = base2;                 // [N] f32
  float* pooled = base2 + 1000000;       // [B,256] f32
  float* r1     = base2 + 3000000;       // [B,256] f32
  float* r2     = base2 + 5000000;       // [B,128] f32
  float* r3     = base2 + 6000000;       // [B,64]  f32

  if (ws_size < off) {
    hipMemsetAsync(d_out, 0, (size_t)out_size * 4, stream);
    return;
  }

  zero_kernel<<<391, 256, 0, stream>>>(deg, cursor, macc);
  mean_kernel<<<64, 256, 0, stream>>>(ea, macc);
  meanattr_kernel<<<1, 64, 0, stream>>>(macc, meanattr);
  epself_kernel<<<4, 256, 0, stream>>>(meanattr, We, ep_self);
  count_kernel<<<860, 256, 0, stream>>>(ei, deg);
  scan1_kernel<<<NSCANB, 1024, 0, stream>>>(deg, rowptr, bsum);
  scan2_kernel<<<1, 128, 0, stream>>>(bsum);
  scan3_kernel<<<NSCANB, 1024, 0, stream>>>(rowptr, bsum);
  scatter_kernel<<<860, 256, 0, stream>>>(ei, rowptr, cursor, csr);
  brp_kernel<<<512, 256, 0, stream>>>(batch, brp);

  // weight conversions (transpose + bf16)
  wt_kernel<<<(256 * 96 + 255) / 256, 256, 0, stream>>>(W_in, Wint, 75, 96, 256);
  wlr_kernel<<<512, 256, 0, stream>>>(Wl, Wr, Wlrt);
  wt_kernel<<<128, 256, 0, stream>>>(Wg1, Wg1t, 256, 256, 128);
  convx_kernel<<<4096, 256, 0, stream>>>(x, xpad);

  // input projection: h = elu((x @ W_in + b_in) * BN_S)  [MFMA, K=96]
  gemm_mfma<<<1564, 256, 0, stream>>>(xpad, Wint, b_in, h, hb,
                                      N_NODES, 256, 96, 2, BN_S, 2);

  for (int i = 0; i < 4; ++i) {
    // fused xl||xr GEMM: [N,256] @ [256,512] -> xlr [N,512]
    gemm_mfma<<<3128, 256, 0, stream>>>(hb, Wlrt + (size_t)i * 131072, nullptr,
                                        nullptr, xlr, N_NODES, 512, 256, 0, 1.f, 4);
    // pass A: edge-parallel logits
    logits_kernel<<<2048, 256, 0, stream>>>(xlr, ei, ea, We + (size_t)i * 2560,
                                            att + (size_t)i * 256, logits);
    // pass B: node-parallel softmax + aggregate
    attn_kernel<<<25000, 256, 0, stream>>>(xlr, h, hb, ei, logits,
                                           att + (size_t)i * 256, bgat + (size_t)i * 256,
                                           ep_self + (size_t)i * 256, rowptr, csr);
  }

  // fused pooling gate: gate = relu(hb @ Wg1 + bg1) . Wg2 + bg2
  gemm_gate<<<782, 256, 0, stream>>>(hb, Wg1t, bg1, Wg2, bg2, gate, N_NODES);
  pool_kernel<<<N_B, 64, 0, stream>>>(gate, h, brp, pooled);

  // readout MLP (f32, tiny)
  gemm_f32<<<dim3(4, 64), 256, 0, stream>>>(pooled, W1, b1, r1, N_B, 256, 256, 1, BN_S);
  gemm_f32<<<dim3(2, 64), 256, 0, stream>>>(r1, W2, b2, r2, N_B, 128, 256, 1, BN_S);
  gemm_f32<<<dim3(1, 64), 256, 0, stream>>>(r2, W3, b3, r3, N_B, 64, 128, 1, 1.f);
  out_kernel<<<1024, 256, 0, stream>>>(r3, W4, b4, out);
}

// Round 7
// 1357.247 us; speedup vs baseline: 1.1438x; 1.0027x over previous
//
#include <hip/hip_runtime.h>

#define N_NODES 100000
#define N_EDGES 220000
#define N_B     4096
#define HIDDEN  256
#define BN_S    0.9999950000374997f
#define NSCANB  98       // ceil(100000/1024)

typedef __attribute__((ext_vector_type(8))) short bf16x8;
typedef __attribute__((ext_vector_type(4))) float f32x4;

__device__ __forceinline__ float bf2f(unsigned short u) {
  return __uint_as_float(((unsigned int)u) << 16);
}
__device__ __forceinline__ unsigned short f2bf(float f) {
  unsigned int x = __float_as_uint(f);
  unsigned int lsb = (x >> 16) & 1u;
  x += 0x7fffu + lsb;
  return (unsigned short)(x >> 16);
}

// async global->LDS 16B: dest is wave-uniform base + lane*16 (linear);
// per-lane GLOBAL address carries the XOR swizzle (m173 pattern).
__device__ __forceinline__ void g2lds16(const void* g, void* l) {
  __builtin_amdgcn_global_load_lds(
      (const __attribute__((address_space(1))) unsigned int*)g,
      (__attribute__((address_space(3))) unsigned int*)l, 16, 0, 0);
}

// bijective XCD swizzle (m204)
__device__ __forceinline__ int xcd_swz(int b, int nwg) {
  int q = nwg >> 3, r = nwg & 7;
  int xcd = b & 7, idx = b >> 3;
  int base = (xcd < r) ? xcd * (q + 1) : r * (q + 1) + (xcd - r) * q;
  return base + idx;
}

// ---------------- zero-init of counters ----------------
__global__ void zero_kernel(int* __restrict__ deg, int* __restrict__ cursor, float* __restrict__ macc) {
  int i = blockIdx.x * blockDim.x + threadIdx.x;
  if (i < N_NODES) { deg[i] = 0; cursor[i] = 0; }
  if (i < 16) macc[i] = 0.f;
}

// ---------------- mean of edge_attr (block-reduced, 1 atomic/k/block) ----------------
__global__ __launch_bounds__(256) void mean_kernel(const float* __restrict__ ea, float* __restrict__ macc) {
  __shared__ float sred[4][16];
  int lane = threadIdx.x & 63;
  int wv = threadIdx.x >> 6;
  float loc[10];
#pragma unroll
  for (int k = 0; k < 10; ++k) loc[k] = 0.f;
  for (int e = blockIdx.x * blockDim.x + threadIdx.x; e < N_EDGES; e += gridDim.x * blockDim.x) {
    const float* p = ea + (size_t)e * 10;
#pragma unroll
    for (int k = 0; k < 10; ++k) loc[k] += p[k];
  }
#pragma unroll
  for (int k = 0; k < 10; ++k) {
    float v = loc[k];
#pragma unroll
    for (int o = 1; o < 64; o <<= 1) v += __shfl_xor(v, o);
    if (lane == 0) sred[wv][k] = v;
  }
  __syncthreads();
  if (threadIdx.x < 10) {
    float s = sred[0][threadIdx.x] + sred[1][threadIdx.x] +
              sred[2][threadIdx.x] + sred[3][threadIdx.x];
    atomicAdd(&macc[threadIdx.x], s);
  }
}

__global__ void meanattr_kernel(const float* __restrict__ macc, float* __restrict__ meanattr) {
  int t = threadIdx.x;
  const float invE = 1.f / (float)N_EDGES;
  if (t < 10) meanattr[t] = macc[t] * invE;
}

// ---------------- ep_self[i][c] = meanattr . We[i][:,c] ----------------
__global__ void epself_kernel(const float* __restrict__ meanattr, const float* __restrict__ We,
                              float* __restrict__ ep_self) {
  int i = blockIdx.x;
  int c = threadIdx.x;
  float s = 0.f;
#pragma unroll
  for (int k = 0; k < 10; ++k)
    s += meanattr[k] * We[(size_t)i * 2560 + k * 256 + c];
  ep_self[i * 256 + c] = s;
}

// ---------------- CSR build (REAL edges only) ----------------
__global__ void count_kernel(const int* __restrict__ ei, int* __restrict__ deg) {
  for (int e = blockIdx.x * blockDim.x + threadIdx.x; e < N_EDGES; e += gridDim.x * blockDim.x) {
    atomicAdd(&deg[ei[N_EDGES + e]], 1);
  }
}

// ---------------- 3-phase scan ----------------
__global__ __launch_bounds__(1024) void scan1_kernel(const int* __restrict__ deg,
                                                     int* __restrict__ rowptr,
                                                     int* __restrict__ bsum) {
  __shared__ int buf[1024];
  int t = threadIdx.x;
  int i = blockIdx.x * 1024 + t;
  int v = (i < N_NODES) ? deg[i] : 0;
  buf[t] = v;
  __syncthreads();
  for (int off = 1; off < 1024; off <<= 1) {
    int add = (t >= off) ? buf[t - off] : 0;
    __syncthreads();
    buf[t] += add;
    __syncthreads();
  }
  if (i < N_NODES) rowptr[i + 1] = buf[t];
  if (t == 1023) bsum[blockIdx.x] = buf[t];
  if (i == 0) rowptr[0] = 0;
}

__global__ __launch_bounds__(128) void scan2_kernel(int* __restrict__ bsum) {
  __shared__ int buf[128];
  int t = threadIdx.x;
  int v = (t < NSCANB) ? bsum[t] : 0;
  buf[t] = v;
  __syncthreads();
  for (int off = 1; off < 128; off <<= 1) {
    int add = (t >= off) ? buf[t - off] : 0;
    __syncthreads();
    buf[t] += add;
    __syncthreads();
  }
  if (t < NSCANB) bsum[t] = buf[t];
}

__global__ __launch_bounds__(1024) void scan3_kernel(int* __restrict__ rowptr,
                                                     const int* __restrict__ bsum) {
  int b = blockIdx.x;
  if (b == 0) return;
  int i = b * 1024 + threadIdx.x;
  if (i < N_NODES) rowptr[i + 1] += bsum[b - 1];
}

__global__ void scatter_kernel(const int* __restrict__ ei, const int* __restrict__ rowptr,
                               int* __restrict__ cursor, int* __restrict__ csr) {
  for (int e = blockIdx.x * blockDim.x + threadIdx.x; e < N_EDGES; e += gridDim.x * blockDim.x) {
    int t = ei[N_EDGES + e];
    int pos = atomicAdd(&cursor[t], 1);
    csr[rowptr[t] + pos] = e;
  }
}

__global__ void brp_kernel(const int* __restrict__ batch, int* __restrict__ brp) {
  for (int i = blockIdx.x * blockDim.x + threadIdx.x; i < N_NODES; i += gridDim.x * blockDim.x) {
    int bi = batch[i];
    int bp = (i == 0) ? -1 : batch[i - 1];
    for (int b = bp + 1; b <= bi; ++b) brp[b] = i;
    if (i == N_NODES - 1) {
      for (int b = bi + 1; b <= N_B; ++b) brp[b] = N_NODES;
    }
  }
}

// ---------------- x -> padded bf16 [N,96] ----------------
__global__ void convx_kernel(const float* __restrict__ x, unsigned short* __restrict__ xp) {
  int total = N_NODES * 96;
  for (int idx = blockIdx.x * blockDim.x + threadIdx.x; idx < total; idx += gridDim.x * blockDim.x) {
    int nn = idx / 96;
    int j = idx - nn * 96;
    unsigned short v = 0;
    if (j < 75) v = f2bf(x[(size_t)nn * 75 + j]);
    xp[idx] = v;
  }
}

// ---------------- weight transpose+bf16 ----------------
__global__ void wt_kernel(const float* __restrict__ src, unsigned short* __restrict__ dst,
                          int K, int Kp, int N) {
  int idx = blockIdx.x * blockDim.x + threadIdx.x;
  int total = N * Kp;
  if (idx >= total) return;
  int n = idx / Kp, k = idx - n * Kp;
  dst[idx] = (k < K) ? f2bf(src[(size_t)k * N + n]) : (unsigned short)0;
}

// ---------------- all 4 layers Wl^T||Wr^T in one launch ----------------
__global__ void wlr_kernel(const float* __restrict__ Wl, const float* __restrict__ Wr,
                           unsigned short* __restrict__ dst) {
  const int total = 4 * 512 * 256;
  for (int idx = blockIdx.x * blockDim.x + threadIdx.x; idx < total; idx += gridDim.x * blockDim.x) {
    int i = idx >> 17;          // /131072
    int rem = idx & 131071;
    int n = rem >> 8;           // 0..511
    int k = rem & 255;
    float v = (n < 256) ? Wl[(size_t)i * 65536 + k * 256 + n]
                        : Wr[(size_t)i * 65536 + k * 256 + (n - 256)];
    dst[idx] = f2bf(v);
  }
}

// ---------------- bf16 MFMA GEMM, double-buffered global_load_lds staging ----------------
// 2-phase pipeline: issue next K-tile into buf^1 BEFORE computing buf; single
// __syncthreads per K-step (drains vmcnt after MFMA covered the load flight).
__global__ __launch_bounds__(256) void gemm_mfma(
    const unsigned short* __restrict__ A, const unsigned short* __restrict__ Bt,
    const float* __restrict__ bias, float* __restrict__ Cf, unsigned short* __restrict__ Cb,
    int M, int Ncol, int K, int act, float scale, int gx)
{
  __shared__ unsigned short As[2][128 * 32];
  __shared__ unsigned short Bs[2][128 * 32];
  const int tid = threadIdx.x;
  const int wave = tid >> 6;
  const int lane = tid & 63;

  const int wg = xcd_swz(blockIdx.x, gridDim.x);
  const int col0 = (wg % gx) * 128;
  const int row0 = (wg / gx) * 128;

  const int wrow = (wave >> 1) * 64;
  const int wcol = (wave & 1) * 64;
  const int lrow = lane & 15;
  const int quad = lane >> 4;

  // staging geometry: wave stages tile rows [32*wave, 32*wave+32)
  const int rbase = wave * 32;
  const int lr4 = lane >> 2;      // 0..15
  const int lc = lane & 3;        // 16B slot
  const int tr0 = rbase + lr4;
  const int tr1 = rbase + 16 + lr4;
  int gra0 = row0 + tr0; if (gra0 > M - 1) gra0 = M - 1;  // clamp: rows >= M discarded in epilogue
  int gra1 = row0 + tr1; if (gra1 > M - 1) gra1 = M - 1;
  const int sca0 = (lc ^ ((tr0 >> 1) & 3)) * 8;   // pre-swizzled source slot (elems)
  const int sca1 = (lc ^ ((tr1 >> 1) & 3)) * 8;
  const unsigned short* pa0 = A + (size_t)gra0 * K + sca0;
  const unsigned short* pa1 = A + (size_t)gra1 * K + sca1;
  const unsigned short* pb0 = Bt + (size_t)(col0 + tr0) * K + sca0;
  const unsigned short* pb1 = Bt + (size_t)(col0 + tr1) * K + sca1;

  f32x4 acc[4][4] = {};

  // prologue: stage first K-tile into buf 0
  g2lds16(pa0, &As[0][rbase * 32]);
  g2lds16(pa1, &As[0][(rbase + 16) * 32]);
  g2lds16(pb0, &Bs[0][rbase * 32]);
  g2lds16(pb1, &Bs[0][(rbase + 16) * 32]);
  __syncthreads();

  int cur = 0;
  for (int k0 = 0; k0 < K; k0 += 32) {
    int nxt = cur ^ 1;
    if (k0 + 32 < K) {   // issue next-tile loads (overlap with compute below)
      g2lds16(pa0 + k0 + 32, &As[nxt][rbase * 32]);
      g2lds16(pa1 + k0 + 32, &As[nxt][(rbase + 16) * 32]);
      g2lds16(pb0 + k0 + 32, &Bs[nxt][rbase * 32]);
      g2lds16(pb1 + k0 + 32, &Bs[nxt][(rbase + 16) * 32]);
    }
    bf16x8 afr[4], bfr[4];
#pragma unroll
    for (int mt = 0; mt < 4; ++mt) {
      int rr = wrow + mt * 16 + lrow;
      afr[mt] = *(const bf16x8*)(&As[cur][rr * 32 + ((quad ^ ((rr >> 1) & 3)) << 3)]);
    }
#pragma unroll
    for (int nt = 0; nt < 4; ++nt) {
      int rr = wcol + nt * 16 + lrow;
      bfr[nt] = *(const bf16x8*)(&Bs[cur][rr * 32 + ((quad ^ ((rr >> 1) & 3)) << 3)]);
    }
#pragma unroll
    for (int mt = 0; mt < 4; ++mt)
#pragma unroll
      for (int nt = 0; nt < 4; ++nt)
        acc[mt][nt] = __builtin_amdgcn_mfma_f32_16x16x32_bf16(afr[mt], bfr[nt], acc[mt][nt], 0, 0, 0);
    __syncthreads();   // drains vmcnt (prefetch landed) + lgkm; buffers swap safely
    cur = nxt;
  }

#pragma unroll
  for (int mt = 0; mt < 4; ++mt) {
#pragma unroll
    for (int nt = 0; nt < 4; ++nt) {
      int gcol = col0 + wcol + nt * 16 + lrow;
      float bv = bias ? bias[gcol] : 0.f;
#pragma unroll
      for (int r = 0; r < 4; ++r) {
        int grow = row0 + wrow + mt * 16 + quad * 4 + r;
        if (grow >= M) continue;
        float v = (acc[mt][nt][r] + bv) * scale;
        if (act == 1) v = fmaxf(v, 0.f);
        else if (act == 2) v = (v > 0.f) ? v : (__expf(v) - 1.f);
        if (Cf) Cf[(size_t)grow * Ncol + gcol] = v;
        if (Cb) Cb[(size_t)grow * Ncol + gcol] = f2bf(v);
      }
    }
  }
}

// ---------------- fused pooling-gate GEMM (same dbuf staging, K=256) ----------------
__global__ __launch_bounds__(256) void gemm_gate(
    const unsigned short* __restrict__ A, const unsigned short* __restrict__ Bt,
    const float* __restrict__ bg1, const float* __restrict__ Wg2,
    const float* __restrict__ bg2, float* __restrict__ gate, int M)
{
  __shared__ unsigned short As[2][128 * 32];
  __shared__ unsigned short Bs[2][128 * 32];
  __shared__ float gbuf[128][2];
  const int tid = threadIdx.x;
  const int wave = tid >> 6;
  const int lane = tid & 63;

  const int wg = xcd_swz(blockIdx.x, gridDim.x);
  const int row0 = wg * 128;

  const int wrow = (wave >> 1) * 64;
  const int wcol = (wave & 1) * 64;
  const int lrow = lane & 15;
  const int quad = lane >> 4;

  const int rbase = wave * 32;
  const int lr4 = lane >> 2;
  const int lc = lane & 3;
  const int tr0 = rbase + lr4;
  const int tr1 = rbase + 16 + lr4;
  int gra0 = row0 + tr0; if (gra0 > M - 1) gra0 = M - 1;
  int gra1 = row0 + tr1; if (gra1 > M - 1) gra1 = M - 1;
  const int sca0 = (lc ^ ((tr0 >> 1) & 3)) * 8;
  const int sca1 = (lc ^ ((tr1 >> 1) & 3)) * 8;
  const unsigned short* pa0 = A + (size_t)gra0 * 256 + sca0;
  const unsigned short* pa1 = A + (size_t)gra1 * 256 + sca1;
  const unsigned short* pb0 = Bt + (size_t)tr0 * 256 + sca0;
  const unsigned short* pb1 = Bt + (size_t)tr1 * 256 + sca1;

  f32x4 acc[4][4] = {};

  g2lds16(pa0, &As[0][rbase * 32]);
  g2lds16(pa1, &As[0][(rbase + 16) * 32]);
  g2lds16(pb0, &Bs[0][rbase * 32]);
  g2lds16(pb1, &Bs[0][(rbase + 16) * 32]);
  __syncthreads();

  int cur = 0;
  for (int k0 = 0; k0 < 256; k0 += 32) {
    int nxt = cur ^ 1;
    if (k0 + 32 < 256) {
      g2lds16(pa0 + k0 + 32, &As[nxt][rbase * 32]);
      g2lds16(pa1 + k0 + 32, &As[nxt][(rbase + 16) * 32]);
      g2lds16(pb0 + k0 + 32, &Bs[nxt][rbase * 32]);
      g2lds16(pb1 + k0 + 32, &Bs[nxt][(rbase + 16) * 32]);
    }
    bf16x8 afr[4], bfr[4];
#pragma unroll
    for (int mt = 0; mt < 4; ++mt) {
      int rr = wrow + mt * 16 + lrow;
      afr[mt] = *(const bf16x8*)(&As[cur][rr * 32 + ((quad ^ ((rr >> 1) & 3)) << 3)]);
    }
#pragma unroll
    for (int nt = 0; nt < 4; ++nt) {
      int rr = wcol + nt * 16 + lrow;
      bfr[nt] = *(const bf16x8*)(&Bs[cur][rr * 32 + ((quad ^ ((rr >> 1) & 3)) << 3)]);
    }
#pragma unroll
    for (int mt = 0; mt < 4; ++mt)
#pragma unroll
      for (int nt = 0; nt < 4; ++nt)
        acc[mt][nt] = __builtin_amdgcn_mfma_f32_16x16x32_bf16(afr[mt], bfr[nt], acc[mt][nt], 0, 0, 0);
    __syncthreads();
    cur = nxt;
  }

  float p[4][4];
#pragma unroll
  for (int mt = 0; mt < 4; ++mt)
#pragma unroll
    for (int r = 0; r < 4; ++r) p[mt][r] = 0.f;
#pragma unroll
  for (int nt = 0; nt < 4; ++nt) {
    int gcol = wcol + nt * 16 + lrow;
    float b1v = bg1[gcol];
    float w2v = Wg2[gcol];
#pragma unroll
    for (int mt = 0; mt < 4; ++mt)
#pragma unroll
      for (int r = 0; r < 4; ++r) {
        float v = fmaxf(acc[mt][nt][r] + b1v, 0.f);
        p[mt][r] = fmaf(v, w2v, p[mt][r]);
      }
  }
#pragma unroll
  for (int mt = 0; mt < 4; ++mt)
#pragma unroll
    for (int r = 0; r < 4; ++r) {
      float v = p[mt][r];
      v += __shfl_xor(v, 1);
      v += __shfl_xor(v, 2);
      v += __shfl_xor(v, 4);
      v += __shfl_xor(v, 8);
      if (lrow == 0) gbuf[wrow + mt * 16 + quad * 4 + r][wcol >> 6] = v;
    }
  __syncthreads();
  if (tid < 128) {
    int grow = row0 + tid;
    if (grow < M) gate[grow] = gbuf[tid][0] + gbuf[tid][1] + bg2[0];
  }
}

// ---------------- f32 GEMM for the tiny readout layers ----------------
__global__ __launch_bounds__(256) void gemm_f32(
    const float* __restrict__ A, const float* __restrict__ B,
    const float* __restrict__ bias, float* __restrict__ C,
    int M, int Ncol, int K, int act, float scale)
{
  __shared__ float As[32][68];
  __shared__ float Bs[32][68];
  const int tid = threadIdx.x;
  const int tx = tid & 15, ty = tid >> 4;
  const int col0 = blockIdx.x * 64;
  const int row0 = blockIdx.y * 64;
  float acc[4][4];
#pragma unroll
  for (int i = 0; i < 4; ++i)
#pragma unroll
    for (int j = 0; j < 4; ++j) acc[i][j] = 0.f;

  const int ar = tid >> 3;
  const int ak = (tid & 7) * 4;
  const int bk = tid >> 4;
  const int bc = (tid & 15) * 4;

  for (int k0 = 0; k0 < K; k0 += 32) {
#pragma unroll
    for (int p = 0; p < 2; ++p) {
      int r = ar + p * 32;
      int grow = row0 + r;
      float4 v = make_float4(0.f, 0.f, 0.f, 0.f);
      if (grow < M) v = *(const float4*)(A + (size_t)grow * K + k0 + ak);
      As[ak + 0][r] = v.x; As[ak + 1][r] = v.y; As[ak + 2][r] = v.z; As[ak + 3][r] = v.w;
    }
#pragma unroll
    for (int p = 0; p < 2; ++p) {
      int kk = bk + p * 16;
      float4 v = *(const float4*)(B + (size_t)(k0 + kk) * Ncol + col0 + bc);
      *(float4*)(&Bs[kk][bc]) = v;
    }
    __syncthreads();
#pragma unroll
    for (int kk = 0; kk < 32; ++kk) {
      float4 a = *(const float4*)(&As[kk][ty * 4]);
      float4 b = *(const float4*)(&Bs[kk][tx * 4]);
      float av[4] = {a.x, a.y, a.z, a.w};
      float bv[4] = {b.x, b.y, b.z, b.w};
#pragma unroll
      for (int i = 0; i < 4; ++i)
#pragma unroll
        for (int j = 0; j < 4; ++j) acc[i][j] = fmaf(av[i], bv[j], acc[i][j]);
    }
    __syncthreads();
  }
  float bvals[4] = {0.f, 0.f, 0.f, 0.f};
  if (bias) {
#pragma unroll
    for (int j = 0; j < 4; ++j) bvals[j] = bias[col0 + tx * 4 + j];
  }
#pragma unroll
  for (int i = 0; i < 4; ++i) {
    int r = row0 + ty * 4 + i;
    if (r >= M) continue;
    float4 outv;
    float* o = (float*)&outv;
#pragma unroll
    for (int j = 0; j < 4; ++j) {
      float v = (acc[i][j] + bvals[j]) * scale;
      if (act == 1) v = fmaxf(v, 0.f);
      else if (act == 2) v = (v > 0.f) ? v : (__expf(v) - 1.f);
      o[j] = v;
    }
    *(float4*)(C + (size_t)r * Ncol + col0 + tx * 4) = outv;
  }
}

// ---------------- PASS A: edge-parallel logits (real edges only) ----------------
__global__ __launch_bounds__(256) void logits_kernel(
    const unsigned short* __restrict__ xlr,
    const int* __restrict__ ei, const float* __restrict__ eattr,
    const float* __restrict__ We, const float* __restrict__ att,
    float* __restrict__ logits)
{
  const int lane = threadIdx.x & 63;
  const int wv = threadIdx.x >> 6;
  const int c0 = lane * 4;
  const int head = lane >> 3;

  float4 attf4 = *(const float4*)(att + c0);
  float attf[4] = {attf4.x, attf4.y, attf4.z, attf4.w};
  float wef[10][4];
#pragma unroll
  for (int k = 0; k < 10; ++k) {
    float4 w4 = *(const float4*)(We + k * 256 + c0);
    wef[k][0] = w4.x; wef[k][1] = w4.y; wef[k][2] = w4.z; wef[k][3] = w4.w;
  }

  auto edge_logit = [&](int e) {
    int src = ei[e];
    int tgt = ei[N_EDGES + e];
    const float* eap = eattr + (size_t)e * 10;
    float2 q0 = *(const float2*)(eap + 0);
    float2 q1 = *(const float2*)(eap + 2);
    float2 q2 = *(const float2*)(eap + 4);
    float2 q3 = *(const float2*)(eap + 6);
    float2 q4 = *(const float2*)(eap + 8);
    ushort4 ua = *(const ushort4*)(xlr + (size_t)src * 512 + c0);
    ushort4 ub = *(const ushort4*)(xlr + (size_t)tgt * 512 + 256 + c0);
    float ev[10] = {q0.x, q0.y, q1.x, q1.y, q2.x, q2.y, q3.x, q3.y, q4.x, q4.y};
    float p0 = 0.f, p1 = 0.f, p2 = 0.f, p3 = 0.f;
#pragma unroll
    for (int k = 0; k < 10; ++k) {
      p0 = fmaf(ev[k], wef[k][0], p0);
      p1 = fmaf(ev[k], wef[k][1], p1);
      p2 = fmaf(ev[k], wef[k][2], p2);
      p3 = fmaf(ev[k], wef[k][3], p3);
    }
    float s0 = bf2f(ua.x) + bf2f(ub.x) + p0;
    float s1 = bf2f(ua.y) + bf2f(ub.y) + p1;
    float s2 = bf2f(ua.z) + bf2f(ub.z) + p2;
    float s3 = bf2f(ua.w) + bf2f(ub.w) + p3;
    s0 = (s0 > 0.f) ? s0 : 0.2f * s0;
    s1 = (s1 > 0.f) ? s1 : 0.2f * s1;
    s2 = (s2 > 0.f) ? s2 : 0.2f * s2;
    s3 = (s3 > 0.f) ? s3 : 0.2f * s3;
    float part = s0 * attf[0] + s1 * attf[1] + s2 * attf[2] + s3 * attf[3];
    part += __shfl_xor(part, 1);
    part += __shfl_xor(part, 2);
    part += __shfl_xor(part, 4);
    if ((lane & 7) == 0) logits[(size_t)e * 8 + head] = part;
  };

  const int nw = gridDim.x * 4;
  const int e0 = (blockIdx.x * 4 + wv) * 2;
  for (int e = e0; e < N_EDGES; e += nw * 2) {
    edge_logit(e);
    if (e + 1 < N_EDGES) edge_logit(e + 1);
  }
}

// ---------------- PASS B: node-parallel softmax + aggregate + BN/ELU/residual ----------------
__global__ __launch_bounds__(256) void attn_kernel(
    const unsigned short* __restrict__ xlr,
    float* __restrict__ h, unsigned short* __restrict__ hb,
    const int* __restrict__ ei, const float* __restrict__ logits,
    const float* __restrict__ att, const float* __restrict__ bgat,
    const float* __restrict__ ep_self,
    const int* __restrict__ rowptr, const int* __restrict__ csr)
{
  const int lane = threadIdx.x & 63;
  const int wv = threadIdx.x >> 6;
  const int n = blockIdx.x * 4 + wv;
  if (n >= N_NODES) return;
  const int c0 = lane * 4;
  const int head = lane >> 3;

  const int s = rowptr[n], e = rowptr[n + 1];

  ushort4 ul = *(const ushort4*)(xlr + (size_t)n * 512 + c0);        // xl[n]
  ushort4 ur = *(const ushort4*)(xlr + (size_t)n * 512 + 256 + c0);  // xr[n]
  float4 hold = *(const float4*)(h + (size_t)n * HIDDEN + c0);
  float4 attf = *(const float4*)(att + c0);
  float4 eps = *(const float4*)(ep_self + c0);

  float xln[4] = {bf2f(ul.x), bf2f(ul.y), bf2f(ul.z), bf2f(ul.w)};

  // self-loop logit
  float lself;
  {
    float s0 = xln[0] + bf2f(ur.x) + eps.x;
    float s1 = xln[1] + bf2f(ur.y) + eps.y;
    float s2 = xln[2] + bf2f(ur.z) + eps.z;
    float s3 = xln[3] + bf2f(ur.w) + eps.w;
    s0 = (s0 > 0.f) ? s0 : 0.2f * s0;
    s1 = (s1 > 0.f) ? s1 : 0.2f * s1;
    s2 = (s2 > 0.f) ? s2 : 0.2f * s2;
    s3 = (s3 > 0.f) ? s3 : 0.2f * s3;
    float part = s0 * attf.x + s1 * attf.y + s2 * attf.z + s3 * attf.w;
    part += __shfl_xor(part, 1);
    part += __shfl_xor(part, 2);
    part += __shfl_xor(part, 4);
    lself = part;
  }

  // loop1: max over real in-edge logits
  float m = lself;
  const int elast = e - 1;
  for (int idx = s; idx < e; idx += 4) {
    int i1 = idx + 1, i2 = idx + 2, i3 = idx + 3;
    int eid0 = csr[idx];
    int eid1 = csr[(i1 <= elast) ? i1 : elast];
    int eid2 = csr[(i2 <= elast) ? i2 : elast];
    int eid3 = csr[(i3 <= elast) ? i3 : elast];
    float l0 = logits[(size_t)eid0 * 8 + head];
    float l1 = logits[(size_t)eid1 * 8 + head];
    float l2 = logits[(size_t)eid2 * 8 + head];
    float l3 = logits[(size_t)eid3 * 8 + head];
    m = fmaxf(fmaxf(m, fmaxf(l0, l1)), fmaxf(l2, l3));
  }

  // loop2: independent accumulate
  float wself = __expf(lself - m);
  float d = wself;
  float a0 = wself * xln[0], a1 = wself * xln[1], a2 = wself * xln[2], a3 = wself * xln[3];
  for (int idx = s; idx < e; idx += 2) {
    int i1 = idx + 1;
    bool v1 = (i1 <= elast);
    int eid0 = csr[idx];
    int eid1 = csr[v1 ? i1 : elast];
    float l0 = logits[(size_t)eid0 * 8 + head];
    float l1 = logits[(size_t)eid1 * 8 + head];
    int s0 = ei[eid0];
    int s1 = ei[eid1];
    float w0 = __expf(l0 - m);
    float w1 = v1 ? __expf(l1 - m) : 0.f;
    ushort4 u0 = *(const ushort4*)(xlr + (size_t)s0 * 512 + c0);
    ushort4 u1 = *(const ushort4*)(xlr + (size_t)s1 * 512 + c0);
    d += w0 + w1;
    a0 += w0 * bf2f(u0.x) + w1 * bf2f(u1.x);
    a1 += w0 * bf2f(u0.y) + w1 * bf2f(u1.y);
    a2 += w0 * bf2f(u0.z) + w1 * bf2f(u1.z);
    a3 += w0 * bf2f(u0.w) + w1 * bf2f(u1.w);
  }

  float inv = 1.f / (d + 1e-16f);
  float4 bg = *(const float4*)(bgat + c0);
  float ov[4] = {a0 * inv, a1 * inv, a2 * inv, a3 * inv};
  float bgv[4] = {bg.x, bg.y, bg.z, bg.w};
  float hv[4] = {hold.x, hold.y, hold.z, hold.w};
  float4 res;
  float* rp = (float*)&res;
  ushort4 resb;
  unsigned short* rb = (unsigned short*)&resb;
#pragma unroll
  for (int j = 0; j < 4; ++j) {
    float v = (ov[j] + bgv[j]) * BN_S;
    v = (v > 0.f) ? v : (__expf(v) - 1.f);
    float nv = v + hv[j];
    rp[j] = nv;
    rb[j] = f2bf(nv);
  }
  *(float4*)(h + (size_t)n * HIDDEN + c0) = res;
  *(ushort4*)(hb + (size_t)n * HIDDEN + c0) = resb;
}

// ---------------- global attention pooling per graph ----------------
__global__ __launch_bounds__(64) void pool_kernel(
    const float* __restrict__ gate, const float* __restrict__ h,
    const int* __restrict__ brp, float* __restrict__ pooled)
{
  int b = blockIdx.x;
  int lane = threadIdx.x;
  int s = brp[b], e = brp[b + 1];
  float m = -__builtin_inff();
  for (int i = s + lane; i < e; i += 64) m = fmaxf(m, gate[i]);
#pragma unroll
  for (int o = 1; o < 64; o <<= 1) m = fmaxf(m, __shfl_xor(m, o));
  float d = 0.f;
  for (int i = s + lane; i < e; i += 64) d += __expf(gate[i] - m);
#pragma unroll
  for (int o = 1; o < 64; o <<= 1) d += __shfl_xor(d, o);
  float inv = 1.f / (d + 1e-16f);
  int c0 = lane * 4;
  float acc[4] = {0.f, 0.f, 0.f, 0.f};
  for (int i = s; i < e; ++i) {
    float w = __expf(gate[i] - m) * inv;
    float4 hv = *(const float4*)(h + (size_t)i * HIDDEN + c0);
    acc[0] = fmaf(w, hv.x, acc[0]);
    acc[1] = fmaf(w, hv.y, acc[1]);
    acc[2] = fmaf(w, hv.z, acc[2]);
    acc[3] = fmaf(w, hv.w, acc[3]);
  }
  float4 outv = make_float4(acc[0], acc[1], acc[2], acc[3]);
  *(float4*)(pooled + (size_t)b * HIDDEN + c0) = outv;
}

// ---------------- final: out[b] = r3[b,:] . W4 + b4 ----------------
__global__ __launch_bounds__(256) void out_kernel(
    const float* __restrict__ r3, const float* __restrict__ W4,
    const float* __restrict__ b4, float* __restrict__ out)
{
  int lane = threadIdx.x & 63;
  int wv = threadIdx.x >> 6;
  int b = blockIdx.x * 4 + wv;
  if (b >= N_B) return;
  float v = r3[(size_t)b * 64 + lane] * W4[lane];
#pragma unroll
  for (int o = 1; o < 64; o <<= 1) v += __shfl_xor(v, o);
  if (lane == 0) out[b] = v + b4[0];
}

extern "C" void kernel_launch(void* const* d_in, const int* in_sizes, int n_in,
                              void* d_out, int out_size, void* d_ws, size_t ws_size,
                              hipStream_t stream)
{
  const float* x    = (const float*)d_in[0];
  const int* ei     = (const int*)d_in[1];
  const float* ea   = (const float*)d_in[2];
  const int* batch  = (const int*)d_in[3];
  const float* W_in = (const float*)d_in[4];
  const float* b_in = (const float*)d_in[5];
  const float* Wl   = (const float*)d_in[6];
  const float* Wr   = (const float*)d_in[7];
  const float* We   = (const float*)d_in[8];
  const float* att  = (const float*)d_in[9];
  const float* bgat = (const float*)d_in[10];
  const float* Wg1  = (const float*)d_in[11];
  const float* bg1  = (const float*)d_in[12];
  const float* Wg2  = (const float*)d_in[13];
  const float* bg2  = (const float*)d_in[14];
  const float* W1   = (const float*)d_in[15];
  const float* b1   = (const float*)d_in[16];
  const float* W2   = (const float*)d_in[17];
  const float* b2   = (const float*)d_in[18];
  const float* W3   = (const float*)d_in[19];
  const float* b3   = (const float*)d_in[20];
  const float* W4   = (const float*)d_in[21];
  const float* b4   = (const float*)d_in[22];
  float* out = (float*)d_out;

  char* ws = (char*)d_ws;
  size_t off = 0;
  auto alloc = [&](size_t bytes) -> char* {
    char* p = ws + off;
    off += (bytes + 255) & ~(size_t)255;
    return p;
  };
  float* h            = (float*)alloc((size_t)N_NODES * HIDDEN * 4);           // 102.4 MB
  unsigned short* hb  = (unsigned short*)alloc((size_t)N_NODES * HIDDEN * 2);  // 51.2 MB
  unsigned short* xlr = (unsigned short*)alloc((size_t)N_NODES * 512 * 2);     // 102.4 MB
  int* deg       = (int*)alloc((size_t)N_NODES * 4);
  int* rowptr    = (int*)alloc((size_t)(N_NODES + 1) * 4);
  int* cursor    = (int*)alloc((size_t)N_NODES * 4);
  int* csr       = (int*)alloc((size_t)N_EDGES * 4);       // real edges only
  int* brp       = (int*)alloc((size_t)(N_B + 1) * 4);
  int* bsum      = (int*)alloc(512);
  float* macc    = (float*)alloc(64);
  float* meanattr= (float*)alloc(64);
  float* ep_self = (float*)alloc(4 * 256 * 4);
  float* logits  = (float*)alloc((size_t)N_EDGES * 8 * 4); // 7.04 MB
  unsigned short* Wint  = (unsigned short*)alloc(256 * 96 * 2);       // [256][96]
  unsigned short* Wlrt  = (unsigned short*)alloc(4 * 512 * 256 * 2);  // [i][512][256] = Wl^T || Wr^T
  unsigned short* Wg1t  = (unsigned short*)alloc(128 * 256 * 2);      // [128][256]
  // total ≈ 266.3 MB < 268.4 MB ws  ✓

  // aliases into dead regions of xlr:
  unsigned short* xpad = xlr;            // [N,96] bf16, pre-layer0 only
  float* base2  = (float*)xlr;           // xlr fully dead after last attn layer
  float* gate   = base2;                 // [N] f32
  float* pooled = base2 + 1000000;       // [B,256] f32
  float* r1     = base2 + 3000000;       // [B,256] f32
  float* r2     = base2 + 5000000;       // [B,128] f32
  float* r3     = base2 + 6000000;       // [B,64]  f32

  if (ws_size < off) {
    hipMemsetAsync(d_out, 0, (size_t)out_size * 4, stream);
    return;
  }

  zero_kernel<<<391, 256, 0, stream>>>(deg, cursor, macc);
  mean_kernel<<<64, 256, 0, stream>>>(ea, macc);
  meanattr_kernel<<<1, 64, 0, stream>>>(macc, meanattr);
  epself_kernel<<<4, 256, 0, stream>>>(meanattr, We, ep_self);
  count_kernel<<<860, 256, 0, stream>>>(ei, deg);
  scan1_kernel<<<NSCANB, 1024, 0, stream>>>(deg, rowptr, bsum);
  scan2_kernel<<<1, 128, 0, stream>>>(bsum);
  scan3_kernel<<<NSCANB, 1024, 0, stream>>>(rowptr, bsum);
  scatter_kernel<<<860, 256, 0, stream>>>(ei, rowptr, cursor, csr);
  brp_kernel<<<512, 256, 0, stream>>>(batch, brp);

  // weight conversions (transpose + bf16)
  wt_kernel<<<(256 * 96 + 255) / 256, 256, 0, stream>>>(W_in, Wint, 75, 96, 256);
  wlr_kernel<<<512, 256, 0, stream>>>(Wl, Wr, Wlrt);
  wt_kernel<<<128, 256, 0, stream>>>(Wg1, Wg1t, 256, 256, 128);
  convx_kernel<<<4096, 256, 0, stream>>>(x, xpad);

  // input projection: h = elu((x @ W_in + b_in) * BN_S)  [MFMA, K=96]
  gemm_mfma<<<1564, 256, 0, stream>>>(xpad, Wint, b_in, h, hb,
                                      N_NODES, 256, 96, 2, BN_S, 2);

  for (int i = 0; i < 4; ++i) {
    // fused xl||xr GEMM: [N,256] @ [256,512] -> xlr [N,512]
    gemm_mfma<<<3128, 256, 0, stream>>>(hb, Wlrt + (size_t)i * 131072, nullptr,
                                        nullptr, xlr, N_NODES, 512, 256, 0, 1.f, 4);
    // pass A: edge-parallel logits
    logits_kernel<<<2048, 256, 0, stream>>>(xlr, ei, ea, We + (size_t)i * 2560,
                                            att + (size_t)i * 256, logits);
    // pass B: node-parallel softmax + aggregate
    attn_kernel<<<25000, 256, 0, stream>>>(xlr, h, hb, ei, logits,
                                           att + (size_t)i * 256, bgat + (size_t)i * 256,
                                           ep_self + (size_t)i * 256, rowptr, csr);
  }

  // fused pooling gate: gate = relu(hb @ Wg1 + bg1) . Wg2 + bg2
  gemm_gate<<<782, 256, 0, stream>>>(hb, Wg1t, bg1, Wg2, bg2, gate, N_NODES);
  pool_kernel<<<N_B, 64, 0, stream>>>(gate, h, brp, pooled);

  // readout MLP (f32, tiny)
  gemm_f32<<<dim3(4, 64), 256, 0, stream>>>(pooled, W1, b1, r1, N_B, 256, 256, 1, BN_S);
  gemm_f32<<<dim3(2, 64), 256, 0, stream>>>(r1, W2, b2, r2, N_B, 128, 256, 1, BN_S);
  gemm_f32<<<dim3(1, 64), 256, 0, stream>>>(r2, W3, b3, r3, N_B, 64, 128, 1, 1.f);
  out_kernel<<<1024, 256, 0, stream>>>(r3, W4, b4, out);
}

// Round 8
// 1220.301 us; speedup vs baseline: 1.2722x; 1.1122x over previous
//
#include <hip/hip_runtime.h>

#define N_NODES 100000
#define N_EDGES 220000
#define N_B     4096
#define HIDDEN  256
#define BN_S    0.9999950000374997f
#define NSCANB  98       // ceil(100000/1024)

typedef __attribute__((ext_vector_type(8))) short bf16x8;
typedef __attribute__((ext_vector_type(4))) float f32x4;

__device__ __forceinline__ float bf2f(unsigned short u) {
  return __uint_as_float(((unsigned int)u) << 16);
}
__device__ __forceinline__ unsigned short f2bf(float f) {
  unsigned int x = __float_as_uint(f);
  unsigned int lsb = (x >> 16) & 1u;
  x += 0x7fffu + lsb;
  return (unsigned short)(x >> 16);
}

// async global->LDS 16B: dest is wave-uniform base + lane*16 (linear);
// per-lane GLOBAL address carries the XOR swizzle (m173 pattern).
__device__ __forceinline__ void g2lds16(const void* g, void* l) {
  __builtin_amdgcn_global_load_lds(
      (const __attribute__((address_space(1))) unsigned int*)g,
      (__attribute__((address_space(3))) unsigned int*)l, 16, 0, 0);
}

// bijective XCD swizzle (m204)
__device__ __forceinline__ int xcd_swz(int b, int nwg) {
  int q = nwg >> 3, r = nwg & 7;
  int xcd = b & 7, idx = b >> 3;
  int base = (xcd < r) ? xcd * (q + 1) : r * (q + 1) + (xcd - r) * q;
  return base + idx;
}

// ---------------- zero-init of counters ----------------
__global__ void zero_kernel(int* __restrict__ deg, int* __restrict__ cursor, float* __restrict__ macc) {
  int i = blockIdx.x * blockDim.x + threadIdx.x;
  if (i < N_NODES) { deg[i] = 0; cursor[i] = 0; }
  if (i < 16) macc[i] = 0.f;
}

// ---------------- mean of edge_attr (block-reduced, 1 atomic/k/block) ----------------
__global__ __launch_bounds__(256) void mean_kernel(const float* __restrict__ ea, float* __restrict__ macc) {
  __shared__ float sred[4][16];
  int lane = threadIdx.x & 63;
  int wv = threadIdx.x >> 6;
  float loc[10];
#pragma unroll
  for (int k = 0; k < 10; ++k) loc[k] = 0.f;
  for (int e = blockIdx.x * blockDim.x + threadIdx.x; e < N_EDGES; e += gridDim.x * blockDim.x) {
    const float* p = ea + (size_t)e * 10;
#pragma unroll
    for (int k = 0; k < 10; ++k) loc[k] += p[k];
  }
#pragma unroll
  for (int k = 0; k < 10; ++k) {
    float v = loc[k];
#pragma unroll
    for (int o = 1; o < 64; o <<= 1) v += __shfl_xor(v, o);
    if (lane == 0) sred[wv][k] = v;
  }
  __syncthreads();
  if (threadIdx.x < 10) {
    float s = sred[0][threadIdx.x] + sred[1][threadIdx.x] +
              sred[2][threadIdx.x] + sred[3][threadIdx.x];
    atomicAdd(&macc[threadIdx.x], s);
  }
}

__global__ void meanattr_kernel(const float* __restrict__ macc, float* __restrict__ meanattr) {
  int t = threadIdx.x;
  const float invE = 1.f / (float)N_EDGES;
  if (t < 10) meanattr[t] = macc[t] * invE;
}

// ---------------- ep_self[i][c] = meanattr . We[i][:,c] ----------------
__global__ void epself_kernel(const float* __restrict__ meanattr, const float* __restrict__ We,
                              float* __restrict__ ep_self) {
  int i = blockIdx.x;
  int c = threadIdx.x;
  float s = 0.f;
#pragma unroll
  for (int k = 0; k < 10; ++k)
    s += meanattr[k] * We[(size_t)i * 2560 + k * 256 + c];
  ep_self[i * 256 + c] = s;
}

// ---------------- CSR build (REAL edges only) ----------------
__global__ void count_kernel(const int* __restrict__ ei, int* __restrict__ deg) {
  for (int e = blockIdx.x * blockDim.x + threadIdx.x; e < N_EDGES; e += gridDim.x * blockDim.x) {
    atomicAdd(&deg[ei[N_EDGES + e]], 1);
  }
}

// ---------------- 3-phase scan ----------------
__global__ __launch_bounds__(1024) void scan1_kernel(const int* __restrict__ deg,
                                                     int* __restrict__ rowptr,
                                                     int* __restrict__ bsum) {
  __shared__ int buf[1024];
  int t = threadIdx.x;
  int i = blockIdx.x * 1024 + t;
  int v = (i < N_NODES) ? deg[i] : 0;
  buf[t] = v;
  __syncthreads();
  for (int off = 1; off < 1024; off <<= 1) {
    int add = (t >= off) ? buf[t - off] : 0;
    __syncthreads();
    buf[t] += add;
    __syncthreads();
  }
  if (i < N_NODES) rowptr[i + 1] = buf[t];
  if (t == 1023) bsum[blockIdx.x] = buf[t];
  if (i == 0) rowptr[0] = 0;
}

__global__ __launch_bounds__(128) void scan2_kernel(int* __restrict__ bsum) {
  __shared__ int buf[128];
  int t = threadIdx.x;
  int v = (t < NSCANB) ? bsum[t] : 0;
  buf[t] = v;
  __syncthreads();
  for (int off = 1; off < 128; off <<= 1) {
    int add = (t >= off) ? buf[t - off] : 0;
    __syncthreads();
    buf[t] += add;
    __syncthreads();
  }
  if (t < NSCANB) bsum[t] = buf[t];
}

__global__ __launch_bounds__(1024) void scan3_kernel(int* __restrict__ rowptr,
                                                     const int* __restrict__ bsum) {
  int b = blockIdx.x;
  if (b == 0) return;
  int i = b * 1024 + threadIdx.x;
  if (i < N_NODES) rowptr[i + 1] += bsum[b - 1];
}

__global__ void scatter_kernel(const int* __restrict__ ei, const int* __restrict__ rowptr,
                               int* __restrict__ cursor, int* __restrict__ csr) {
  for (int e = blockIdx.x * blockDim.x + threadIdx.x; e < N_EDGES; e += gridDim.x * blockDim.x) {
    int t = ei[N_EDGES + e];
    int pos = atomicAdd(&cursor[t], 1);
    csr[rowptr[t] + pos] = e;
  }
}

__global__ void brp_kernel(const int* __restrict__ batch, int* __restrict__ brp) {
  for (int i = blockIdx.x * blockDim.x + threadIdx.x; i < N_NODES; i += gridDim.x * blockDim.x) {
    int bi = batch[i];
    int bp = (i == 0) ? -1 : batch[i - 1];
    for (int b = bp + 1; b <= bi; ++b) brp[b] = i;
    if (i == N_NODES - 1) {
      for (int b = bi + 1; b <= N_B; ++b) brp[b] = N_NODES;
    }
  }
}

// ---------------- x -> padded bf16 [N,96] ----------------
__global__ void convx_kernel(const float* __restrict__ x, unsigned short* __restrict__ xp) {
  int total = N_NODES * 96;
  for (int idx = blockIdx.x * blockDim.x + threadIdx.x; idx < total; idx += gridDim.x * blockDim.x) {
    int nn = idx / 96;
    int j = idx - nn * 96;
    unsigned short v = 0;
    if (j < 75) v = f2bf(x[(size_t)nn * 75 + j]);
    xp[idx] = v;
  }
}

// ---------------- weight transpose+bf16 ----------------
__global__ void wt_kernel(const float* __restrict__ src, unsigned short* __restrict__ dst,
                          int K, int Kp, int N) {
  int idx = blockIdx.x * blockDim.x + threadIdx.x;
  int total = N * Kp;
  if (idx >= total) return;
  int n = idx / Kp, k = idx - n * Kp;
  dst[idx] = (k < K) ? f2bf(src[(size_t)k * N + n]) : (unsigned short)0;
}

// ---------------- all 4 layers Wl^T||Wr^T in one launch ----------------
__global__ void wlr_kernel(const float* __restrict__ Wl, const float* __restrict__ Wr,
                           unsigned short* __restrict__ dst) {
  const int total = 4 * 512 * 256;
  for (int idx = blockIdx.x * blockDim.x + threadIdx.x; idx < total; idx += gridDim.x * blockDim.x) {
    int i = idx >> 17;          // /131072
    int rem = idx & 131071;
    int n = rem >> 8;           // 0..511
    int k = rem & 255;
    float v = (n < 256) ? Wl[(size_t)i * 65536 + k * 256 + n]
                        : Wr[(size_t)i * 65536 + k * 256 + (n - 256)];
    dst[idx] = f2bf(v);
  }
}

// ---------------- bf16 MFMA GEMM, single-buffer staging + LDS-staged C-write ----------------
// K-loop: R6 structure (proven). Epilogue: bf16 C staged through LDS in two
// 64-row passes -> 16B coalesced stores (replaces 64 scalar 2B stores/thread).
__global__ __launch_bounds__(256) void gemm_mfma(
    const unsigned short* __restrict__ A, const unsigned short* __restrict__ Bt,
    const float* __restrict__ bias, float* __restrict__ Cf, unsigned short* __restrict__ Cb,
    int M, int Ncol, int K, int act, float scale, int gx)
{
  __shared__ unsigned short smem[64 * 136];   // 17408 B: As(8KB)+Bs(8KB) during loop, C-stage after
  unsigned short* As = smem;                  // [128*32]
  unsigned short* Bs = smem + 4096;           // [128*32]
  const int tid = threadIdx.x;
  const int wave = tid >> 6;
  const int lane = tid & 63;

  const int wg = xcd_swz(blockIdx.x, gridDim.x);
  const int col0 = (wg % gx) * 128;
  const int row0 = (wg / gx) * 128;

  const int wrow = (wave >> 1) * 64;
  const int wcol = (wave & 1) * 64;
  const int lrow = lane & 15;
  const int quad = lane >> 4;

  // staging geometry: wave stages tile rows [32*wave, 32*wave+32)
  const int rbase = wave * 32;
  const int lr4 = lane >> 2;      // 0..15
  const int lc = lane & 3;        // 16B slot
  const int tr0 = rbase + lr4;
  const int tr1 = rbase + 16 + lr4;
  int gra0 = row0 + tr0; if (gra0 > M - 1) gra0 = M - 1;  // clamp: rows >= M discarded in epilogue
  int gra1 = row0 + tr1; if (gra1 > M - 1) gra1 = M - 1;
  const int sca0 = (lc ^ ((tr0 >> 1) & 3)) * 8;   // pre-swizzled source slot (elems)
  const int sca1 = (lc ^ ((tr1 >> 1) & 3)) * 8;
  const unsigned short* pa0 = A + (size_t)gra0 * K + sca0;
  const unsigned short* pa1 = A + (size_t)gra1 * K + sca1;
  const unsigned short* pb0 = Bt + (size_t)(col0 + tr0) * K + sca0;
  const unsigned short* pb1 = Bt + (size_t)(col0 + tr1) * K + sca1;

  f32x4 acc[4][4] = {};

  for (int k0 = 0; k0 < K; k0 += 32) {
    g2lds16(pa0 + k0, &As[rbase * 32]);
    g2lds16(pa1 + k0, &As[(rbase + 16) * 32]);
    g2lds16(pb0 + k0, &Bs[rbase * 32]);
    g2lds16(pb1 + k0, &Bs[(rbase + 16) * 32]);
    __syncthreads();   // drains vmcnt (global_load_lds) before LDS reads
    bf16x8 afr[4], bfr[4];
#pragma unroll
    for (int mt = 0; mt < 4; ++mt) {
      int rr = wrow + mt * 16 + lrow;
      afr[mt] = *(const bf16x8*)(&As[rr * 32 + ((quad ^ ((rr >> 1) & 3)) << 3)]);
    }
#pragma unroll
    for (int nt = 0; nt < 4; ++nt) {
      int rr = wcol + nt * 16 + lrow;
      bfr[nt] = *(const bf16x8*)(&Bs[rr * 32 + ((quad ^ ((rr >> 1) & 3)) << 3)]);
    }
#pragma unroll
    for (int mt = 0; mt < 4; ++mt)
#pragma unroll
      for (int nt = 0; nt < 4; ++nt)
        acc[mt][nt] = __builtin_amdgcn_mfma_f32_16x16x32_bf16(afr[mt], bfr[nt], acc[mt][nt], 0, 0, 0);
    __syncthreads();
  }

  // ---- epilogue: two 64-row passes through LDS, coalesced 16B bf16 stores ----
#pragma unroll
  for (int p = 0; p < 2; ++p) {
#pragma unroll
    for (int mtl = 0; mtl < 2; ++mtl) {
      int mt = 2 * p + mtl;
#pragma unroll
      for (int nt = 0; nt < 4; ++nt) {
        int lcol = wcol + nt * 16 + lrow;
        float bv = bias ? bias[col0 + lcol] : 0.f;
#pragma unroll
        for (int r = 0; r < 4; ++r) {
          float v = (acc[mt][nt][r] + bv) * scale;
          if (act == 1) v = fmaxf(v, 0.f);
          else if (act == 2) v = (v > 0.f) ? v : (__expf(v) - 1.f);
          int srow = (wave >> 1) * 32 + mtl * 16 + quad * 4 + r;
          smem[srow * 136 + lcol] = f2bf(v);
          if (Cf) {
            int grow = row0 + wrow + mt * 16 + quad * 4 + r;
            if (grow < M) Cf[(size_t)grow * Ncol + col0 + lcol] = v;
          }
        }
      }
    }
    __syncthreads();
    if (Cb) {
#pragma unroll
      for (int round = 0; round < 4; ++round) {
        int s_r = round * 16 + (tid >> 4);
        int ce = (tid & 15) * 8;
        int w2 = s_r >> 5, mtl = (s_r >> 4) & 1, rr = s_r & 15;
        int grow = row0 + w2 * 64 + (2 * p + mtl) * 16 + rr;
        if (grow < M) {
          uint4 v = *(const uint4*)(&smem[s_r * 136 + ce]);
          *(uint4*)(Cb + (size_t)grow * Ncol + col0 + ce) = v;
        }
      }
    }
    __syncthreads();
  }
}

// ---------------- fused pooling-gate GEMM (single-buffer staging, K=256) ----------------
__global__ __launch_bounds__(256) void gemm_gate(
    const unsigned short* __restrict__ A, const unsigned short* __restrict__ Bt,
    const float* __restrict__ bg1, const float* __restrict__ Wg2,
    const float* __restrict__ bg2, float* __restrict__ gate, int M)
{
  __shared__ unsigned short As[128 * 32];
  __shared__ unsigned short Bs[128 * 32];
  __shared__ float gbuf[128][2];
  const int tid = threadIdx.x;
  const int wave = tid >> 6;
  const int lane = tid & 63;

  const int wg = xcd_swz(blockIdx.x, gridDim.x);
  const int row0 = wg * 128;

  const int wrow = (wave >> 1) * 64;
  const int wcol = (wave & 1) * 64;
  const int lrow = lane & 15;
  const int quad = lane >> 4;

  const int rbase = wave * 32;
  const int lr4 = lane >> 2;
  const int lc = lane & 3;
  const int tr0 = rbase + lr4;
  const int tr1 = rbase + 16 + lr4;
  int gra0 = row0 + tr0; if (gra0 > M - 1) gra0 = M - 1;
  int gra1 = row0 + tr1; if (gra1 > M - 1) gra1 = M - 1;
  const int sca0 = (lc ^ ((tr0 >> 1) & 3)) * 8;
  const int sca1 = (lc ^ ((tr1 >> 1) & 3)) * 8;
  const unsigned short* pa0 = A + (size_t)gra0 * 256 + sca0;
  const unsigned short* pa1 = A + (size_t)gra1 * 256 + sca1;
  const unsigned short* pb0 = Bt + (size_t)tr0 * 256 + sca0;
  const unsigned short* pb1 = Bt + (size_t)tr1 * 256 + sca1;

  f32x4 acc[4][4] = {};

  for (int k0 = 0; k0 < 256; k0 += 32) {
    g2lds16(pa0 + k0, &As[rbase * 32]);
    g2lds16(pa1 + k0, &As[(rbase + 16) * 32]);
    g2lds16(pb0 + k0, &Bs[rbase * 32]);
    g2lds16(pb1 + k0, &Bs[(rbase + 16) * 32]);
    __syncthreads();
    bf16x8 afr[4], bfr[4];
#pragma unroll
    for (int mt = 0; mt < 4; ++mt) {
      int rr = wrow + mt * 16 + lrow;
      afr[mt] = *(const bf16x8*)(&As[rr * 32 + ((quad ^ ((rr >> 1) & 3)) << 3)]);
    }
#pragma unroll
    for (int nt = 0; nt < 4; ++nt) {
      int rr = wcol + nt * 16 + lrow;
      bfr[nt] = *(const bf16x8*)(&Bs[rr * 32 + ((quad ^ ((rr >> 1) & 3)) << 3)]);
    }
#pragma unroll
    for (int mt = 0; mt < 4; ++mt)
#pragma unroll
      for (int nt = 0; nt < 4; ++nt)
        acc[mt][nt] = __builtin_amdgcn_mfma_f32_16x16x32_bf16(afr[mt], bfr[nt], acc[mt][nt], 0, 0, 0);
    __syncthreads();
  }

  float p[4][4];
#pragma unroll
  for (int mt = 0; mt < 4; ++mt)
#pragma unroll
    for (int r = 0; r < 4; ++r) p[mt][r] = 0.f;
#pragma unroll
  for (int nt = 0; nt < 4; ++nt) {
    int gcol = wcol + nt * 16 + lrow;
    float b1v = bg1[gcol];
    float w2v = Wg2[gcol];
#pragma unroll
    for (int mt = 0; mt < 4; ++mt)
#pragma unroll
      for (int r = 0; r < 4; ++r) {
        float v = fmaxf(acc[mt][nt][r] + b1v, 0.f);
        p[mt][r] = fmaf(v, w2v, p[mt][r]);
      }
  }
#pragma unroll
  for (int mt = 0; mt < 4; ++mt)
#pragma unroll
    for (int r = 0; r < 4; ++r) {
      float v = p[mt][r];
      v += __shfl_xor(v, 1);
      v += __shfl_xor(v, 2);
      v += __shfl_xor(v, 4);
      v += __shfl_xor(v, 8);
      if (lrow == 0) gbuf[wrow + mt * 16 + quad * 4 + r][wcol >> 6] = v;
    }
  __syncthreads();
  if (tid < 128) {
    int grow = row0 + tid;
    if (grow < M) gate[grow] = gbuf[tid][0] + gbuf[tid][1] + bg2[0];
  }
}

// ---------------- f32 GEMM for the tiny readout layers ----------------
__global__ __launch_bounds__(256) void gemm_f32(
    const float* __restrict__ A, const float* __restrict__ B,
    const float* __restrict__ bias, float* __restrict__ C,
    int M, int Ncol, int K, int act, float scale)
{
  __shared__ float As[32][68];
  __shared__ float Bs[32][68];
  const int tid = threadIdx.x;
  const int tx = tid & 15, ty = tid >> 4;
  const int col0 = blockIdx.x * 64;
  const int row0 = blockIdx.y * 64;
  float acc[4][4];
#pragma unroll
  for (int i = 0; i < 4; ++i)
#pragma unroll
    for (int j = 0; j < 4; ++j) acc[i][j] = 0.f;

  const int ar = tid >> 3;
  const int ak = (tid & 7) * 4;
  const int bk = tid >> 4;
  const int bc = (tid & 15) * 4;

  for (int k0 = 0; k0 < K; k0 += 32) {
#pragma unroll
    for (int p = 0; p < 2; ++p) {
      int r = ar + p * 32;
      int grow = row0 + r;
      float4 v = make_float4(0.f, 0.f, 0.f, 0.f);
      if (grow < M) v = *(const float4*)(A + (size_t)grow * K + k0 + ak);
      As[ak + 0][r] = v.x; As[ak + 1][r] = v.y; As[ak + 2][r] = v.z; As[ak + 3][r] = v.w;
    }
#pragma unroll
    for (int p = 0; p < 2; ++p) {
      int kk = bk + p * 16;
      float4 v = *(const float4*)(B + (size_t)(k0 + kk) * Ncol + col0 + bc);
      *(float4*)(&Bs[kk][bc]) = v;
    }
    __syncthreads();
#pragma unroll
    for (int kk = 0; kk < 32; ++kk) {
      float4 a = *(const float4*)(&As[kk][ty * 4]);
      float4 b = *(const float4*)(&Bs[kk][tx * 4]);
      float av[4] = {a.x, a.y, a.z, a.w};
      float bv[4] = {b.x, b.y, b.z, b.w};
#pragma unroll
      for (int i = 0; i < 4; ++i)
#pragma unroll
        for (int j = 0; j < 4; ++j) acc[i][j] = fmaf(av[i], bv[j], acc[i][j]);
    }
    __syncthreads();
  }
  float bvals[4] = {0.f, 0.f, 0.f, 0.f};
  if (bias) {
#pragma unroll
    for (int j = 0; j < 4; ++j) bvals[j] = bias[col0 + tx * 4 + j];
  }
#pragma unroll
  for (int i = 0; i < 4; ++i) {
    int r = row0 + ty * 4 + i;
    if (r >= M) continue;
    float4 outv;
    float* o = (float*)&outv;
#pragma unroll
    for (int j = 0; j < 4; ++j) {
      float v = (acc[i][j] + bvals[j]) * scale;
      if (act == 1) v = fmaxf(v, 0.f);
      else if (act == 2) v = (v > 0.f) ? v : (__expf(v) - 1.f);
      o[j] = v;
    }
    *(float4*)(C + (size_t)r * Ncol + col0 + tx * 4) = outv;
  }
}

// ---------------- PASS A: edge-parallel logits (real edges only) ----------------
__global__ __launch_bounds__(256) void logits_kernel(
    const unsigned short* __restrict__ xlr,
    const int* __restrict__ ei, const float* __restrict__ eattr,
    const float* __restrict__ We, const float* __restrict__ att,
    float* __restrict__ logits)
{
  const int lane = threadIdx.x & 63;
  const int wv = threadIdx.x >> 6;
  const int c0 = lane * 4;
  const int head = lane >> 3;

  float4 attf4 = *(const float4*)(att + c0);
  float attf[4] = {attf4.x, attf4.y, attf4.z, attf4.w};
  float wef[10][4];
#pragma unroll
  for (int k = 0; k < 10; ++k) {
    float4 w4 = *(const float4*)(We + k * 256 + c0);
    wef[k][0] = w4.x; wef[k][1] = w4.y; wef[k][2] = w4.z; wef[k][3] = w4.w;
  }

  auto edge_logit = [&](int e) {
    int src = ei[e];
    int tgt = ei[N_EDGES + e];
    const float* eap = eattr + (size_t)e * 10;
    float2 q0 = *(const float2*)(eap + 0);
    float2 q1 = *(const float2*)(eap + 2);
    float2 q2 = *(const float2*)(eap + 4);
    float2 q3 = *(const float2*)(eap + 6);
    float2 q4 = *(const float2*)(eap + 8);
    ushort4 ua = *(const ushort4*)(xlr + (size_t)src * 512 + c0);
    ushort4 ub = *(const ushort4*)(xlr + (size_t)tgt * 512 + 256 + c0);
    float ev[10] = {q0.x, q0.y, q1.x, q1.y, q2.x, q2.y, q3.x, q3.y, q4.x, q4.y};
    float p0 = 0.f, p1 = 0.f, p2 = 0.f, p3 = 0.f;
#pragma unroll
    for (int k = 0; k < 10; ++k) {
      p0 = fmaf(ev[k], wef[k][0], p0);
      p1 = fmaf(ev[k], wef[k][1], p1);
      p2 = fmaf(ev[k], wef[k][2], p2);
      p3 = fmaf(ev[k], wef[k][3], p3);
    }
    float s0 = bf2f(ua.x) + bf2f(ub.x) + p0;
    float s1 = bf2f(ua.y) + bf2f(ub.y) + p1;
    float s2 = bf2f(ua.z) + bf2f(ub.z) + p2;
    float s3 = bf2f(ua.w) + bf2f(ub.w) + p3;
    s0 = (s0 > 0.f) ? s0 : 0.2f * s0;
    s1 = (s1 > 0.f) ? s1 : 0.2f * s1;
    s2 = (s2 > 0.f) ? s2 : 0.2f * s2;
    s3 = (s3 > 0.f) ? s3 : 0.2f * s3;
    float part = s0 * attf[0] + s1 * attf[1] + s2 * attf[2] + s3 * attf[3];
    part += __shfl_xor(part, 1);
    part += __shfl_xor(part, 2);
    part += __shfl_xor(part, 4);
    if ((lane & 7) == 0) logits[(size_t)e * 8 + head] = part;
  };

  const int nw = gridDim.x * 4;
  const int e0 = (blockIdx.x * 4 + wv) * 2;
  for (int e = e0; e < N_EDGES; e += nw * 2) {
    edge_logit(e);
    if (e + 1 < N_EDGES) edge_logit(e + 1);
  }
}

// ---------------- PASS B: node-parallel softmax + aggregate + BN/ELU/residual ----------------
__global__ __launch_bounds__(256) void attn_kernel(
    const unsigned short* __restrict__ xlr,
    float* __restrict__ h, unsigned short* __restrict__ hb,
    const int* __restrict__ ei, const float* __restrict__ logits,
    const float* __restrict__ att, const float* __restrict__ bgat,
    const float* __restrict__ ep_self,
    const int* __restrict__ rowptr, const int* __restrict__ csr)
{
  const int lane = threadIdx.x & 63;
  const int wv = threadIdx.x >> 6;
  const int n = blockIdx.x * 4 + wv;
  if (n >= N_NODES) return;
  const int c0 = lane * 4;
  const int head = lane >> 3;

  const int s = rowptr[n], e = rowptr[n + 1];

  ushort4 ul = *(const ushort4*)(xlr + (size_t)n * 512 + c0);        // xl[n]
  ushort4 ur = *(const ushort4*)(xlr + (size_t)n * 512 + 256 + c0);  // xr[n]
  float4 hold = *(const float4*)(h + (size_t)n * HIDDEN + c0);
  float4 attf = *(const float4*)(att + c0);
  float4 eps = *(const float4*)(ep_self + c0);

  float xln[4] = {bf2f(ul.x), bf2f(ul.y), bf2f(ul.z), bf2f(ul.w)};

  // self-loop logit
  float lself;
  {
    float s0 = xln[0] + bf2f(ur.x) + eps.x;
    float s1 = xln[1] + bf2f(ur.y) + eps.y;
    float s2 = xln[2] + bf2f(ur.z) + eps.z;
    float s3 = xln[3] + bf2f(ur.w) + eps.w;
    s0 = (s0 > 0.f) ? s0 : 0.2f * s0;
    s1 = (s1 > 0.f) ? s1 : 0.2f * s1;
    s2 = (s2 > 0.f) ? s2 : 0.2f * s2;
    s3 = (s3 > 0.f) ? s3 : 0.2f * s3;
    float part = s0 * attf.x + s1 * attf.y + s2 * attf.z + s3 * attf.w;
    part += __shfl_xor(part, 1);
    part += __shfl_xor(part, 2);
    part += __shfl_xor(part, 4);
    lself = part;
  }

  // loop1: max over real in-edge logits
  float m = lself;
  const int elast = e - 1;
  for (int idx = s; idx < e; idx += 4) {
    int i1 = idx + 1, i2 = idx + 2, i3 = idx + 3;
    int eid0 = csr[idx];
    int eid1 = csr[(i1 <= elast) ? i1 : elast];
    int eid2 = csr[(i2 <= elast) ? i2 : elast];
    int eid3 = csr[(i3 <= elast) ? i3 : elast];
    float l0 = logits[(size_t)eid0 * 8 + head];
    float l1 = logits[(size_t)eid1 * 8 + head];
    float l2 = logits[(size_t)eid2 * 8 + head];
    float l3 = logits[(size_t)eid3 * 8 + head];
    m = fmaxf(fmaxf(m, fmaxf(l0, l1)), fmaxf(l2, l3));
  }

  // loop2: independent accumulate
  float wself = __expf(lself - m);
  float d = wself;
  float a0 = wself * xln[0], a1 = wself * xln[1], a2 = wself * xln[2], a3 = wself * xln[3];
  for (int idx = s; idx < e; idx += 2) {
    int i1 = idx + 1;
    bool v1 = (i1 <= elast);
    int eid0 = csr[idx];
    int eid1 = csr[v1 ? i1 : elast];
    float l0 = logits[(size_t)eid0 * 8 + head];
    float l1 = logits[(size_t)eid1 * 8 + head];
    int s0 = ei[eid0];
    int s1 = ei[eid1];
    float w0 = __expf(l0 - m);
    float w1 = v1 ? __expf(l1 - m) : 0.f;
    ushort4 u0 = *(const ushort4*)(xlr + (size_t)s0 * 512 + c0);
    ushort4 u1 = *(const ushort4*)(xlr + (size_t)s1 * 512 + c0);
    d += w0 + w1;
    a0 += w0 * bf2f(u0.x) + w1 * bf2f(u1.x);
    a1 += w0 * bf2f(u0.y) + w1 * bf2f(u1.y);
    a2 += w0 * bf2f(u0.z) + w1 * bf2f(u1.z);
    a3 += w0 * bf2f(u0.w) + w1 * bf2f(u1.w);
  }

  float inv = 1.f / (d + 1e-16f);
  float4 bg = *(const float4*)(bgat + c0);
  float ov[4] = {a0 * inv, a1 * inv, a2 * inv, a3 * inv};
  float bgv[4] = {bg.x, bg.y, bg.z, bg.w};
  float hv[4] = {hold.x, hold.y, hold.z, hold.w};
  float4 res;
  float* rp = (float*)&res;
  ushort4 resb;
  unsigned short* rb = (unsigned short*)&resb;
#pragma unroll
  for (int j = 0; j < 4; ++j) {
    float v = (ov[j] + bgv[j]) * BN_S;
    v = (v > 0.f) ? v : (__expf(v) - 1.f);
    float nv = v + hv[j];
    rp[j] = nv;
    rb[j] = f2bf(nv);
  }
  *(float4*)(h + (size_t)n * HIDDEN + c0) = res;
  *(ushort4*)(hb + (size_t)n * HIDDEN + c0) = resb;
}

// ---------------- global attention pooling per graph ----------------
__global__ __launch_bounds__(64) void pool_kernel(
    const float* __restrict__ gate, const float* __restrict__ h,
    const int* __restrict__ brp, float* __restrict__ pooled)
{
  int b = blockIdx.x;
  int lane = threadIdx.x;
  int s = brp[b], e = brp[b + 1];
  float m = -__builtin_inff();
  for (int i = s + lane; i < e; i += 64) m = fmaxf(m, gate[i]);
#pragma unroll
  for (int o = 1; o < 64; o <<= 1) m = fmaxf(m, __shfl_xor(m, o));
  float d = 0.f;
  for (int i = s + lane; i < e; i += 64) d += __expf(gate[i] - m);
#pragma unroll
  for (int o = 1; o < 64; o <<= 1) d += __shfl_xor(d, o);
  float inv = 1.f / (d + 1e-16f);
  int c0 = lane * 4;
  float acc[4] = {0.f, 0.f, 0.f, 0.f};
  for (int i = s; i < e; ++i) {
    float w = __expf(gate[i] - m) * inv;
    float4 hv = *(const float4*)(h + (size_t)i * HIDDEN + c0);
    acc[0] = fmaf(w, hv.x, acc[0]);
    acc[1] = fmaf(w, hv.y, acc[1]);
    acc[2] = fmaf(w, hv.z, acc[2]);
    acc[3] = fmaf(w, hv.w, acc[3]);
  }
  float4 outv = make_float4(acc[0], acc[1], acc[2], acc[3]);
  *(float4*)(pooled + (size_t)b * HIDDEN + c0) = outv;
}

// ---------------- final: out[b] = r3[b,:] . W4 + b4 ----------------
__global__ __launch_bounds__(256) void out_kernel(
    const float* __restrict__ r3, const float* __restrict__ W4,
    const float* __restrict__ b4, float* __restrict__ out)
{
  int lane = threadIdx.x & 63;
  int wv = threadIdx.x >> 6;
  int b = blockIdx.x * 4 + wv;
  if (b >= N_B) return;
  float v = r3[(size_t)b * 64 + lane] * W4[lane];
#pragma unroll
  for (int o = 1; o < 64; o <<= 1) v += __shfl_xor(v, o);
  if (lane == 0) out[b] = v + b4[0];
}

extern "C" void kernel_launch(void* const* d_in, const int* in_sizes, int n_in,
                              void* d_out, int out_size, void* d_ws, size_t ws_size,
                              hipStream_t stream)
{
  const float* x    = (const float*)d_in[0];
  const int* ei     = (const int*)d_in[1];
  const float* ea   = (const float*)d_in[2];
  const int* batch  = (const int*)d_in[3];
  const float* W_in = (const float*)d_in[4];
  const float* b_in = (const float*)d_in[5];
  const float* Wl   = (const float*)d_in[6];
  const float* Wr   = (const float*)d_in[7];
  const float* We   = (const float*)d_in[8];
  const float* att  = (const float*)d_in[9];
  const float* bgat = (const float*)d_in[10];
  const float* Wg1  = (const float*)d_in[11];
  const float* bg1  = (const float*)d_in[12];
  const float* Wg2  = (const float*)d_in[13];
  const float* bg2  = (const float*)d_in[14];
  const float* W1   = (const float*)d_in[15];
  const float* b1   = (const float*)d_in[16];
  const float* W2   = (const float*)d_in[17];
  const float* b2   = (const float*)d_in[18];
  const float* W3   = (const float*)d_in[19];
  const float* b3   = (const float*)d_in[20];
  const float* W4   = (const float*)d_in[21];
  const float* b4   = (const float*)d_in[22];
  float* out = (float*)d_out;

  char* ws = (char*)d_ws;
  size_t off = 0;
  auto alloc = [&](size_t bytes) -> char* {
    char* p = ws + off;
    off += (bytes + 255) & ~(size_t)255;
    return p;
  };
  float* h            = (float*)alloc((size_t)N_NODES * HIDDEN * 4);           // 102.4 MB
  unsigned short* hb  = (unsigned short*)alloc((size_t)N_NODES * HIDDEN * 2);  // 51.2 MB
  unsigned short* xlr = (unsigned short*)alloc((size_t)N_NODES * 512 * 2);     // 102.4 MB
  int* deg       = (int*)alloc((size_t)N_NODES * 4);
  int* rowptr    = (int*)alloc((size_t)(N_NODES + 1) * 4);
  int* cursor    = (int*)alloc((size_t)N_NODES * 4);
  int* csr       = (int*)alloc((size_t)N_EDGES * 4);       // real edges only
  int* brp       = (int*)alloc((size_t)(N_B + 1) * 4);
  int* bsum      = (int*)alloc(512);
  float* macc    = (float*)alloc(64);
  float* meanattr= (float*)alloc(64);
  float* ep_self = (float*)alloc(4 * 256 * 4);
  float* logits  = (float*)alloc((size_t)N_EDGES * 8 * 4); // 7.04 MB
  unsigned short* Wint  = (unsigned short*)alloc(256 * 96 * 2);       // [256][96]
  unsigned short* Wlrt  = (unsigned short*)alloc(4 * 512 * 256 * 2);  // [i][512][256] = Wl^T || Wr^T
  unsigned short* Wg1t  = (unsigned short*)alloc(128 * 256 * 2);      // [128][256]
  // total ≈ 266.3 MB < 268.4 MB ws  ✓

  // aliases into dead regions of xlr:
  unsigned short* xpad = xlr;            // [N,96] bf16, pre-layer0 only
  float* base2  = (float*)xlr;           // xlr fully dead after last attn layer
  float* gate   = base2;                 // [N] f32
  float* pooled = base2 + 1000000;       // [B,256] f32
  float* r1     = base2 + 3000000;       // [B,256] f32
  float* r2     = base2 + 5000000;       // [B,128] f32
  float* r3     = base2 + 6000000;       // [B,64]  f32

  if (ws_size < off) {
    hipMemsetAsync(d_out, 0, (size_t)out_size * 4, stream);
    return;
  }

  zero_kernel<<<391, 256, 0, stream>>>(deg, cursor, macc);
  mean_kernel<<<64, 256, 0, stream>>>(ea, macc);
  meanattr_kernel<<<1, 64, 0, stream>>>(macc, meanattr);
  epself_kernel<<<4, 256, 0, stream>>>(meanattr, We, ep_self);
  count_kernel<<<860, 256, 0, stream>>>(ei, deg);
  scan1_kernel<<<NSCANB, 1024, 0, stream>>>(deg, rowptr, bsum);
  scan2_kernel<<<1, 128, 0, stream>>>(bsum);
  scan3_kernel<<<NSCANB, 1024, 0, stream>>>(rowptr, bsum);
  scatter_kernel<<<860, 256, 0, stream>>>(ei, rowptr, cursor, csr);
  brp_kernel<<<512, 256, 0, stream>>>(batch, brp);

  // weight conversions (transpose + bf16)
  wt_kernel<<<(256 * 96 + 255) / 256, 256, 0, stream>>>(W_in, Wint, 75, 96, 256);
  wlr_kernel<<<512, 256, 0, stream>>>(Wl, Wr, Wlrt);
  wt_kernel<<<128, 256, 0, stream>>>(Wg1, Wg1t, 256, 256, 128);
  convx_kernel<<<4096, 256, 0, stream>>>(x, xpad);

  // input projection: h = elu((x @ W_in + b_in) * BN_S)  [MFMA, K=96]
  gemm_mfma<<<1564, 256, 0, stream>>>(xpad, Wint, b_in, h, hb,
                                      N_NODES, 256, 96, 2, BN_S, 2);

  for (int i = 0; i < 4; ++i) {
    // fused xl||xr GEMM: [N,256] @ [256,512] -> xlr [N,512]
    gemm_mfma<<<3128, 256, 0, stream>>>(hb, Wlrt + (size_t)i * 131072, nullptr,
                                        nullptr, xlr, N_NODES, 512, 256, 0, 1.f, 4);
    // pass A: edge-parallel logits
    logits_kernel<<<2048, 256, 0, stream>>>(xlr, ei, ea, We + (size_t)i * 2560,
                                            att + (size_t)i * 256, logits);
    // pass B: node-parallel softmax + aggregate
    attn_kernel<<<25000, 256, 0, stream>>>(xlr, h, hb, ei, logits,
                                           att + (size_t)i * 256, bgat + (size_t)i * 256,
                                           ep_self + (size_t)i * 256, rowptr, csr);
  }

  // fused pooling gate: gate = relu(hb @ Wg1 + bg1) . Wg2 + bg2
  gemm_gate<<<782, 256, 0, stream>>>(hb, Wg1t, bg1, Wg2, bg2, gate, N_NODES);
  pool_kernel<<<N_B, 64, 0, stream>>>(gate, h, brp, pooled);

  // readout MLP (f32, tiny)
  gemm_f32<<<dim3(4, 64), 256, 0, stream>>>(pooled, W1, b1, r1, N_B, 256, 256, 1, BN_S);
  gemm_f32<<<dim3(2, 64), 256, 0, stream>>>(r1, W2, b2, r2, N_B, 128, 256, 1, BN_S);
  gemm_f32<<<dim3(1, 64), 256, 0, stream>>>(r2, W3, b3, r3, N_B, 64, 128, 1, 1.f);
  out_kernel<<<1024, 256, 0, stream>>>(r3, W4, b4, out);
}

// Round 9
// 1201.393 us; speedup vs baseline: 1.2922x; 1.0157x over previous
//
#include <hip/hip_runtime.h>

#define N_NODES 100000
#define N_EDGES 220000
#define N_B     4096
#define HIDDEN  256
#define BN_S    0.9999950000374997f
#define NSCANB  98       // ceil(100000/1024)

typedef __attribute__((ext_vector_type(8))) short bf16x8;
typedef __attribute__((ext_vector_type(4))) float f32x4;

__device__ __forceinline__ float bf2f(unsigned short u) {
  return __uint_as_float(((unsigned int)u) << 16);
}
__device__ __forceinline__ unsigned short f2bf(float f) {
  unsigned int x = __float_as_uint(f);
  unsigned int lsb = (x >> 16) & 1u;
  x += 0x7fffu + lsb;
  return (unsigned short)(x >> 16);
}

// async global->LDS 16B: dest is wave-uniform base + lane*16 (linear);
// per-lane GLOBAL address carries the XOR swizzle (m173 pattern).
__device__ __forceinline__ void g2lds16(const void* g, void* l) {
  __builtin_amdgcn_global_load_lds(
      (const __attribute__((address_space(1))) unsigned int*)g,
      (__attribute__((address_space(3))) unsigned int*)l, 16, 0, 0);
}

// bijective XCD swizzle (m204)
__device__ __forceinline__ int xcd_swz(int b, int nwg) {
  int q = nwg >> 3, r = nwg & 7;
  int xcd = b & 7, idx = b >> 3;
  int base = (xcd < r) ? xcd * (q + 1) : r * (q + 1) + (xcd - r) * q;
  return base + idx;
}

// ---------------- zero-init of counters ----------------
__global__ void zero_kernel(int* __restrict__ deg, int* __restrict__ cursor, float* __restrict__ macc) {
  int i = blockIdx.x * blockDim.x + threadIdx.x;
  if (i < N_NODES) { deg[i] = 0; cursor[i] = 0; }
  if (i < 16) macc[i] = 0.f;
}

// ---------------- mean of edge_attr (block-reduced, 1 atomic/k/block) ----------------
__global__ __launch_bounds__(256) void mean_kernel(const float* __restrict__ ea, float* __restrict__ macc) {
  __shared__ float sred[4][16];
  int lane = threadIdx.x & 63;
  int wv = threadIdx.x >> 6;
  float loc[10];
#pragma unroll
  for (int k = 0; k < 10; ++k) loc[k] = 0.f;
  for (int e = blockIdx.x * blockDim.x + threadIdx.x; e < N_EDGES; e += gridDim.x * blockDim.x) {
    const float* p = ea + (size_t)e * 10;
#pragma unroll
    for (int k = 0; k < 10; ++k) loc[k] += p[k];
  }
#pragma unroll
  for (int k = 0; k < 10; ++k) {
    float v = loc[k];
#pragma unroll
    for (int o = 1; o < 64; o <<= 1) v += __shfl_xor(v, o);
    if (lane == 0) sred[wv][k] = v;
  }
  __syncthreads();
  if (threadIdx.x < 10) {
    float s = sred[0][threadIdx.x] + sred[1][threadIdx.x] +
              sred[2][threadIdx.x] + sred[3][threadIdx.x];
    atomicAdd(&macc[threadIdx.x], s);
  }
}

__global__ void meanattr_kernel(const float* __restrict__ macc, float* __restrict__ meanattr) {
  int t = threadIdx.x;
  const float invE = 1.f / (float)N_EDGES;
  if (t < 10) meanattr[t] = macc[t] * invE;
}

// ---------------- ep_self[i][c] = meanattr . We[i][:,c] ----------------
__global__ void epself_kernel(const float* __restrict__ meanattr, const float* __restrict__ We,
                              float* __restrict__ ep_self) {
  int i = blockIdx.x;
  int c = threadIdx.x;
  float s = 0.f;
#pragma unroll
  for (int k = 0; k < 10; ++k)
    s += meanattr[k] * We[(size_t)i * 2560 + k * 256 + c];
  ep_self[i * 256 + c] = s;
}

// ---------------- CSR build (REAL edges only) ----------------
__global__ void count_kernel(const int* __restrict__ ei, int* __restrict__ deg) {
  for (int e = blockIdx.x * blockDim.x + threadIdx.x; e < N_EDGES; e += gridDim.x * blockDim.x) {
    atomicAdd(&deg[ei[N_EDGES + e]], 1);
  }
}

// ---------------- 3-phase scan ----------------
__global__ __launch_bounds__(1024) void scan1_kernel(const int* __restrict__ deg,
                                                     int* __restrict__ rowptr,
                                                     int* __restrict__ bsum) {
  __shared__ int buf[1024];
  int t = threadIdx.x;
  int i = blockIdx.x * 1024 + t;
  int v = (i < N_NODES) ? deg[i] : 0;
  buf[t] = v;
  __syncthreads();
  for (int off = 1; off < 1024; off <<= 1) {
    int add = (t >= off) ? buf[t - off] : 0;
    __syncthreads();
    buf[t] += add;
    __syncthreads();
  }
  if (i < N_NODES) rowptr[i + 1] = buf[t];
  if (t == 1023) bsum[blockIdx.x] = buf[t];
  if (i == 0) rowptr[0] = 0;
}

__global__ __launch_bounds__(128) void scan2_kernel(int* __restrict__ bsum) {
  __shared__ int buf[128];
  int t = threadIdx.x;
  int v = (t < NSCANB) ? bsum[t] : 0;
  buf[t] = v;
  __syncthreads();
  for (int off = 1; off < 128; off <<= 1) {
    int add = (t >= off) ? buf[t - off] : 0;
    __syncthreads();
    buf[t] += add;
    __syncthreads();
  }
  if (t < NSCANB) bsum[t] = buf[t];
}

__global__ __launch_bounds__(1024) void scan3_kernel(int* __restrict__ rowptr,
                                                     const int* __restrict__ bsum) {
  int b = blockIdx.x;
  if (b == 0) return;
  int i = b * 1024 + threadIdx.x;
  if (i < N_NODES) rowptr[i + 1] += bsum[b - 1];
}

__global__ void scatter_kernel(const int* __restrict__ ei, const int* __restrict__ rowptr,
                               int* __restrict__ cursor, int* __restrict__ csr) {
  for (int e = blockIdx.x * blockDim.x + threadIdx.x; e < N_EDGES; e += gridDim.x * blockDim.x) {
    int t = ei[N_EDGES + e];
    int pos = atomicAdd(&cursor[t], 1);
    csr[rowptr[t] + pos] = e;
  }
}

__global__ void brp_kernel(const int* __restrict__ batch, int* __restrict__ brp) {
  for (int i = blockIdx.x * blockDim.x + threadIdx.x; i < N_NODES; i += gridDim.x * blockDim.x) {
    int bi = batch[i];
    int bp = (i == 0) ? -1 : batch[i - 1];
    for (int b = bp + 1; b <= bi; ++b) brp[b] = i;
    if (i == N_NODES - 1) {
      for (int b = bi + 1; b <= N_B; ++b) brp[b] = N_NODES;
    }
  }
}

// ---------------- x -> padded bf16 [N,96] ----------------
__global__ void convx_kernel(const float* __restrict__ x, unsigned short* __restrict__ xp) {
  int total = N_NODES * 96;
  for (int idx = blockIdx.x * blockDim.x + threadIdx.x; idx < total; idx += gridDim.x * blockDim.x) {
    int nn = idx / 96;
    int j = idx - nn * 96;
    unsigned short v = 0;
    if (j < 75) v = f2bf(x[(size_t)nn * 75 + j]);
    xp[idx] = v;
  }
}

// ---------------- weight transpose+bf16 ----------------
__global__ void wt_kernel(const float* __restrict__ src, unsigned short* __restrict__ dst,
                          int K, int Kp, int N) {
  int idx = blockIdx.x * blockDim.x + threadIdx.x;
  int total = N * Kp;
  if (idx >= total) return;
  int n = idx / Kp, k = idx - n * Kp;
  dst[idx] = (k < K) ? f2bf(src[(size_t)k * N + n]) : (unsigned short)0;
}

// ---------------- all 4 layers Wl^T||Wr^T in one launch ----------------
__global__ void wlr_kernel(const float* __restrict__ Wl, const float* __restrict__ Wr,
                           unsigned short* __restrict__ dst) {
  const int total = 4 * 512 * 256;
  for (int idx = blockIdx.x * blockDim.x + threadIdx.x; idx < total; idx += gridDim.x * blockDim.x) {
    int i = idx >> 17;          // /131072
    int rem = idx & 131071;
    int n = rem >> 8;           // 0..511
    int k = rem & 255;
    float v = (n < 256) ? Wl[(size_t)i * 65536 + k * 256 + n]
                        : Wr[(size_t)i * 65536 + k * 256 + (n - 256)];
    dst[idx] = f2bf(v);
  }
}

// ---------------- bf16 MFMA GEMM, single-buffer staging + LDS-staged C-write ----------------
__global__ __launch_bounds__(256) void gemm_mfma(
    const unsigned short* __restrict__ A, const unsigned short* __restrict__ Bt,
    const float* __restrict__ bias, float* __restrict__ Cf, unsigned short* __restrict__ Cb,
    int M, int Ncol, int K, int act, float scale, int gx)
{
  __shared__ unsigned short smem[64 * 136];   // 17408 B: As(8KB)+Bs(8KB) during loop, C-stage after
  unsigned short* As = smem;                  // [128*32]
  unsigned short* Bs = smem + 4096;           // [128*32]
  const int tid = threadIdx.x;
  const int wave = tid >> 6;
  const int lane = tid & 63;

  const int wg = xcd_swz(blockIdx.x, gridDim.x);
  const int col0 = (wg % gx) * 128;
  const int row0 = (wg / gx) * 128;

  const int wrow = (wave >> 1) * 64;
  const int wcol = (wave & 1) * 64;
  const int lrow = lane & 15;
  const int quad = lane >> 4;

  // staging geometry: wave stages tile rows [32*wave, 32*wave+32)
  const int rbase = wave * 32;
  const int lr4 = lane >> 2;      // 0..15
  const int lc = lane & 3;        // 16B slot
  const int tr0 = rbase + lr4;
  const int tr1 = rbase + 16 + lr4;
  int gra0 = row0 + tr0; if (gra0 > M - 1) gra0 = M - 1;  // clamp: rows >= M discarded in epilogue
  int gra1 = row0 + tr1; if (gra1 > M - 1) gra1 = M - 1;
  const int sca0 = (lc ^ ((tr0 >> 1) & 3)) * 8;   // pre-swizzled source slot (elems)
  const int sca1 = (lc ^ ((tr1 >> 1) & 3)) * 8;
  const unsigned short* pa0 = A + (size_t)gra0 * K + sca0;
  const unsigned short* pa1 = A + (size_t)gra1 * K + sca1;
  const unsigned short* pb0 = Bt + (size_t)(col0 + tr0) * K + sca0;
  const unsigned short* pb1 = Bt + (size_t)(col0 + tr1) * K + sca1;

  f32x4 acc[4][4] = {};

  for (int k0 = 0; k0 < K; k0 += 32) {
    g2lds16(pa0 + k0, &As[rbase * 32]);
    g2lds16(pa1 + k0, &As[(rbase + 16) * 32]);
    g2lds16(pb0 + k0, &Bs[rbase * 32]);
    g2lds16(pb1 + k0, &Bs[(rbase + 16) * 32]);
    __syncthreads();   // drains vmcnt (global_load_lds) before LDS reads
    bf16x8 afr[4], bfr[4];
#pragma unroll
    for (int mt = 0; mt < 4; ++mt) {
      int rr = wrow + mt * 16 + lrow;
      afr[mt] = *(const bf16x8*)(&As[rr * 32 + ((quad ^ ((rr >> 1) & 3)) << 3)]);
    }
#pragma unroll
    for (int nt = 0; nt < 4; ++nt) {
      int rr = wcol + nt * 16 + lrow;
      bfr[nt] = *(const bf16x8*)(&Bs[rr * 32 + ((quad ^ ((rr >> 1) & 3)) << 3)]);
    }
#pragma unroll
    for (int mt = 0; mt < 4; ++mt)
#pragma unroll
      for (int nt = 0; nt < 4; ++nt)
        acc[mt][nt] = __builtin_amdgcn_mfma_f32_16x16x32_bf16(afr[mt], bfr[nt], acc[mt][nt], 0, 0, 0);
    __syncthreads();
  }

  // ---- epilogue: two 64-row passes through LDS, coalesced 16B bf16 stores ----
#pragma unroll
  for (int p = 0; p < 2; ++p) {
#pragma unroll
    for (int mtl = 0; mtl < 2; ++mtl) {
      int mt = 2 * p + mtl;
#pragma unroll
      for (int nt = 0; nt < 4; ++nt) {
        int lcol = wcol + nt * 16 + lrow;
        float bv = bias ? bias[col0 + lcol] : 0.f;
#pragma unroll
        for (int r = 0; r < 4; ++r) {
          float v = (acc[mt][nt][r] + bv) * scale;
          if (act == 1) v = fmaxf(v, 0.f);
          else if (act == 2) v = (v > 0.f) ? v : (__expf(v) - 1.f);
          int srow = (wave >> 1) * 32 + mtl * 16 + quad * 4 + r;
          smem[srow * 136 + lcol] = f2bf(v);
          if (Cf) {
            int grow = row0 + wrow + mt * 16 + quad * 4 + r;
            if (grow < M) Cf[(size_t)grow * Ncol + col0 + lcol] = v;
          }
        }
      }
    }
    __syncthreads();
    if (Cb) {
#pragma unroll
      for (int round = 0; round < 4; ++round) {
        int s_r = round * 16 + (tid >> 4);
        int ce = (tid & 15) * 8;
        int w2 = s_r >> 5, mtl = (s_r >> 4) & 1, rr = s_r & 15;
        int grow = row0 + w2 * 64 + (2 * p + mtl) * 16 + rr;
        if (grow < M) {
          uint4 v = *(const uint4*)(&smem[s_r * 136 + ce]);
          *(uint4*)(Cb + (size_t)grow * Ncol + col0 + ce) = v;
        }
      }
    }
    __syncthreads();
  }
}

// ---------------- fused pooling-gate GEMM (single-buffer staging, K=256) ----------------
__global__ __launch_bounds__(256) void gemm_gate(
    const unsigned short* __restrict__ A, const unsigned short* __restrict__ Bt,
    const float* __restrict__ bg1, const float* __restrict__ Wg2,
    const float* __restrict__ bg2, float* __restrict__ gate, int M)
{
  __shared__ unsigned short As[128 * 32];
  __shared__ unsigned short Bs[128 * 32];
  __shared__ float gbuf[128][2];
  const int tid = threadIdx.x;
  const int wave = tid >> 6;
  const int lane = tid & 63;

  const int wg = xcd_swz(blockIdx.x, gridDim.x);
  const int row0 = wg * 128;

  const int wrow = (wave >> 1) * 64;
  const int wcol = (wave & 1) * 64;
  const int lrow = lane & 15;
  const int quad = lane >> 4;

  const int rbase = wave * 32;
  const int lr4 = lane >> 2;
  const int lc = lane & 3;
  const int tr0 = rbase + lr4;
  const int tr1 = rbase + 16 + lr4;
  int gra0 = row0 + tr0; if (gra0 > M - 1) gra0 = M - 1;
  int gra1 = row0 + tr1; if (gra1 > M - 1) gra1 = M - 1;
  const int sca0 = (lc ^ ((tr0 >> 1) & 3)) * 8;
  const int sca1 = (lc ^ ((tr1 >> 1) & 3)) * 8;
  const unsigned short* pa0 = A + (size_t)gra0 * 256 + sca0;
  const unsigned short* pa1 = A + (size_t)gra1 * 256 + sca1;
  const unsigned short* pb0 = Bt + (size_t)tr0 * 256 + sca0;
  const unsigned short* pb1 = Bt + (size_t)tr1 * 256 + sca1;

  f32x4 acc[4][4] = {};

  for (int k0 = 0; k0 < 256; k0 += 32) {
    g2lds16(pa0 + k0, &As[rbase * 32]);
    g2lds16(pa1 + k0, &As[(rbase + 16) * 32]);
    g2lds16(pb0 + k0, &Bs[rbase * 32]);
    g2lds16(pb1 + k0, &Bs[(rbase + 16) * 32]);
    __syncthreads();
    bf16x8 afr[4], bfr[4];
#pragma unroll
    for (int mt = 0; mt < 4; ++mt) {
      int rr = wrow + mt * 16 + lrow;
      afr[mt] = *(const bf16x8*)(&As[rr * 32 + ((quad ^ ((rr >> 1) & 3)) << 3)]);
    }
#pragma unroll
    for (int nt = 0; nt < 4; ++nt) {
      int rr = wcol + nt * 16 + lrow;
      bfr[nt] = *(const bf16x8*)(&Bs[rr * 32 + ((quad ^ ((rr >> 1) & 3)) << 3)]);
    }
#pragma unroll
    for (int mt = 0; mt < 4; ++mt)
#pragma unroll
      for (int nt = 0; nt < 4; ++nt)
        acc[mt][nt] = __builtin_amdgcn_mfma_f32_16x16x32_bf16(afr[mt], bfr[nt], acc[mt][nt], 0, 0, 0);
    __syncthreads();
  }

  float p[4][4];
#pragma unroll
  for (int mt = 0; mt < 4; ++mt)
#pragma unroll
    for (int r = 0; r < 4; ++r) p[mt][r] = 0.f;
#pragma unroll
  for (int nt = 0; nt < 4; ++nt) {
    int gcol = wcol + nt * 16 + lrow;
    float b1v = bg1[gcol];
    float w2v = Wg2[gcol];
#pragma unroll
    for (int mt = 0; mt < 4; ++mt)
#pragma unroll
      for (int r = 0; r < 4; ++r) {
        float v = fmaxf(acc[mt][nt][r] + b1v, 0.f);
        p[mt][r] = fmaf(v, w2v, p[mt][r]);
      }
  }
#pragma unroll
  for (int mt = 0; mt < 4; ++mt)
#pragma unroll
    for (int r = 0; r < 4; ++r) {
      float v = p[mt][r];
      v += __shfl_xor(v, 1);
      v += __shfl_xor(v, 2);
      v += __shfl_xor(v, 4);
      v += __shfl_xor(v, 8);
      if (lrow == 0) gbuf[wrow + mt * 16 + quad * 4 + r][wcol >> 6] = v;
    }
  __syncthreads();
  if (tid < 128) {
    int grow = row0 + tid;
    if (grow < M) gate[grow] = gbuf[tid][0] + gbuf[tid][1] + bg2[0];
  }
}

// ---------------- f32 GEMM for the tiny readout layers ----------------
__global__ __launch_bounds__(256) void gemm_f32(
    const float* __restrict__ A, const float* __restrict__ B,
    const float* __restrict__ bias, float* __restrict__ C,
    int M, int Ncol, int K, int act, float scale)
{
  __shared__ float As[32][68];
  __shared__ float Bs[32][68];
  const int tid = threadIdx.x;
  const int tx = tid & 15, ty = tid >> 4;
  const int col0 = blockIdx.x * 64;
  const int row0 = blockIdx.y * 64;
  float acc[4][4];
#pragma unroll
  for (int i = 0; i < 4; ++i)
#pragma unroll
    for (int j = 0; j < 4; ++j) acc[i][j] = 0.f;

  const int ar = tid >> 3;
  const int ak = (tid & 7) * 4;
  const int bk = tid >> 4;
  const int bc = (tid & 15) * 4;

  for (int k0 = 0; k0 < K; k0 += 32) {
#pragma unroll
    for (int p = 0; p < 2; ++p) {
      int r = ar + p * 32;
      int grow = row0 + r;
      float4 v = make_float4(0.f, 0.f, 0.f, 0.f);
      if (grow < M) v = *(const float4*)(A + (size_t)grow * K + k0 + ak);
      As[ak + 0][r] = v.x; As[ak + 1][r] = v.y; As[ak + 2][r] = v.z; As[ak + 3][r] = v.w;
    }
#pragma unroll
    for (int p = 0; p < 2; ++p) {
      int kk = bk + p * 16;
      float4 v = *(const float4*)(B + (size_t)(k0 + kk) * Ncol + col0 + bc);
      *(float4*)(&Bs[kk][bc]) = v;
    }
    __syncthreads();
#pragma unroll
    for (int kk = 0; kk < 32; ++kk) {
      float4 a = *(const float4*)(&As[kk][ty * 4]);
      float4 b = *(const float4*)(&Bs[kk][tx * 4]);
      float av[4] = {a.x, a.y, a.z, a.w};
      float bv[4] = {b.x, b.y, b.z, b.w};
#pragma unroll
      for (int i = 0; i < 4; ++i)
#pragma unroll
        for (int j = 0; j < 4; ++j) acc[i][j] = fmaf(av[i], bv[j], acc[i][j]);
    }
    __syncthreads();
  }
  float bvals[4] = {0.f, 0.f, 0.f, 0.f};
  if (bias) {
#pragma unroll
    for (int j = 0; j < 4; ++j) bvals[j] = bias[col0 + tx * 4 + j];
  }
#pragma unroll
  for (int i = 0; i < 4; ++i) {
    int r = row0 + ty * 4 + i;
    if (r >= M) continue;
    float4 outv;
    float* o = (float*)&outv;
#pragma unroll
    for (int j = 0; j < 4; ++j) {
      float v = (acc[i][j] + bvals[j]) * scale;
      if (act == 1) v = fmaxf(v, 0.f);
      else if (act == 2) v = (v > 0.f) ? v : (__expf(v) - 1.f);
      o[j] = v;
    }
    *(float4*)(C + (size_t)r * Ncol + col0 + tx * 4) = outv;
  }
}

// ---------------- PASS A: edge-parallel logits (real edges only) ----------------
__global__ __launch_bounds__(256) void logits_kernel(
    const unsigned short* __restrict__ xlr,
    const int* __restrict__ ei, const float* __restrict__ eattr,
    const float* __restrict__ We, const float* __restrict__ att,
    float* __restrict__ logits)
{
  const int lane = threadIdx.x & 63;
  const int wv = threadIdx.x >> 6;
  const int c0 = lane * 4;
  const int head = lane >> 3;

  float4 attf4 = *(const float4*)(att + c0);
  float attf[4] = {attf4.x, attf4.y, attf4.z, attf4.w};
  float wef[10][4];
#pragma unroll
  for (int k = 0; k < 10; ++k) {
    float4 w4 = *(const float4*)(We + k * 256 + c0);
    wef[k][0] = w4.x; wef[k][1] = w4.y; wef[k][2] = w4.z; wef[k][3] = w4.w;
  }

  auto edge_logit = [&](int e) {
    int src = ei[e];
    int tgt = ei[N_EDGES + e];
    const float* eap = eattr + (size_t)e * 10;
    float2 q0 = *(const float2*)(eap + 0);
    float2 q1 = *(const float2*)(eap + 2);
    float2 q2 = *(const float2*)(eap + 4);
    float2 q3 = *(const float2*)(eap + 6);
    float2 q4 = *(const float2*)(eap + 8);
    ushort4 ua = *(const ushort4*)(xlr + (size_t)src * 512 + c0);
    ushort4 ub = *(const ushort4*)(xlr + (size_t)tgt * 512 + 256 + c0);
    float ev[10] = {q0.x, q0.y, q1.x, q1.y, q2.x, q2.y, q3.x, q3.y, q4.x, q4.y};
    float p0 = 0.f, p1 = 0.f, p2 = 0.f, p3 = 0.f;
#pragma unroll
    for (int k = 0; k < 10; ++k) {
      p0 = fmaf(ev[k], wef[k][0], p0);
      p1 = fmaf(ev[k], wef[k][1], p1);
      p2 = fmaf(ev[k], wef[k][2], p2);
      p3 = fmaf(ev[k], wef[k][3], p3);
    }
    float s0 = bf2f(ua.x) + bf2f(ub.x) + p0;
    float s1 = bf2f(ua.y) + bf2f(ub.y) + p1;
    float s2 = bf2f(ua.z) + bf2f(ub.z) + p2;
    float s3 = bf2f(ua.w) + bf2f(ub.w) + p3;
    s0 = (s0 > 0.f) ? s0 : 0.2f * s0;
    s1 = (s1 > 0.f) ? s1 : 0.2f * s1;
    s2 = (s2 > 0.f) ? s2 : 0.2f * s2;
    s3 = (s3 > 0.f) ? s3 : 0.2f * s3;
    float part = s0 * attf[0] + s1 * attf[1] + s2 * attf[2] + s3 * attf[3];
    part += __shfl_xor(part, 1);
    part += __shfl_xor(part, 2);
    part += __shfl_xor(part, 4);
    if ((lane & 7) == 0) logits[(size_t)e * 8 + head] = part;
  };

  const int nw = gridDim.x * 4;
  const int e0 = (blockIdx.x * 4 + wv) * 2;
  for (int e = e0; e < N_EDGES; e += nw * 2) {
    edge_logit(e);
    if (e + 1 < N_EDGES) edge_logit(e + 1);
  }
}

// ---------------- PASS B: node-parallel softmax + aggregate + BN/ELU/residual ----------------
// Register-phase softmax: up to 8 edges' (csr,logit,src) loaded into registers
// with clamped indices (8-wide MLP per dependency level); padding slots get
// w=0 and the self row (no NaN). Rare deg>8 tail falls back to a loop.
__global__ __launch_bounds__(256) void attn_kernel(
    const unsigned short* __restrict__ xlr,
    float* __restrict__ h, unsigned short* __restrict__ hb,
    const int* __restrict__ ei, const float* __restrict__ logits,
    const float* __restrict__ att, const float* __restrict__ bgat,
    const float* __restrict__ ep_self,
    const int* __restrict__ rowptr, const int* __restrict__ csr)
{
  const int lane = threadIdx.x & 63;
  const int wv = threadIdx.x >> 6;
  const int n = blockIdx.x * 4 + wv;
  if (n >= N_NODES) return;
  const int c0 = lane * 4;
  const int head = lane >> 3;

  const int s = rowptr[n], e = rowptr[n + 1];
  const int deg = e - s;

  ushort4 ul = *(const ushort4*)(xlr + (size_t)n * 512 + c0);        // xl[n]
  ushort4 ur = *(const ushort4*)(xlr + (size_t)n * 512 + 256 + c0);  // xr[n]
  float4 hold = *(const float4*)(h + (size_t)n * HIDDEN + c0);
  float4 attf = *(const float4*)(att + c0);
  float4 eps = *(const float4*)(ep_self + c0);

  float xln[4] = {bf2f(ul.x), bf2f(ul.y), bf2f(ul.z), bf2f(ul.w)};

  // self-loop logit
  float lself;
  {
    float s0 = xln[0] + bf2f(ur.x) + eps.x;
    float s1 = xln[1] + bf2f(ur.y) + eps.y;
    float s2 = xln[2] + bf2f(ur.z) + eps.z;
    float s3 = xln[3] + bf2f(ur.w) + eps.w;
    s0 = (s0 > 0.f) ? s0 : 0.2f * s0;
    s1 = (s1 > 0.f) ? s1 : 0.2f * s1;
    s2 = (s2 > 0.f) ? s2 : 0.2f * s2;
    s3 = (s3 > 0.f) ? s3 : 0.2f * s3;
    float part = s0 * attf.x + s1 * attf.y + s2 * attf.z + s3 * attf.w;
    part += __shfl_xor(part, 1);
    part += __shfl_xor(part, 2);
    part += __shfl_xor(part, 4);
    lself = part;
  }

  // phase 1: load up to 8 (csr -> logit, src) into registers; global max
  float lg[8];
  int src[8];
  float m = lself;
  if (deg > 0) {
    const int elast = e - 1;
#pragma unroll
    for (int j = 0; j < 8; ++j) {
      int idx = s + j;
      if (idx > elast) idx = elast;
      int eid = csr[idx];
      lg[j] = logits[(size_t)eid * 8 + head];
      src[j] = ei[eid];
    }
#pragma unroll
    for (int j = 0; j < 8; ++j)
      if (j < deg) m = fmaxf(m, lg[j]);
    for (int idx = s + 8; idx < e; ++idx) {   // rare tail (deg > 8)
      int eid = csr[idx];
      m = fmaxf(m, logits[(size_t)eid * 8 + head]);
    }
  }

  // phase 2: weights, then all gathers in flight, then accumulate
  float w[8];
#pragma unroll
  for (int j = 0; j < 8; ++j)
    w[j] = (j < deg) ? __expf(lg[j] - m) : 0.f;

  ushort4 uu[8];
#pragma unroll
  for (int j = 0; j < 8; ++j) uu[j] = ul;    // padding default: self row (no NaN)
#pragma unroll
  for (int j = 0; j < 8; ++j)
    if (j < deg) uu[j] = *(const ushort4*)(xlr + (size_t)src[j] * 512 + c0);

  float wself = __expf(lself - m);
  float d = wself;
  float a0 = wself * xln[0], a1 = wself * xln[1], a2 = wself * xln[2], a3 = wself * xln[3];
#pragma unroll
  for (int j = 0; j < 8; ++j) {
    d += w[j];
    a0 += w[j] * bf2f(uu[j].x);
    a1 += w[j] * bf2f(uu[j].y);
    a2 += w[j] * bf2f(uu[j].z);
    a3 += w[j] * bf2f(uu[j].w);
  }
  // rare tail (deg > 8)
  for (int idx = s + 8; idx < e; ++idx) {
    int eid = csr[idx];
    float l = logits[(size_t)eid * 8 + head];
    int sn = ei[eid];
    float ww = __expf(l - m);
    ushort4 u = *(const ushort4*)(xlr + (size_t)sn * 512 + c0);
    d += ww;
    a0 += ww * bf2f(u.x);
    a1 += ww * bf2f(u.y);
    a2 += ww * bf2f(u.z);
    a3 += ww * bf2f(u.w);
  }

  float inv = 1.f / (d + 1e-16f);
  float4 bg = *(const float4*)(bgat + c0);
  float ov[4] = {a0 * inv, a1 * inv, a2 * inv, a3 * inv};
  float bgv[4] = {bg.x, bg.y, bg.z, bg.w};
  float hv[4] = {hold.x, hold.y, hold.z, hold.w};
  float4 res;
  float* rp = (float*)&res;
  ushort4 resb;
  unsigned short* rb = (unsigned short*)&resb;
#pragma unroll
  for (int j = 0; j < 4; ++j) {
    float v = (ov[j] + bgv[j]) * BN_S;
    v = (v > 0.f) ? v : (__expf(v) - 1.f);
    float nv = v + hv[j];
    rp[j] = nv;
    rb[j] = f2bf(nv);
  }
  *(float4*)(h + (size_t)n * HIDDEN + c0) = res;
  *(ushort4*)(hb + (size_t)n * HIDDEN + c0) = resb;
}

// ---------------- global attention pooling per graph ----------------
__global__ __launch_bounds__(64) void pool_kernel(
    const float* __restrict__ gate, const float* __restrict__ h,
    const int* __restrict__ brp, float* __restrict__ pooled)
{
  int b = blockIdx.x;
  int lane = threadIdx.x;
  int s = brp[b], e = brp[b + 1];
  float m = -__builtin_inff();
  for (int i = s + lane; i < e; i += 64) m = fmaxf(m, gate[i]);
#pragma unroll
  for (int o = 1; o < 64; o <<= 1) m = fmaxf(m, __shfl_xor(m, o));
  float d = 0.f;
  for (int i = s + lane; i < e; i += 64) d += __expf(gate[i] - m);
#pragma unroll
  for (int o = 1; o < 64; o <<= 1) d += __shfl_xor(d, o);
  float inv = 1.f / (d + 1e-16f);
  int c0 = lane * 4;
  float acc[4] = {0.f, 0.f, 0.f, 0.f};
  for (int i = s; i < e; ++i) {
    float w = __expf(gate[i] - m) * inv;
    float4 hv = *(const float4*)(h + (size_t)i * HIDDEN + c0);
    acc[0] = fmaf(w, hv.x, acc[0]);
    acc[1] = fmaf(w, hv.y, acc[1]);
    acc[2] = fmaf(w, hv.z, acc[2]);
    acc[3] = fmaf(w, hv.w, acc[3]);
  }
  float4 outv = make_float4(acc[0], acc[1], acc[2], acc[3]);
  *(float4*)(pooled + (size_t)b * HIDDEN + c0) = outv;
}

// ---------------- final: out[b] = r3[b,:] . W4 + b4 ----------------
__global__ __launch_bounds__(256) void out_kernel(
    const float* __restrict__ r3, const float* __restrict__ W4,
    const float* __restrict__ b4, float* __restrict__ out)
{
  int lane = threadIdx.x & 63;
  int wv = threadIdx.x >> 6;
  int b = blockIdx.x * 4 + wv;
  if (b >= N_B) return;
  float v = r3[(size_t)b * 64 + lane] * W4[lane];
#pragma unroll
  for (int o = 1; o < 64; o <<= 1) v += __shfl_xor(v, o);
  if (lane == 0) out[b] = v + b4[0];
}

extern "C" void kernel_launch(void* const* d_in, const int* in_sizes, int n_in,
                              void* d_out, int out_size, void* d_ws, size_t ws_size,
                              hipStream_t stream)
{
  const float* x    = (const float*)d_in[0];
  const int* ei     = (const int*)d_in[1];
  const float* ea   = (const float*)d_in[2];
  const int* batch  = (const int*)d_in[3];
  const float* W_in = (const float*)d_in[4];
  const float* b_in = (const float*)d_in[5];
  const float* Wl   = (const float*)d_in[6];
  const float* Wr   = (const float*)d_in[7];
  const float* We   = (const float*)d_in[8];
  const float* att  = (const float*)d_in[9];
  const float* bgat = (const float*)d_in[10];
  const float* Wg1  = (const float*)d_in[11];
  const float* bg1  = (const float*)d_in[12];
  const float* Wg2  = (const float*)d_in[13];
  const float* bg2  = (const float*)d_in[14];
  const float* W1   = (const float*)d_in[15];
  const float* b1   = (const float*)d_in[16];
  const float* W2   = (const float*)d_in[17];
  const float* b2   = (const float*)d_in[18];
  const float* W3   = (const float*)d_in[19];
  const float* b3   = (const float*)d_in[20];
  const float* W4   = (const float*)d_in[21];
  const float* b4   = (const float*)d_in[22];
  float* out = (float*)d_out;

  char* ws = (char*)d_ws;
  size_t off = 0;
  auto alloc = [&](size_t bytes) -> char* {
    char* p = ws + off;
    off += (bytes + 255) & ~(size_t)255;
    return p;
  };
  float* h            = (float*)alloc((size_t)N_NODES * HIDDEN * 4);           // 102.4 MB
  unsigned short* hb  = (unsigned short*)alloc((size_t)N_NODES * HIDDEN * 2);  // 51.2 MB
  unsigned short* xlr = (unsigned short*)alloc((size_t)N_NODES * 512 * 2);     // 102.4 MB
  int* deg       = (int*)alloc((size_t)N_NODES * 4);
  int* rowptr    = (int*)alloc((size_t)(N_NODES + 1) * 4);
  int* cursor    = (int*)alloc((size_t)N_NODES * 4);
  int* csr       = (int*)alloc((size_t)N_EDGES * 4);       // real edges only
  int* brp       = (int*)alloc((size_t)(N_B + 1) * 4);
  int* bsum      = (int*)alloc(512);
  float* macc    = (float*)alloc(64);
  float* meanattr= (float*)alloc(64);
  float* ep_self = (float*)alloc(4 * 256 * 4);
  float* logits  = (float*)alloc((size_t)N_EDGES * 8 * 4); // 7.04 MB
  unsigned short* Wint  = (unsigned short*)alloc(256 * 96 * 2);       // [256][96]
  unsigned short* Wlrt  = (unsigned short*)alloc(4 * 512 * 256 * 2);  // [i][512][256] = Wl^T || Wr^T
  unsigned short* Wg1t  = (unsigned short*)alloc(128 * 256 * 2);      // [128][256]
  // total ≈ 266.3 MB < 268.4 MB ws  ✓

  // aliases into dead regions of xlr:
  unsigned short* xpad = xlr;            // [N,96] bf16, pre-layer0 only
  float* base2  = (float*)xlr;           // xlr fully dead after last attn layer
  float* gate   = base2;                 // [N] f32
  float* pooled = base2 + 1000000;       // [B,256] f32
  float* r1     = base2 + 3000000;       // [B,256] f32
  float* r2     = base2 + 5000000;       // [B,128] f32
  float* r3     = base2 + 6000000;       // [B,64]  f32

  if (ws_size < off) {
    hipMemsetAsync(d_out, 0, (size_t)out_size * 4, stream);
    return;
  }

  zero_kernel<<<391, 256, 0, stream>>>(deg, cursor, macc);
  mean_kernel<<<64, 256, 0, stream>>>(ea, macc);
  meanattr_kernel<<<1, 64, 0, stream>>>(macc, meanattr);
  epself_kernel<<<4, 256, 0, stream>>>(meanattr, We, ep_self);
  count_kernel<<<860, 256, 0, stream>>>(ei, deg);
  scan1_kernel<<<NSCANB, 1024, 0, stream>>>(deg, rowptr, bsum);
  scan2_kernel<<<1, 128, 0, stream>>>(bsum);
  scan3_kernel<<<NSCANB, 1024, 0, stream>>>(rowptr, bsum);
  scatter_kernel<<<860, 256, 0, stream>>>(ei, rowptr, cursor, csr);
  brp_kernel<<<512, 256, 0, stream>>>(batch, brp);

  // weight conversions (transpose + bf16)
  wt_kernel<<<(256 * 96 + 255) / 256, 256, 0, stream>>>(W_in, Wint, 75, 96, 256);
  wlr_kernel<<<512, 256, 0, stream>>>(Wl, Wr, Wlrt);
  wt_kernel<<<128, 256, 0, stream>>>(Wg1, Wg1t, 256, 256, 128);
  convx_kernel<<<4096, 256, 0, stream>>>(x, xpad);

  // input projection: h = elu((x @ W_in + b_in) * BN_S)  [MFMA, K=96]
  gemm_mfma<<<1564, 256, 0, stream>>>(xpad, Wint, b_in, h, hb,
                                      N_NODES, 256, 96, 2, BN_S, 2);

  for (int i = 0; i < 4; ++i) {
    // fused xl||xr GEMM: [N,256] @ [256,512] -> xlr [N,512]
    gemm_mfma<<<3128, 256, 0, stream>>>(hb, Wlrt + (size_t)i * 131072, nullptr,
                                        nullptr, xlr, N_NODES, 512, 256, 0, 1.f, 4);
    // pass A: edge-parallel logits
    logits_kernel<<<2048, 256, 0, stream>>>(xlr, ei, ea, We + (size_t)i * 2560,
                                            att + (size_t)i * 256, logits);
    // pass B: node-parallel softmax + aggregate
    attn_kernel<<<25000, 256, 0, stream>>>(xlr, h, hb, ei, logits,
                                           att + (size_t)i * 256, bgat + (size_t)i * 256,
                                           ep_self + (size_t)i * 256, rowptr, csr);
  }

  // fused pooling gate: gate = relu(hb @ Wg1 + bg1) . Wg2 + bg2
  gemm_gate<<<782, 256, 0, stream>>>(hb, Wg1t, bg1, Wg2, bg2, gate, N_NODES);
  pool_kernel<<<N_B, 64, 0, stream>>>(gate, h, brp, pooled);

  // readout MLP (f32, tiny)
  gemm_f32<<<dim3(4, 64), 256, 0, stream>>>(pooled, W1, b1, r1, N_B, 256, 256, 1, BN_S);
  gemm_f32<<<dim3(2, 64), 256, 0, stream>>>(r1, W2, b2, r2, N_B, 128, 256, 1, BN_S);
  gemm_f32<<<dim3(1, 64), 256, 0, stream>>>(r2, W3, b3, r3, N_B, 64, 128, 1, 1.f);
  out_kernel<<<1024, 256, 0, stream>>>(r3, W4, b4, out);
}